// Round 9
// baseline (1532.090 us; speedup 1.0000x reference)
//
#include <hip/hip_runtime.h>
#include <math.h>

#define BATCH 8
#define SEQ   2048
#define TOK   (BATCH*SEQ)     // 16384
#define CIN   32
#define DM    512
#define DFF   2048
#define NH    8
#define HD    64
#define NSAMP 24
#define NTOP  24
#define EPS   1e-5f
#define QKVLD 1536

typedef unsigned int u32;
typedef unsigned short u16;
typedef unsigned long long u64;
typedef __attribute__((ext_vector_type(8))) short short8;
typedef __attribute__((ext_vector_type(4))) float floatx4;

__device__ __forceinline__ void async16(const void* g, void* l) {
    __builtin_amdgcn_global_load_lds((const __attribute__((address_space(1))) u32*)g,
                                     (__attribute__((address_space(3))) u32*)l, 16, 0, 0);
}
__device__ __forceinline__ u16 bf16rn(float f) {
    u32 u = __float_as_uint(f);
    return (u16)((u + 0x7fffu + ((u >> 16) & 1u)) >> 16);
}

// ---------------- Threefry-2x32 ----------------
__device__ __forceinline__ void tf_round(unsigned &x0, unsigned &x1, int r) {
    x0 += x1;
    x1 = (x1 << r) | (x1 >> (32 - r));
    x1 ^= x0;
}
__device__ __forceinline__ void threefry(unsigned k0, unsigned k1,
                                         unsigned c0, unsigned c1,
                                         unsigned &o0, unsigned &o1) {
    unsigned ks0 = k0, ks1 = k1, ks2 = k0 ^ k1 ^ 0x1BD11BDAu;
    unsigned x0 = c0 + ks0, x1 = c1 + ks1;
    tf_round(x0,x1,13); tf_round(x0,x1,15); tf_round(x0,x1,26); tf_round(x0,x1,6);
    x0 += ks1; x1 += ks2 + 1u;
    tf_round(x0,x1,17); tf_round(x0,x1,29); tf_round(x0,x1,16); tf_round(x0,x1,24);
    x0 += ks2; x1 += ks0 + 2u;
    tf_round(x0,x1,13); tf_round(x0,x1,15); tf_round(x0,x1,26); tf_round(x0,x1,6);
    x0 += ks0; x1 += ks1 + 3u;
    tf_round(x0,x1,17); tf_round(x0,x1,29); tf_round(x0,x1,16); tf_round(x0,x1,24);
    x0 += ks1; x1 += ks2 + 4u;
    tf_round(x0,x1,13); tf_round(x0,x1,15); tf_round(x0,x1,26); tf_round(x0,x1,6);
    x0 += ks2; x1 += ks0 + 5u;
    o0 = x0; o1 = x1;
}

__global__ void sample_kernel(int* __restrict__ idx_sample) {
    const int HALF = (SEQ * NSAMP) / 2;  // 24576
    int p = blockIdx.x * blockDim.x + threadIdx.x;
    int li = blockIdx.y;
    if (p >= HALF) return;
    unsigned f0, f1;
    threefry(0u, 42u, 0u, (unsigned)li, f0, f1);
    unsigned a0, a1, b0, b1;
    threefry(f0, f1, 0u, 2u, a0, a1);
    threefry(f0, f1, 1u, 3u, b0, b1);
    unsigned o0, o1;
    threefry(a1, b1, (unsigned)p, (unsigned)(p + HALF), o0, o1);
    idx_sample[li * SEQ * NSAMP + p]        = (int)(o0 & (SEQ - 1));
    idx_sample[li * SEQ * NSAMP + p + HALF] = (int)(o1 & (SEQ - 1));
}

// ---------------- input layernorm over C_IN=32 ----------------
__global__ __launch_bounds__(256) void ln_in_kernel(const float* __restrict__ x,
        const float* __restrict__ g, const float* __restrict__ b,
        float* __restrict__ out) {
    int t = blockIdx.x * blockDim.x + threadIdx.x;
    if (t >= TOK) return;
    const float* xr = x + (size_t)t * CIN;
    float vals[CIN];
    float s = 0.f;
#pragma unroll
    for (int c = 0; c < CIN; c++) { vals[c] = xr[c]; s += vals[c]; }
    float m = s * (1.f / CIN);
    float v = 0.f;
#pragma unroll
    for (int c = 0; c < CIN; c++) { float d = vals[c] - m; v += d * d; }
    v *= (1.f / CIN);
    float inv = rsqrtf(v + EPS);
    float* orow = out + (size_t)t * CIN;
#pragma unroll
    for (int c = 0; c < CIN; c++) orow[c] = (vals[c] - m) * inv * g[c] + b[c];
}

// ---------------- im2col (wrap pad), fp32: A[t][j], j=w*32+c ----------------
__global__ __launch_bounds__(128) void im2col_kernel(const float* __restrict__ xln,
        float* __restrict__ a) {
    int t = blockIdx.x;
    int j = threadIdx.x;
    if (j >= 96) return;
    int b = t >> 11, l = t & 2047;
    int w = j >> 5, c = j & 31;
    int lw = (l - 1 + w + SEQ) & 2047;
    a[(size_t)t * 96 + j] = xln[(((size_t)b << 11) | lw) * CIN + c];
}

// ---------------- W_tok transpose + split to separate bf16 h/l: wt[o][j] ----------------
__global__ __launch_bounds__(256) void wtok_split(const float* __restrict__ Wtok,
        u16* __restrict__ wth, u16* __restrict__ wtl) {
    int e = blockIdx.x * 256 + threadIdx.x;  // < 49152
    int o = e / 96, j = e % 96;
    float f = Wtok[(size_t)j * DM + o];
    u16 hb = bf16rn(f);
    wth[e] = hb;
    wtl[e] = bf16rn(f - __uint_as_float((u32)hb << 16));
}

// ---------------- positional embedding table pe[l][o] ----------------
__global__ __launch_bounds__(256) void pe_kernel(float* __restrict__ pe) {
    int e = blockIdx.x * 256 + threadIdx.x;  // < 1048576
    int l = e >> 9, o = e & 511;
    const float c1 = -0.017988946039016f;  // -ln(10000)/512
    int i2 = o & ~1;
    float div = expf((float)i2 * c1);
    float arg = (float)l * div;
    pe[e] = (o & 1) ? cosf(arg) : sinf(arg);
}

// ---------------- rsd[t][o] = pe[l][o] + tf[t]·Wtime[o] ----------------
__global__ __launch_bounds__(256) void rsd_kernel(const float* __restrict__ pe,
        const float* __restrict__ tfeat, const float* __restrict__ Wtime,
        float* __restrict__ rsd) {
    int t = blockIdx.x, tid = threadIdx.x;
    int l = t & 2047;
    float t0 = tfeat[(size_t)t * 4], t1 = tfeat[(size_t)t * 4 + 1];
    float t2 = tfeat[(size_t)t * 4 + 2], t3 = tfeat[(size_t)t * 4 + 3];
    for (int o = tid; o < DM; o += 256) {
        rsd[(size_t)t * DM + o] = pe[l * DM + o]
            + t0 * Wtime[o * 4] + t1 * Wtime[o * 4 + 1]
            + t2 * Wtime[o * 4 + 2] + t3 * Wtime[o * 4 + 3];
    }
}

// ---------------- weight split: fp32 -> separate bf16 high/low buffers ----------------
__global__ __launch_bounds__(256) void split_weights(const float* __restrict__ Wq,
        const float* __restrict__ Wk, const float* __restrict__ Wv,
        const float* __restrict__ Wo, const float* __restrict__ W1,
        const float* __restrict__ W2, u16* __restrict__ wh, u16* __restrict__ wl) {
    int i = blockIdx.x * 256 + threadIdx.x;  // < 3145728
    const float* src; int off;
    if (i < 1048576) {
        src = (i < 262144) ? Wq : (i < 524288) ? Wk : (i < 786432) ? Wv : Wo;
        off = i & 262143;
    } else if (i < 2097152) { src = W1; off = i - 1048576; }
    else { src = W2; off = i - 2097152; }
    float f = src[off];
    u16 h = bf16rn(f);
    wh[i] = h;
    wl[i] = bf16rn(f - __uint_as_float((u32)h << 16));
}

__global__ void concat_bias(const float* __restrict__ bq, const float* __restrict__ bk,
                            const float* __restrict__ bv, float* __restrict__ o) {
    int i = blockIdx.x * 256 + threadIdx.x;  // < 1536
    o[i] = (i < 512) ? bq[i] : (i < 1024) ? bk[i - 512] : bv[i - 1024];
}

// ---------------- split-bf16 MFMA GEMM, double-buffered single-barrier K-loop ----------
// C = A[MxK]*W[NxK]^T + bias (+res)(+relu).  A: fp32 split on the fly;
// W: separate bf16 Wh/Wl buffers -> direct ds_read_b128 fragments, zero unpack VALU.
template<bool RELU, bool RES>
__global__ __launch_bounds__(256, 2) void gemm_split(const float* __restrict__ A,
        const u16* __restrict__ Wh, const u16* __restrict__ Wl,
        const float* __restrict__ bias, const float* __restrict__ Rsd,
        float* __restrict__ C, int ldc, int K, int lda) {
    __shared__ alignas(16) u16 AhS[2][128 * 40];   // padded stride 40
    __shared__ alignas(16) u16 AlS[2][128 * 40];
    __shared__ alignas(16) u16 WhS[2][4096];       // [kchunk 0..3][row 0..127][8]
    __shared__ alignas(16) u16 WlS[2][4096];
    const int tid = threadIdx.x;
    const int m0 = blockIdx.y * 128, n0 = blockIdx.x * 128;
    const int lane = tid & 63, wv = tid >> 6;
    const int wm = wv >> 1, wn = wv & 1;
    const int fr = lane & 15, q = lane >> 4;

    floatx4 acc[4][4] = {};

    const int arow = tid >> 1, ahalf = tid & 1;
    const float* abase = A + (size_t)(m0 + arow) * lda + ahalf * 16;
    const int wrow = tid & 127, wc = tid >> 7;     // wc in {0,1}
    const u16* whbase = Wh + (size_t)(n0 + wrow) * K + wc * 8;
    const u16* wlbase = Wl + (size_t)(n0 + wrow) * K + wc * 8;
    const int wdoff = (wc * 128 + wrow) * 16;      // byte offset: kchunk wc(+2i), row wrow
    const int aoff = arow * 40 + ahalf * 16;

    const int nk = K >> 5;
    float f[16];

    // ---- prologue: stage tile 0 into buf 0, prefetch A tile 1 regs ----
#pragma unroll
    for (int i = 0; i < 2; i++) {
        async16(whbase + i * 16, (char*)WhS[0] + wdoff + i * 4096);
        async16(wlbase + i * 16, (char*)WlS[0] + wdoff + i * 4096);
    }
    *(float4*)&f[0]  = *(const float4*)(abase);
    *(float4*)&f[4]  = *(const float4*)(abase + 4);
    *(float4*)&f[8]  = *(const float4*)(abase + 8);
    *(float4*)&f[12] = *(const float4*)(abase + 12);
    {
        short8 h0, h1, l0, l1;
#pragma unroll
        for (int j = 0; j < 8; j++) {
            u16 hb = bf16rn(f[j]);
            float r = f[j] - __uint_as_float((u32)hb << 16);
            h0[j] = (short)hb; l0[j] = (short)bf16rn(r);
            u16 hb2 = bf16rn(f[j + 8]);
            float r2 = f[j + 8] - __uint_as_float((u32)hb2 << 16);
            h1[j] = (short)hb2; l1[j] = (short)bf16rn(r2);
        }
        *(short8*)&AhS[0][aoff] = h0;  *(short8*)&AhS[0][aoff + 8] = h1;
        *(short8*)&AlS[0][aoff] = l0;  *(short8*)&AlS[0][aoff + 8] = l1;
    }
    {
        int k1 = (nk > 1) ? 32 : 0;
        const float* ap = abase + k1;
        *(float4*)&f[0]  = *(const float4*)(ap);
        *(float4*)&f[4]  = *(const float4*)(ap + 4);
        *(float4*)&f[8]  = *(const float4*)(ap + 8);
        *(float4*)&f[12] = *(const float4*)(ap + 12);
    }

    for (int k = 0; k < nk; k++) {
        const int b = k & 1;
        __syncthreads();   // buf b staged (W-DMA k + A LDS writes); drains prev iter's vmem
        if (k + 1 < nk) {
            int k0n = (k + 1) << 5;
#pragma unroll
            for (int i = 0; i < 2; i++) {
                async16(whbase + k0n + i * 16, (char*)WhS[b ^ 1] + wdoff + i * 4096);
                async16(wlbase + k0n + i * 16, (char*)WlS[b ^ 1] + wdoff + i * 4096);
            }
            short8 h0, h1, l0, l1;
#pragma unroll
            for (int j = 0; j < 8; j++) {
                u16 hb = bf16rn(f[j]);
                float r = f[j] - __uint_as_float((u32)hb << 16);
                h0[j] = (short)hb; l0[j] = (short)bf16rn(r);
                u16 hb2 = bf16rn(f[j + 8]);
                float r2 = f[j + 8] - __uint_as_float((u32)hb2 << 16);
                h1[j] = (short)hb2; l1[j] = (short)bf16rn(r2);
            }
            *(short8*)&AhS[b ^ 1][aoff] = h0;  *(short8*)&AhS[b ^ 1][aoff + 8] = h1;
            *(short8*)&AlS[b ^ 1][aoff] = l0;  *(short8*)&AlS[b ^ 1][aoff + 8] = l1;
            int k0nn = (k + 2 < nk) ? ((k + 2) << 5) : 0;
            const float* ap = abase + k0nn;
            *(float4*)&f[0]  = *(const float4*)(ap);
            *(float4*)&f[4]  = *(const float4*)(ap + 4);
            *(float4*)&f[8]  = *(const float4*)(ap + 8);
            *(float4*)&f[12] = *(const float4*)(ap + 12);
        }
        // ---- MFMA on buf b: direct b128 fragment reads ----
        short8 ah[4], al[4];
#pragma unroll
        for (int mi = 0; mi < 4; mi++) {
            int off = (wm * 64 + mi * 16 + fr) * 40 + q * 8;
            ah[mi] = *(const short8*)&AhS[b][off];
            al[mi] = *(const short8*)&AlS[b][off];
        }
#pragma unroll
        for (int ni = 0; ni < 4; ni++) {
            int woff = (q * 128 + wn * 64 + ni * 16 + fr) * 8;
            short8 wh8 = *(const short8*)&WhS[b][woff];
            short8 wl8 = *(const short8*)&WlS[b][woff];
#pragma unroll
            for (int mi = 0; mi < 4; mi++) {
                acc[mi][ni] = __builtin_amdgcn_mfma_f32_16x16x32_bf16(ah[mi], wh8, acc[mi][ni], 0, 0, 0);
                acc[mi][ni] = __builtin_amdgcn_mfma_f32_16x16x32_bf16(ah[mi], wl8, acc[mi][ni], 0, 0, 0);
                acc[mi][ni] = __builtin_amdgcn_mfma_f32_16x16x32_bf16(al[mi], wh8, acc[mi][ni], 0, 0, 0);
            }
        }
    }
    // --- epilogue ---
#pragma unroll
    for (int ni = 0; ni < 4; ni++) {
        int col = n0 + wn * 64 + ni * 16 + fr;
        float bv = bias[col];
#pragma unroll
        for (int mi = 0; mi < 4; mi++) {
            int row = m0 + wm * 64 + mi * 16 + q * 4;
#pragma unroll
            for (int r = 0; r < 4; r++) {
                size_t idx = (size_t)(row + r) * ldc + col;
                float v = acc[mi][ni][r] + bv;
                if (RES) v += Rsd[idx];
                if (RELU) v = fmaxf(v, 0.f);
                C[idx] = v;
            }
        }
    }
}

// ---------------- M = max(QK_sample) - sum/L : one wave per (b,h,l) ----------------
__global__ __launch_bounds__(256) void qk_sample_kernel(const float* __restrict__ qkv,
        const int* __restrict__ idx_sample, float* __restrict__ Mout) {
    int r = (blockIdx.x * 256 + threadIdx.x) >> 6;
    int lane = threadIdx.x & 63;
    if (r >= BATCH * NH * SEQ) return;
    int b = r / (NH * SEQ);
    int head = (r / SEQ) % NH;
    int l = r % SEQ;
    int sidx = lane >> 4, dc = lane & 15;
    const float* qrow = qkv + ((size_t)(b * SEQ + l)) * QKVLD + head * HD + dc * 4;
    float4 qf = *(const float4*)qrow;
    int myidx = (lane < NSAMP) ? idx_sample[l * NSAMP + lane] : 0;
    const float* kbase = qkv + (size_t)b * SEQ * QKVLD + 512 + head * HD + dc * 4;
    float mx = -INFINITY, sm = 0.f;
#pragma unroll
    for (int p = 0; p < 6; p++) {
        int s = p * 4 + sidx;
        int kidx = __shfl(myidx, s);
        float4 kf = *(const float4*)(kbase + (size_t)kidx * QKVLD);
        float part = qf.x * kf.x + qf.y * kf.y + qf.z * kf.z + qf.w * kf.w;
        part += __shfl_xor(part, 1);
        part += __shfl_xor(part, 2);
        part += __shfl_xor(part, 4);
        part += __shfl_xor(part, 8);
        mx = fmaxf(mx, part);
        sm += part;
    }
    mx = fmaxf(mx, __shfl_xor(mx, 16));
    mx = fmaxf(mx, __shfl_xor(mx, 32));
    sm += __shfl_xor(sm, 16);
    sm += __shfl_xor(sm, 32);
    if (lane == 0) Mout[r] = mx - sm * (1.f / SEQ);
}

// ---------------- top-24 two-stage: packed u64 keys, exact (idx unique) ----------------
__device__ __forceinline__ u64 pack_key(float v, int idx) {
    u32 u = __float_as_uint(v);
    u32 m = (u & 0x80000000u) ? ~u : (u | 0x80000000u);
    return ((u64)m << 32) | (u32)(~(u32)idx);
}

__global__ __launch_bounds__(256) void topk_part(const float* __restrict__ Mbuf,
        u64* __restrict__ cand) {
    __shared__ u64 vals[256];
    __shared__ u64 red[256];
    int bh = blockIdx.x, chunk = blockIdx.y;
    int tid = threadIdx.x;
    int l = chunk * 256 + tid;
    vals[tid] = pack_key(Mbuf[(size_t)bh * SEQ + l], l);
    __syncthreads();
    for (int it = 0; it < NTOP; it++) {
        red[tid] = vals[tid];
        __syncthreads();
        for (int s = 128; s > 0; s >>= 1) {
            if (tid < s) { u64 o = red[tid + s]; if (o > red[tid]) red[tid] = o; }
            __syncthreads();
        }
        u64 win = red[0];
        if (vals[tid] == win) vals[tid] = 0;
        if (tid == 0) cand[((size_t)bh * 8 + chunk) * NTOP + it] = win;
        __syncthreads();
    }
}

__global__ __launch_bounds__(256) void topk_merge(const u64* __restrict__ cand,
        int* __restrict__ idx_top) {
    __shared__ u64 vals[256];
    __shared__ u64 red[256];
    int bh = blockIdx.x;
    int tid = threadIdx.x;
    vals[tid] = (tid < 8 * NTOP) ? cand[(size_t)bh * 8 * NTOP + tid] : 0;
    __syncthreads();
    for (int it = 0; it < NTOP; it++) {
        red[tid] = vals[tid];
        __syncthreads();
        for (int s = 128; s > 0; s >>= 1) {
            if (tid < s) { u64 o = red[tid + s]; if (o > red[tid]) red[tid] = o; }
            __syncthreads();
        }
        u64 win = red[0];
        if (vals[tid] == win) vals[tid] = 0;
        if (tid == 0) idx_top[bh * NTOP + it] = (int)(~(u32)(win & 0xffffffffull) & (SEQ - 1));
        __syncthreads();
    }
}

// ---------------- V mean over keys per (b,h) ----------------
__global__ __launch_bounds__(256) void vmean_kernel(const float* __restrict__ qkv,
        float* __restrict__ vmean) {
    __shared__ float red[256];
    int bh = blockIdx.x, slab = blockIdx.y;
    int b = bh >> 3, head = bh & 7;
    int seg = threadIdx.x >> 6, d = threadIdx.x & 63;
    int base_row = slab * 256 + seg * 64;
    float s = 0.f;
    for (int r = 0; r < 64; r++)
        s += qkv[((size_t)(b * SEQ + base_row + r)) * QKVLD + 1024 + head * HD + d];
    red[threadIdx.x] = s;
    __syncthreads();
    if (threadIdx.x < 128) red[threadIdx.x] += red[threadIdx.x + 128];
    __syncthreads();
    if (threadIdx.x < 64) {
        float t = red[threadIdx.x] + red[threadIdx.x + 64];
        atomicAdd(&vmean[bh * HD + d], t * (1.f / SEQ));
    }
}

// ---------------- fill context with V-mean ----------------
__global__ void fillctx_kernel(const float* __restrict__ vmean, float* __restrict__ out) {
    int e = blockIdx.x * 256 + threadIdx.x;
    int c = e & 511;
    int b = e >> 20;
    out[e] = vmean[(((b << 3) | (c >> 6)) << 6) + (c & 63)];
}

// ---------------- flash-style sparse attention: block = (b*h, key-slab of 512) ----------------
__global__ __launch_bounds__(256) void spattn_flash(const float* __restrict__ qkv,
        const int* __restrict__ idx_top, float* __restrict__ opart,
        float* __restrict__ mspart) {
    __shared__ float KtT[64][65];   // transposed: [dim][key]
    __shared__ float Vt[64][65];    // [key][dim]
    __shared__ float Qs[24][64];
    __shared__ float Ps[24][66];
    int bh = blockIdx.x, slab = blockIdx.y;
    int b = bh >> 3, h = bh & 7;
    int tid = threadIdx.x;
    int wv = tid >> 6, lane = tid & 63;
    for (int i = tid; i < NTOP * 64; i += 256) {
        int u = i >> 6, d = i & 63;
        int qi = idx_top[bh * NTOP + u];
        Qs[u][d] = qkv[((size_t)(b * SEQ + qi)) * QKVLD + h * HD + d];
    }
    float m[6], s[6], o[6], alpha[6];
#pragma unroll
    for (int j = 0; j < 6; j++) { m[j] = -INFINITY; s[j] = 0.f; o[j] = 0.f; }
    int key0 = slab * 512;
    int sr = tid >> 2, sc0 = (tid & 3) * 16;
    for (int t = 0; t < 8; t++) {
        int kbase = key0 + t * 64;
        __syncthreads();
        const float* kr = qkv + ((size_t)(b * SEQ + kbase + sr)) * QKVLD + 512 + h * HD + sc0;
        const float* vr = qkv + ((size_t)(b * SEQ + kbase + sr)) * QKVLD + 1024 + h * HD + sc0;
        float kf[16], vf[16];
        *(float4*)&kf[0]  = *(const float4*)(kr);
        *(float4*)&kf[4]  = *(const float4*)(kr + 4);
        *(float4*)&kf[8]  = *(const float4*)(kr + 8);
        *(float4*)&kf[12] = *(const float4*)(kr + 12);
        *(float4*)&vf[0]  = *(const float4*)(vr);
        *(float4*)&vf[4]  = *(const float4*)(vr + 4);
        *(float4*)&vf[8]  = *(const float4*)(vr + 8);
        *(float4*)&vf[12] = *(const float4*)(vr + 12);
#pragma unroll
        for (int i = 0; i < 16; i++) {
            KtT[sc0 + i][sr] = kf[i];
            Vt[sr][sc0 + i] = vf[i];
        }
        __syncthreads();
        float dot[6] = {};
#pragma unroll
        for (int d = 0; d < 64; d++) {
            float kv = KtT[d][lane];
#pragma unroll
            for (int j = 0; j < 6; j++) dot[j] += Qs[wv * 6 + j][d] * kv;
        }
#pragma unroll
        for (int j = 0; j < 6; j++) {
            float sc = dot[j] * 0.125f;
            float tmax = sc;
            for (int off = 32; off > 0; off >>= 1) tmax = fmaxf(tmax, __shfl_xor(tmax, off));
            float mn = fmaxf(m[j], tmax);
            float p = __expf(sc - mn);
            float psum = p;
            for (int off = 32; off > 0; off >>= 1) psum += __shfl_xor(psum, off);
            alpha[j] = __expf(m[j] - mn);
            s[j] = s[j] * alpha[j] + psum;
            m[j] = mn;
            Ps[wv * 6 + j][lane] = p;
        }
        float pv[6] = {};
#pragma unroll
        for (int key = 0; key < 64; key++) {
            float vvv = Vt[key][lane];
#pragma unroll
            for (int j = 0; j < 6; j++) pv[j] += Ps[wv * 6 + j][key] * vvv;
        }
#pragma unroll
        for (int j = 0; j < 6; j++) o[j] = o[j] * alpha[j] + pv[j];
    }
    float* ob = opart + ((size_t)(bh * 4 + slab)) * NTOP * 64;
#pragma unroll
    for (int j = 0; j < 6; j++) ob[(wv * 6 + j) * 64 + lane] = o[j];
    if (lane == 0) {
        float* ms = mspart + ((size_t)(bh * 4 + slab)) * NTOP * 2;
#pragma unroll
        for (int j = 0; j < 6; j++) {
            ms[(wv * 6 + j) * 2]     = m[j];
            ms[(wv * 6 + j) * 2 + 1] = s[j];
        }
    }
}

// ---------------- merge 4 slab partials, scatter into context ----------------
__global__ __launch_bounds__(256) void spattn_combine(const float* __restrict__ opart,
        const float* __restrict__ mspart, const int* __restrict__ idx_top,
        float* __restrict__ out) {
    __shared__ float wgt[4][NTOP];
    int bh = blockIdx.x;
    int b = bh >> 3, h = bh & 7;
    int tid = threadIdx.x;
    if (tid < NTOP) {
        float mv[4], sv[4];
        float M = -INFINITY;
#pragma unroll
        for (int sl = 0; sl < 4; sl++) {
            mv[sl] = mspart[((size_t)(bh * 4 + sl)) * NTOP * 2 + tid * 2];
            sv[sl] = mspart[((size_t)(bh * 4 + sl)) * NTOP * 2 + tid * 2 + 1];
            M = fmaxf(M, mv[sl]);
        }
        float S = 0.f;
#pragma unroll
        for (int sl = 0; sl < 4; sl++) S += sv[sl] * __expf(mv[sl] - M);
        float invS = 1.f / S;
#pragma unroll
        for (int sl = 0; sl < 4; sl++) wgt[sl][tid] = __expf(mv[sl] - M) * invS;
    }
    __syncthreads();
    for (int i = tid; i < NTOP * 64; i += 256) {
        int u = i >> 6, d = i & 63;
        float val = 0.f;
#pragma unroll
        for (int sl = 0; sl < 4; sl++)
            val += wgt[sl][u] * opart[(((size_t)(bh * 4 + sl)) * NTOP + u) * 64 + d];
        int qi = idx_top[bh * NTOP + u];
        out[((size_t)(b * SEQ + qi)) * DM + h * HD + d] = val;
    }
}

// ---------------- layernorm over DM=512 ----------------
__global__ __launch_bounds__(256) void ln_kernel(const float* src,
        const float* __restrict__ g, const float* __restrict__ b, float* dst) {
    __shared__ float red[256];
    int t = blockIdx.x, tid = threadIdx.x;
    const float* xr = src + (size_t)t * DM;
    float x0 = xr[tid], x1 = xr[tid + 256];
    red[tid] = x0 + x1; __syncthreads();
    for (int s = 128; s > 0; s >>= 1) { if (tid < s) red[tid] += red[tid + s]; __syncthreads(); }
    float m = red[0] * (1.f / DM);
    __syncthreads();
    float d0 = x0 - m, d1 = x1 - m;
    red[tid] = d0 * d0 + d1 * d1; __syncthreads();
    for (int s = 128; s > 0; s >>= 1) { if (tid < s) red[tid] += red[tid + s]; __syncthreads(); }
    float inv = rsqrtf(red[0] * (1.f / DM) + EPS);
    float* dr = dst + (size_t)t * DM;
    dr[tid] = d0 * inv * g[tid] + b[tid];
    dr[tid + 256] = d1 * inv * g[tid + 256] + b[tid + 256];
}

// ---------------- prediction head on last token ----------------
__global__ __launch_bounds__(256) void head_kernel(const float* __restrict__ hfin,
        const float* __restrict__ Wpre, const float* __restrict__ bpre,
        const float* __restrict__ Wfc, const float* __restrict__ bfc,
        float* __restrict__ out) {
    __shared__ float last[DM];
    __shared__ float red[256];
    int b = blockIdx.x, tid = threadIdx.x;
    const float* hr = hfin + ((size_t)(b * SEQ + SEQ - 1)) * DM;
    last[tid] = hr[tid];
    last[tid + 256] = hr[tid + 256];
    __syncthreads();
    float acc = bpre[tid];
    for (int c = 0; c < DM; c++) acc += last[c] * Wpre[tid * DM + c];
    acc = fmaxf(acc, 0.f);
    red[tid] = acc * Wfc[tid];
    __syncthreads();
    for (int s = 128; s > 0; s >>= 1) { if (tid < s) red[tid] += red[tid + s]; __syncthreads(); }
    if (tid == 0) out[b] = red[0] + bfc[0];
}

extern "C" void kernel_launch(void* const* d_in, const int* in_sizes, int n_in,
                              void* d_out, int out_size, void* d_ws, size_t ws_size,
                              hipStream_t stream) {
    (void)in_sizes; (void)n_in; (void)out_size; (void)ws_size;
    const float* x      = (const float*)d_in[0];
    const float* tfeat  = (const float*)d_in[1];
    const float* g_in   = (const float*)d_in[2];
    const float* b_in   = (const float*)d_in[3];
    const float* W_tok  = (const float*)d_in[4];
    const float* W_time = (const float*)d_in[5];
    const float* b_time = (const float*)d_in[6];
    const float* Wq     = (const float*)d_in[7];
    const float* bq     = (const float*)d_in[8];
    const float* Wk     = (const float*)d_in[9];
    const float* bk     = (const float*)d_in[10];
    const float* Wv     = (const float*)d_in[11];
    const float* bv     = (const float*)d_in[12];
    const float* Wo     = (const float*)d_in[13];
    const float* bo     = (const float*)d_in[14];
    const float* W1     = (const float*)d_in[15];
    const float* b1     = (const float*)d_in[16];
    const float* W2     = (const float*)d_in[17];
    const float* b2     = (const float*)d_in[18];
    const float* g1     = (const float*)d_in[19];
    const float* be1    = (const float*)d_in[20];
    const float* g2     = (const float*)d_in[21];
    const float* be2    = (const float*)d_in[22];
    const float* g_enc  = (const float*)d_in[23];
    const float* b_enc  = (const float*)d_in[24];
    const float* W_pre  = (const float*)d_in[25];
    const float* b_pre  = (const float*)d_in[26];
    const float* W_fc   = (const float*)d_in[27];
    const float* b_fc   = (const float*)d_in[28];
    float* out = (float*)d_out;

    char* ws = (char*)d_ws;
    float* h    = (float*)(ws);                      // 33.5 MB fp32 residual
    float* tmp  = (float*)(ws + 33554432);           // 33.5 MB fp32
    char*  bigc = ws + 67108864;                     // 134.2 MB multi-use
    float* big  = (float*)bigc;                      // qkv [TOK][1536] fp32 / FFN mid
    // embed-stage overlays inside big:
    float* xln  = (float*)(bigc);                    // 2 MB
    float* acv  = (float*)(bigc + 2097152);          // im2col [TOK][96] fp32, 6.3 MB
    float* pe   = (float*)(bigc + 8388608);          // 4 MB
    float* rsd  = (float*)(bigc + 12582912);         // 33.5 MB
    u16*   wtokh = (u16*)(bigc + 46137344);          // W_tok bf16-high [512][96]
    u16*   wtokl = (u16*)(bigc + 46235648);          // W_tok bf16-low
    u16*   wgh        = (u16*)(ws + 201326592);      // 6.3 MB per-layer weight highs
    u16*   wgl        = (u16*)(ws + 207618048);      // 6.3 MB per-layer weight lows
    float* Mbuf       = (float*)(ws + 213909504);    // 0.5 MB
    float* vmean      = (float*)(ws + 214433792);
    int*   idx_sample = (int*)(ws + 214450176);
    int*   idx_top    = (int*)(ws + 214843392);
    float* biasqkv    = (float*)(ws + 214849536);
    u64*   cand       = (u64*)(ws + 214855680);      // 98 KB
    float* opart      = (float*)(ws + 214953984);    // 1.57 MB
    float* mspart     = (float*)(ws + 216526848);    // 48 KB

    ln_in_kernel<<<TOK / 256, 256, 0, stream>>>(x, g_in, b_in, xln);
    im2col_kernel<<<TOK, 128, 0, stream>>>(xln, acv);
    wtok_split<<<192, 256, 0, stream>>>(W_tok, wtokh, wtokl);
    pe_kernel<<<4096, 256, 0, stream>>>(pe);
    rsd_kernel<<<TOK, 256, 0, stream>>>(pe, tfeat, W_time, rsd);
    sample_kernel<<<dim3(96, 2), 256, 0, stream>>>(idx_sample);

    // conv-as-GEMM: h = im2col @ W_tok^T + b_time + (pe + time emb)
    gemm_split<false, true><<<dim3(4, 128), 256, 0, stream>>>(
        acv, wtokh, wtokl, b_time, rsd, h, DM, 96, 96);

    const u16* wqkv_h = wgh;                 // rows 0..1535 = Wq;Wk;Wv
    const u16* wqkv_l = wgl;
    const u16* wo_h = wgh + 786432,  *wo_l = wgl + 786432;
    const u16* w1_h = wgh + 1048576, *w1_l = wgl + 1048576;
    const u16* w2_h = wgh + 2097152, *w2_l = wgl + 2097152;

    for (int li = 0; li < 2; li++) {
        split_weights<<<12288, 256, 0, stream>>>(
            Wq + (size_t)li * DM * DM, Wk + (size_t)li * DM * DM,
            Wv + (size_t)li * DM * DM, Wo + (size_t)li * DM * DM,
            W1 + (size_t)li * DFF * DM, W2 + (size_t)li * DM * DFF, wgh, wgl);
        concat_bias<<<6, 256, 0, stream>>>(bq + (size_t)li * DM, bk + (size_t)li * DM,
                                           bv + (size_t)li * DM, biasqkv);

        const float* bo_i = bo + (size_t)li * DM;
        const float* b1_i = b1 + (size_t)li * DFF;
        const float* b2_i = b2 + (size_t)li * DM;
        const float* g1_i = g1 + (size_t)li * DM;
        const float* be1_i = be1 + (size_t)li * DM;
        const float* g2_i = g2 + (size_t)li * DM;
        const float* be2_i = be2 + (size_t)li * DM;

        // fused QKV: [TOK][1536] fp32
        gemm_split<false, false><<<dim3(QKVLD / 128, TOK / 128), 256, 0, stream>>>(
            h, wqkv_h, wqkv_l, biasqkv, nullptr, big, QKVLD, DM, DM);

        qk_sample_kernel<<<(BATCH * NH * SEQ) / 4, 256, 0, stream>>>(
            big, idx_sample + li * SEQ * NSAMP, Mbuf);
        topk_part<<<dim3(BATCH * NH, 8), 256, 0, stream>>>(Mbuf, cand);
        topk_merge<<<BATCH * NH, 256, 0, stream>>>(cand, idx_top);
        hipMemsetAsync(vmean, 0, BATCH * NH * HD * sizeof(float), stream);
        vmean_kernel<<<dim3(BATCH * NH, 8), 256, 0, stream>>>(big, vmean);
        fillctx_kernel<<<(TOK * DM) / 256, 256, 0, stream>>>(vmean, tmp);
        spattn_flash<<<dim3(BATCH * NH, 4), 256, 0, stream>>>(big, idx_top, opart, mspart);
        spattn_combine<<<BATCH * NH, 256, 0, stream>>>(opart, mspart, idx_top, tmp);

        // Wo with residual into h
        gemm_split<false, true><<<dim3(DM / 128, TOK / 128), 256, 0, stream>>>(
            tmp, wo_h, wo_l, bo_i, h, h, DM, DM, DM);
        ln_kernel<<<TOK, 256, 0, stream>>>(h, g1_i, be1_i, h);

        // FFN full-width
        gemm_split<true, false><<<dim3(DFF / 128, TOK / 128), 256, 0, stream>>>(
            h, w1_h, w1_l, b1_i, nullptr, big, DFF, DM, DM);
        gemm_split<false, true><<<dim3(DM / 128, TOK / 128), 256, 0, stream>>>(
            big, w2_h, w2_l, b2_i, h, tmp, DM, DFF, DFF);
        ln_kernel<<<TOK, 256, 0, stream>>>(tmp, g2_i, be2_i, h);
    }

    ln_kernel<<<TOK, 256, 0, stream>>>(h, g_enc, b_enc, tmp);
    head_kernel<<<BATCH, 256, 0, stream>>>(tmp, W_pre, b_pre, W_fc, b_fc, out);
}

// Round 10
// 1476.806 us; speedup vs baseline: 1.0374x; 1.0374x over previous
//
#include <hip/hip_runtime.h>
#include <math.h>

#define BATCH 8
#define SEQ   2048
#define TOK   (BATCH*SEQ)     // 16384
#define CIN   32
#define DM    512
#define DFF   2048
#define NH    8
#define HD    64
#define NSAMP 24
#define NTOP  24
#define EPS   1e-5f
#define QKVLD 1536

typedef unsigned int u32;
typedef unsigned short u16;
typedef unsigned long long u64;
typedef __attribute__((ext_vector_type(8))) short short8;
typedef __attribute__((ext_vector_type(4))) float floatx4;

__device__ __forceinline__ void async16(const void* g, void* l) {
    __builtin_amdgcn_global_load_lds((const __attribute__((address_space(1))) u32*)g,
                                     (__attribute__((address_space(3))) u32*)l, 16, 0, 0);
}
__device__ __forceinline__ u16 bf16rn(float f) {
    u32 u = __float_as_uint(f);
    return (u16)((u + 0x7fffu + ((u >> 16) & 1u)) >> 16);
}

// ---------------- Threefry-2x32 ----------------
__device__ __forceinline__ void tf_round(unsigned &x0, unsigned &x1, int r) {
    x0 += x1;
    x1 = (x1 << r) | (x1 >> (32 - r));
    x1 ^= x0;
}
__device__ __forceinline__ void threefry(unsigned k0, unsigned k1,
                                         unsigned c0, unsigned c1,
                                         unsigned &o0, unsigned &o1) {
    unsigned ks0 = k0, ks1 = k1, ks2 = k0 ^ k1 ^ 0x1BD11BDAu;
    unsigned x0 = c0 + ks0, x1 = c1 + ks1;
    tf_round(x0,x1,13); tf_round(x0,x1,15); tf_round(x0,x1,26); tf_round(x0,x1,6);
    x0 += ks1; x1 += ks2 + 1u;
    tf_round(x0,x1,17); tf_round(x0,x1,29); tf_round(x0,x1,16); tf_round(x0,x1,24);
    x0 += ks2; x1 += ks0 + 2u;
    tf_round(x0,x1,13); tf_round(x0,x1,15); tf_round(x0,x1,26); tf_round(x0,x1,6);
    x0 += ks0; x1 += ks1 + 3u;
    tf_round(x0,x1,17); tf_round(x0,x1,29); tf_round(x0,x1,16); tf_round(x0,x1,24);
    x0 += ks1; x1 += ks2 + 4u;
    tf_round(x0,x1,13); tf_round(x0,x1,15); tf_round(x0,x1,26); tf_round(x0,x1,6);
    x0 += ks2; x1 += ks0 + 5u;
    o0 = x0; o1 = x1;
}

__global__ void sample_kernel(int* __restrict__ idx_sample) {
    const int HALF = (SEQ * NSAMP) / 2;  // 24576
    int p = blockIdx.x * blockDim.x + threadIdx.x;
    int li = blockIdx.y;
    if (p >= HALF) return;
    unsigned f0, f1;
    threefry(0u, 42u, 0u, (unsigned)li, f0, f1);
    unsigned a0, a1, b0, b1;
    threefry(f0, f1, 0u, 2u, a0, a1);
    threefry(f0, f1, 1u, 3u, b0, b1);
    unsigned o0, o1;
    threefry(a1, b1, (unsigned)p, (unsigned)(p + HALF), o0, o1);
    idx_sample[li * SEQ * NSAMP + p]        = (int)(o0 & (SEQ - 1));
    idx_sample[li * SEQ * NSAMP + p + HALF] = (int)(o1 & (SEQ - 1));
}

// ---------------- input layernorm over C_IN=32 ----------------
__global__ __launch_bounds__(256) void ln_in_kernel(const float* __restrict__ x,
        const float* __restrict__ g, const float* __restrict__ b,
        float* __restrict__ out) {
    int t = blockIdx.x * blockDim.x + threadIdx.x;
    if (t >= TOK) return;
    const float* xr = x + (size_t)t * CIN;
    float vals[CIN];
    float s = 0.f;
#pragma unroll
    for (int c = 0; c < CIN; c++) { vals[c] = xr[c]; s += vals[c]; }
    float m = s * (1.f / CIN);
    float v = 0.f;
#pragma unroll
    for (int c = 0; c < CIN; c++) { float d = vals[c] - m; v += d * d; }
    v *= (1.f / CIN);
    float inv = rsqrtf(v + EPS);
    float* orow = out + (size_t)t * CIN;
#pragma unroll
    for (int c = 0; c < CIN; c++) orow[c] = (vals[c] - m) * inv * g[c] + b[c];
}

// ---------------- im2col (wrap pad), fp32: A[t][j], j=w*32+c ----------------
__global__ __launch_bounds__(128) void im2col_kernel(const float* __restrict__ xln,
        float* __restrict__ a) {
    int t = blockIdx.x;
    int j = threadIdx.x;
    if (j >= 96) return;
    int b = t >> 11, l = t & 2047;
    int w = j >> 5, c = j & 31;
    int lw = (l - 1 + w + SEQ) & 2047;
    a[(size_t)t * 96 + j] = xln[(((size_t)b << 11) | lw) * CIN + c];
}

// ---------------- W_tok transpose + split to interleaved u32: wt[o][j] ----------------
__global__ __launch_bounds__(256) void wtok_split(const float* __restrict__ Wtok,
        u32* __restrict__ wt) {
    int e = blockIdx.x * 256 + threadIdx.x;  // < 49152
    int o = e / 96, j = e % 96;
    float f = Wtok[(size_t)j * DM + o];
    u16 hb = bf16rn(f);
    u16 lb = bf16rn(f - __uint_as_float((u32)hb << 16));
    wt[e] = (u32)hb | ((u32)lb << 16);
}

// ---------------- positional embedding table pe[l][o] ----------------
__global__ __launch_bounds__(256) void pe_kernel(float* __restrict__ pe) {
    int e = blockIdx.x * 256 + threadIdx.x;  // < 1048576
    int l = e >> 9, o = e & 511;
    const float c1 = -0.017988946039016f;  // -ln(10000)/512
    int i2 = o & ~1;
    float div = expf((float)i2 * c1);
    float arg = (float)l * div;
    pe[e] = (o & 1) ? cosf(arg) : sinf(arg);
}

// ---------------- rsd[t][o] = pe[l][o] + tf[t]·Wtime[o] ----------------
__global__ __launch_bounds__(256) void rsd_kernel(const float* __restrict__ pe,
        const float* __restrict__ tfeat, const float* __restrict__ Wtime,
        float* __restrict__ rsd) {
    int t = blockIdx.x, tid = threadIdx.x;
    int l = t & 2047;
    float t0 = tfeat[(size_t)t * 4], t1 = tfeat[(size_t)t * 4 + 1];
    float t2 = tfeat[(size_t)t * 4 + 2], t3 = tfeat[(size_t)t * 4 + 3];
    for (int o = tid; o < DM; o += 256) {
        rsd[(size_t)t * DM + o] = pe[l * DM + o]
            + t0 * Wtime[o * 4] + t1 * Wtime[o * 4 + 1]
            + t2 * Wtime[o * 4 + 2] + t3 * Wtime[o * 4 + 3];
    }
}

// ---------------- weight split: fp32 -> interleaved (bf16_h | bf16_l<<16) ----------------
__global__ __launch_bounds__(256) void split_weights(const float* __restrict__ Wq,
        const float* __restrict__ Wk, const float* __restrict__ Wv,
        const float* __restrict__ Wo, const float* __restrict__ W1,
        const float* __restrict__ W2, u32* __restrict__ out) {
    int i = blockIdx.x * 256 + threadIdx.x;  // < 3145728
    const float* src; int off;
    if (i < 1048576) {
        src = (i < 262144) ? Wq : (i < 524288) ? Wk : (i < 786432) ? Wv : Wo;
        off = i & 262143;
    } else if (i < 2097152) { src = W1; off = i - 1048576; }
    else { src = W2; off = i - 2097152; }
    float f = src[off];
    u16 h = bf16rn(f);
    u16 l = bf16rn(f - __uint_as_float((u32)h << 16));
    out[i] = (u32)h | ((u32)l << 16);
}

__global__ void concat_bias(const float* __restrict__ bq, const float* __restrict__ bk,
                            const float* __restrict__ bv, float* __restrict__ o) {
    int i = blockIdx.x * 256 + threadIdx.x;  // < 1536
    o[i] = (i < 512) ? bq[i] : (i < 1024) ? bk[i - 512] : bv[i - 1024];
}

// ---------------- split-bf16 MFMA GEMM, double-buffered single-barrier K-loop ----------
// C = A[MxK]*W[NxK]^T + bias (+res)(+relu).  A: fp32 split on the fly; Wp: (h|l<<16) u32.
// XCD-aware swizzle: linear%8 = XCD gets a contiguous band of m-tiles so its resident
// blocks share A rows in its L2 (kills the 8x cross-XCD A re-fetch seen in FETCH_SIZE).
template<bool RELU, bool RES>
__global__ __launch_bounds__(256, 2) void gemm_split(const float* __restrict__ A,
        const u32* __restrict__ Wp, const float* __restrict__ bias,
        const float* __restrict__ Rsd, float* __restrict__ C,
        int ldc, int K, int lda) {
    __shared__ alignas(16) u16 AhS[2][128 * 40];   // padded stride 40
    __shared__ alignas(16) u16 AlS[2][128 * 40];
    __shared__ alignas(16) u32 Wt[2][4 * 128 * 8]; // [kchunk8][row][8 words]
    const int tid = threadIdx.x;
    // ---- XCD swizzle (grid.x*grid.y is a multiple of 8 for all our launches) ----
    int linear = blockIdx.y * gridDim.x + blockIdx.x;
    int xcd = linear & 7, sseq = linear >> 3;
    int mper = gridDim.y >> 3;
    int mt = xcd * mper + (sseq % mper);
    int nt = sseq / mper;
    const int m0 = mt * 128, n0 = nt * 128;
    const int lane = tid & 63, wv = tid >> 6;
    const int wm = wv >> 1, wn = wv & 1;
    const int fr = lane & 15, q = lane >> 4;

    floatx4 acc[4][4] = {};

    const int arow = tid >> 1, ahalf = tid & 1;
    const float* abase = A + (size_t)(m0 + arow) * lda + ahalf * 16;
    const u32* wbase = Wp + (size_t)(n0 + (tid >> 1)) * K + (tid & 1) * 4;
    const int wdoff = tid * 16;                 // byte offset in W buf
    const int aoff = arow * 40 + ahalf * 16;

    const int nk = K >> 5;
    float f[16];

    // ---- prologue: stage tile 0 into buf 0, prefetch A tile 1 regs ----
#pragma unroll
    for (int i = 0; i < 4; i++)
        async16(wbase + i * 8, (char*)Wt[0] + wdoff + i * 4096);
    *(float4*)&f[0]  = *(const float4*)(abase);
    *(float4*)&f[4]  = *(const float4*)(abase + 4);
    *(float4*)&f[8]  = *(const float4*)(abase + 8);
    *(float4*)&f[12] = *(const float4*)(abase + 12);
    {
        short8 h0, h1, l0, l1;
#pragma unroll
        for (int j = 0; j < 8; j++) {
            u16 hb = bf16rn(f[j]);
            float r = f[j] - __uint_as_float((u32)hb << 16);
            h0[j] = (short)hb; l0[j] = (short)bf16rn(r);
            u16 hb2 = bf16rn(f[j + 8]);
            float r2 = f[j + 8] - __uint_as_float((u32)hb2 << 16);
            h1[j] = (short)hb2; l1[j] = (short)bf16rn(r2);
        }
        *(short8*)&AhS[0][aoff] = h0;  *(short8*)&AhS[0][aoff + 8] = h1;
        *(short8*)&AlS[0][aoff] = l0;  *(short8*)&AlS[0][aoff + 8] = l1;
    }
    {
        int k1 = (nk > 1) ? 32 : 0;
        const float* ap = abase + k1;
        *(float4*)&f[0]  = *(const float4*)(ap);
        *(float4*)&f[4]  = *(const float4*)(ap + 4);
        *(float4*)&f[8]  = *(const float4*)(ap + 8);
        *(float4*)&f[12] = *(const float4*)(ap + 12);
    }

    for (int k = 0; k < nk; k++) {
        const int b = k & 1;
        __syncthreads();   // buf b staged; drains prev iter's vmem (issued a full MFMA phase ago)
        if (k + 1 < nk) {
            int k0n = (k + 1) << 5;
#pragma unroll
            for (int i = 0; i < 4; i++)
                async16(wbase + k0n + i * 8, (char*)Wt[b ^ 1] + wdoff + i * 4096);
            short8 h0, h1, l0, l1;
#pragma unroll
            for (int j = 0; j < 8; j++) {
                u16 hb = bf16rn(f[j]);
                float r = f[j] - __uint_as_float((u32)hb << 16);
                h0[j] = (short)hb; l0[j] = (short)bf16rn(r);
                u16 hb2 = bf16rn(f[j + 8]);
                float r2 = f[j + 8] - __uint_as_float((u32)hb2 << 16);
                h1[j] = (short)hb2; l1[j] = (short)bf16rn(r2);
            }
            *(short8*)&AhS[b ^ 1][aoff] = h0;  *(short8*)&AhS[b ^ 1][aoff + 8] = h1;
            *(short8*)&AlS[b ^ 1][aoff] = l0;  *(short8*)&AlS[b ^ 1][aoff + 8] = l1;
            int k0nn = (k + 2 < nk) ? ((k + 2) << 5) : 0;
            const float* ap = abase + k0nn;
            *(float4*)&f[0]  = *(const float4*)(ap);
            *(float4*)&f[4]  = *(const float4*)(ap + 4);
            *(float4*)&f[8]  = *(const float4*)(ap + 8);
            *(float4*)&f[12] = *(const float4*)(ap + 12);
        }
        // ---- MFMA on buf b ----
        short8 ah[4], al[4];
#pragma unroll
        for (int mi = 0; mi < 4; mi++) {
            int off = (wm * 64 + mi * 16 + fr) * 40 + q * 8;
            ah[mi] = *(const short8*)&AhS[b][off];
            al[mi] = *(const short8*)&AlS[b][off];
        }
#pragma unroll
        for (int ni = 0; ni < 4; ni++) {
            const u32* cell = &Wt[b][(size_t)(q * 128 + wn * 64 + ni * 16 + fr) * 8];
            union { u32 u[4]; short8 s; } wh, wl;
            u32 w0 = cell[0], w1 = cell[1], w2 = cell[2], w3 = cell[3];
            u32 w4 = cell[4], w5 = cell[5], w6 = cell[6], w7 = cell[7];
            wh.u[0] = (w0 & 0xffffu) | (w1 << 16);
            wh.u[1] = (w2 & 0xffffu) | (w3 << 16);
            wh.u[2] = (w4 & 0xffffu) | (w5 << 16);
            wh.u[3] = (w6 & 0xffffu) | (w7 << 16);
            wl.u[0] = (w0 >> 16) | (w1 & 0xffff0000u);
            wl.u[1] = (w2 >> 16) | (w3 & 0xffff0000u);
            wl.u[2] = (w4 >> 16) | (w5 & 0xffff0000u);
            wl.u[3] = (w6 >> 16) | (w7 & 0xffff0000u);
#pragma unroll
            for (int mi = 0; mi < 4; mi++) {
                acc[mi][ni] = __builtin_amdgcn_mfma_f32_16x16x32_bf16(ah[mi], wh.s, acc[mi][ni], 0, 0, 0);
                acc[mi][ni] = __builtin_amdgcn_mfma_f32_16x16x32_bf16(ah[mi], wl.s, acc[mi][ni], 0, 0, 0);
                acc[mi][ni] = __builtin_amdgcn_mfma_f32_16x16x32_bf16(al[mi], wh.s, acc[mi][ni], 0, 0, 0);
            }
        }
    }
    // --- epilogue ---
#pragma unroll
    for (int ni = 0; ni < 4; ni++) {
        int col = n0 + wn * 64 + ni * 16 + fr;
        float bv = bias[col];
#pragma unroll
        for (int mi = 0; mi < 4; mi++) {
            int row = m0 + wm * 64 + mi * 16 + q * 4;
#pragma unroll
            for (int r = 0; r < 4; r++) {
                size_t idx = (size_t)(row + r) * ldc + col;
                float v = acc[mi][ni][r] + bv;
                if (RES) v += Rsd[idx];
                if (RELU) v = fmaxf(v, 0.f);
                C[idx] = v;
            }
        }
    }
}

// ---------------- M = max(QK_sample) - sum/L : one wave per (b,h,l) ----------------
__global__ __launch_bounds__(256) void qk_sample_kernel(const float* __restrict__ qkv,
        const int* __restrict__ idx_sample, float* __restrict__ Mout) {
    int r = (blockIdx.x * 256 + threadIdx.x) >> 6;
    int lane = threadIdx.x & 63;
    if (r >= BATCH * NH * SEQ) return;
    int b = r / (NH * SEQ);
    int head = (r / SEQ) % NH;
    int l = r % SEQ;
    int sidx = lane >> 4, dc = lane & 15;
    const float* qrow = qkv + ((size_t)(b * SEQ + l)) * QKVLD + head * HD + dc * 4;
    float4 qf = *(const float4*)qrow;
    int myidx = (lane < NSAMP) ? idx_sample[l * NSAMP + lane] : 0;
    const float* kbase = qkv + (size_t)b * SEQ * QKVLD + 512 + head * HD + dc * 4;
    float mx = -INFINITY, sm = 0.f;
#pragma unroll
    for (int p = 0; p < 6; p++) {
        int s = p * 4 + sidx;
        int kidx = __shfl(myidx, s);
        float4 kf = *(const float4*)(kbase + (size_t)kidx * QKVLD);
        float part = qf.x * kf.x + qf.y * kf.y + qf.z * kf.z + qf.w * kf.w;
        part += __shfl_xor(part, 1);
        part += __shfl_xor(part, 2);
        part += __shfl_xor(part, 4);
        part += __shfl_xor(part, 8);
        mx = fmaxf(mx, part);
        sm += part;
    }
    mx = fmaxf(mx, __shfl_xor(mx, 16));
    mx = fmaxf(mx, __shfl_xor(mx, 32));
    sm += __shfl_xor(sm, 16);
    sm += __shfl_xor(sm, 32);
    if (lane == 0) Mout[r] = mx - sm * (1.f / SEQ);
}

// ---------------- top-24 two-stage: packed u64 keys, exact (idx unique) ----------------
__device__ __forceinline__ u64 pack_key(float v, int idx) {
    u32 u = __float_as_uint(v);
    u32 m = (u & 0x80000000u) ? ~u : (u | 0x80000000u);
    return ((u64)m << 32) | (u32)(~(u32)idx);
}

__global__ __launch_bounds__(256) void topk_part(const float* __restrict__ Mbuf,
        u64* __restrict__ cand) {
    __shared__ u64 vals[256];
    __shared__ u64 red[256];
    int bh = blockIdx.x, chunk = blockIdx.y;
    int tid = threadIdx.x;
    int l = chunk * 256 + tid;
    vals[tid] = pack_key(Mbuf[(size_t)bh * SEQ + l], l);
    __syncthreads();
    for (int it = 0; it < NTOP; it++) {
        red[tid] = vals[tid];
        __syncthreads();
        for (int s = 128; s > 0; s >>= 1) {
            if (tid < s) { u64 o = red[tid + s]; if (o > red[tid]) red[tid] = o; }
            __syncthreads();
        }
        u64 win = red[0];
        if (vals[tid] == win) vals[tid] = 0;
        if (tid == 0) cand[((size_t)bh * 8 + chunk) * NTOP + it] = win;
        __syncthreads();
    }
}

__global__ __launch_bounds__(256) void topk_merge(const u64* __restrict__ cand,
        int* __restrict__ idx_top) {
    __shared__ u64 vals[256];
    __shared__ u64 red[256];
    int bh = blockIdx.x;
    int tid = threadIdx.x;
    vals[tid] = (tid < 8 * NTOP) ? cand[(size_t)bh * 8 * NTOP + tid] : 0;
    __syncthreads();
    for (int it = 0; it < NTOP; it++) {
        red[tid] = vals[tid];
        __syncthreads();
        for (int s = 128; s > 0; s >>= 1) {
            if (tid < s) { u64 o = red[tid + s]; if (o > red[tid]) red[tid] = o; }
            __syncthreads();
        }
        u64 win = red[0];
        if (vals[tid] == win) vals[tid] = 0;
        if (tid == 0) idx_top[bh * NTOP + it] = (int)(~(u32)(win & 0xffffffffull) & (SEQ - 1));
        __syncthreads();
    }
}

// ---------------- V mean over keys per (b,h) ----------------
__global__ __launch_bounds__(256) void vmean_kernel(const float* __restrict__ qkv,
        float* __restrict__ vmean) {
    __shared__ float red[256];
    int bh = blockIdx.x, slab = blockIdx.y;
    int b = bh >> 3, head = bh & 7;
    int seg = threadIdx.x >> 6, d = threadIdx.x & 63;
    int base_row = slab * 256 + seg * 64;
    float s = 0.f;
    for (int r = 0; r < 64; r++)
        s += qkv[((size_t)(b * SEQ + base_row + r)) * QKVLD + 1024 + head * HD + d];
    red[threadIdx.x] = s;
    __syncthreads();
    if (threadIdx.x < 128) red[threadIdx.x] += red[threadIdx.x + 128];
    __syncthreads();
    if (threadIdx.x < 64) {
        float t = red[threadIdx.x] + red[threadIdx.x + 64];
        atomicAdd(&vmean[bh * HD + d], t * (1.f / SEQ));
    }
}

// ---------------- fill context with V-mean ----------------
__global__ void fillctx_kernel(const float* __restrict__ vmean, float* __restrict__ out) {
    int e = blockIdx.x * 256 + threadIdx.x;
    int c = e & 511;
    int b = e >> 20;
    out[e] = vmean[(((b << 3) | (c >> 6)) << 6) + (c & 63)];
}

// ---------------- flash-style sparse attention: block = (b*h, key-slab of 512) ----------------
__global__ __launch_bounds__(256) void spattn_flash(const float* __restrict__ qkv,
        const int* __restrict__ idx_top, float* __restrict__ opart,
        float* __restrict__ mspart) {
    __shared__ float KtT[64][65];   // transposed: [dim][key]
    __shared__ float Vt[64][65];    // [key][dim]
    __shared__ float Qs[24][64];
    __shared__ float Ps[24][66];
    int bh = blockIdx.x, slab = blockIdx.y;
    int b = bh >> 3, h = bh & 7;
    int tid = threadIdx.x;
    int wv = tid >> 6, lane = tid & 63;
    for (int i = tid; i < NTOP * 64; i += 256) {
        int u = i >> 6, d = i & 63;
        int qi = idx_top[bh * NTOP + u];
        Qs[u][d] = qkv[((size_t)(b * SEQ + qi)) * QKVLD + h * HD + d];
    }
    float m[6], s[6], o[6], alpha[6];
#pragma unroll
    for (int j = 0; j < 6; j++) { m[j] = -INFINITY; s[j] = 0.f; o[j] = 0.f; }
    int key0 = slab * 512;
    int sr = tid >> 2, sc0 = (tid & 3) * 16;
    for (int t = 0; t < 8; t++) {
        int kbase = key0 + t * 64;
        __syncthreads();
        const float* kr = qkv + ((size_t)(b * SEQ + kbase + sr)) * QKVLD + 512 + h * HD + sc0;
        const float* vr = qkv + ((size_t)(b * SEQ + kbase + sr)) * QKVLD + 1024 + h * HD + sc0;
        float kf[16], vf[16];
        *(float4*)&kf[0]  = *(const float4*)(kr);
        *(float4*)&kf[4]  = *(const float4*)(kr + 4);
        *(float4*)&kf[8]  = *(const float4*)(kr + 8);
        *(float4*)&kf[12] = *(const float4*)(kr + 12);
        *(float4*)&vf[0]  = *(const float4*)(vr);
        *(float4*)&vf[4]  = *(const float4*)(vr + 4);
        *(float4*)&vf[8]  = *(const float4*)(vr + 8);
        *(float4*)&vf[12] = *(const float4*)(vr + 12);
#pragma unroll
        for (int i = 0; i < 16; i++) {
            KtT[sc0 + i][sr] = kf[i];
            Vt[sr][sc0 + i] = vf[i];
        }
        __syncthreads();
        float dot[6] = {};
#pragma unroll
        for (int d = 0; d < 64; d++) {
            float kv = KtT[d][lane];
#pragma unroll
            for (int j = 0; j < 6; j++) dot[j] += Qs[wv * 6 + j][d] * kv;
        }
#pragma unroll
        for (int j = 0; j < 6; j++) {
            float sc = dot[j] * 0.125f;
            float tmax = sc;
            for (int off = 32; off > 0; off >>= 1) tmax = fmaxf(tmax, __shfl_xor(tmax, off));
            float mn = fmaxf(m[j], tmax);
            float p = __expf(sc - mn);
            float psum = p;
            for (int off = 32; off > 0; off >>= 1) psum += __shfl_xor(psum, off);
            alpha[j] = __expf(m[j] - mn);
            s[j] = s[j] * alpha[j] + psum;
            m[j] = mn;
            Ps[wv * 6 + j][lane] = p;
        }
        float pv[6] = {};
#pragma unroll
        for (int key = 0; key < 64; key++) {
            float vvv = Vt[key][lane];
#pragma unroll
            for (int j = 0; j < 6; j++) pv[j] += Ps[wv * 6 + j][key] * vvv;
        }
#pragma unroll
        for (int j = 0; j < 6; j++) o[j] = o[j] * alpha[j] + pv[j];
    }
    float* ob = opart + ((size_t)(bh * 4 + slab)) * NTOP * 64;
#pragma unroll
    for (int j = 0; j < 6; j++) ob[(wv * 6 + j) * 64 + lane] = o[j];
    if (lane == 0) {
        float* ms = mspart + ((size_t)(bh * 4 + slab)) * NTOP * 2;
#pragma unroll
        for (int j = 0; j < 6; j++) {
            ms[(wv * 6 + j) * 2]     = m[j];
            ms[(wv * 6 + j) * 2 + 1] = s[j];
        }
    }
}

// ---------------- merge 4 slab partials, scatter into context ----------------
__global__ __launch_bounds__(256) void spattn_combine(const float* __restrict__ opart,
        const float* __restrict__ mspart, const int* __restrict__ idx_top,
        float* __restrict__ out) {
    __shared__ float wgt[4][NTOP];
    int bh = blockIdx.x;
    int b = bh >> 3, h = bh & 7;
    int tid = threadIdx.x;
    if (tid < NTOP) {
        float mv[4], sv[4];
        float M = -INFINITY;
#pragma unroll
        for (int sl = 0; sl < 4; sl++) {
            mv[sl] = mspart[((size_t)(bh * 4 + sl)) * NTOP * 2 + tid * 2];
            sv[sl] = mspart[((size_t)(bh * 4 + sl)) * NTOP * 2 + tid * 2 + 1];
            M = fmaxf(M, mv[sl]);
        }
        float S = 0.f;
#pragma unroll
        for (int sl = 0; sl < 4; sl++) S += sv[sl] * __expf(mv[sl] - M);
        float invS = 1.f / S;
#pragma unroll
        for (int sl = 0; sl < 4; sl++) wgt[sl][tid] = __expf(mv[sl] - M) * invS;
    }
    __syncthreads();
    for (int i = tid; i < NTOP * 64; i += 256) {
        int u = i >> 6, d = i & 63;
        float val = 0.f;
#pragma unroll
        for (int sl = 0; sl < 4; sl++)
            val += wgt[sl][u] * opart[(((size_t)(bh * 4 + sl)) * NTOP + u) * 64 + d];
        int qi = idx_top[bh * NTOP + u];
        out[((size_t)(b * SEQ + qi)) * DM + h * HD + d] = val;
    }
}

// ---------------- layernorm over DM=512 ----------------
__global__ __launch_bounds__(256) void ln_kernel(const float* src,
        const float* __restrict__ g, const float* __restrict__ b, float* dst) {
    __shared__ float red[256];
    int t = blockIdx.x, tid = threadIdx.x;
    const float* xr = src + (size_t)t * DM;
    float x0 = xr[tid], x1 = xr[tid + 256];
    red[tid] = x0 + x1; __syncthreads();
    for (int s = 128; s > 0; s >>= 1) { if (tid < s) red[tid] += red[tid + s]; __syncthreads(); }
    float m = red[0] * (1.f / DM);
    __syncthreads();
    float d0 = x0 - m, d1 = x1 - m;
    red[tid] = d0 * d0 + d1 * d1; __syncthreads();
    for (int s = 128; s > 0; s >>= 1) { if (tid < s) red[tid] += red[tid + s]; __syncthreads(); }
    float inv = rsqrtf(red[0] * (1.f / DM) + EPS);
    float* dr = dst + (size_t)t * DM;
    dr[tid] = d0 * inv * g[tid] + b[tid];
    dr[tid + 256] = d1 * inv * g[tid + 256] + b[tid + 256];
}

// ---------------- prediction head on last token ----------------
__global__ __launch_bounds__(256) void head_kernel(const float* __restrict__ hfin,
        const float* __restrict__ Wpre, const float* __restrict__ bpre,
        const float* __restrict__ Wfc, const float* __restrict__ bfc,
        float* __restrict__ out) {
    __shared__ float last[DM];
    __shared__ float red[256];
    int b = blockIdx.x, tid = threadIdx.x;
    const float* hr = hfin + ((size_t)(b * SEQ + SEQ - 1)) * DM;
    last[tid] = hr[tid];
    last[tid + 256] = hr[tid + 256];
    __syncthreads();
    float acc = bpre[tid];
    for (int c = 0; c < DM; c++) acc += last[c] * Wpre[tid * DM + c];
    acc = fmaxf(acc, 0.f);
    red[tid] = acc * Wfc[tid];
    __syncthreads();
    for (int s = 128; s > 0; s >>= 1) { if (tid < s) red[tid] += red[tid + s]; __syncthreads(); }
    if (tid == 0) out[b] = red[0] + bfc[0];
}

extern "C" void kernel_launch(void* const* d_in, const int* in_sizes, int n_in,
                              void* d_out, int out_size, void* d_ws, size_t ws_size,
                              hipStream_t stream) {
    (void)in_sizes; (void)n_in; (void)out_size; (void)ws_size;
    const float* x      = (const float*)d_in[0];
    const float* tfeat  = (const float*)d_in[1];
    const float* g_in   = (const float*)d_in[2];
    const float* b_in   = (const float*)d_in[3];
    const float* W_tok  = (const float*)d_in[4];
    const float* W_time = (const float*)d_in[5];
    const float* b_time = (const float*)d_in[6];
    const float* Wq     = (const float*)d_in[7];
    const float* bq     = (const float*)d_in[8];
    const float* Wk     = (const float*)d_in[9];
    const float* bk     = (const float*)d_in[10];
    const float* Wv     = (const float*)d_in[11];
    const float* bv     = (const float*)d_in[12];
    const float* Wo     = (const float*)d_in[13];
    const float* bo     = (const float*)d_in[14];
    const float* W1     = (const float*)d_in[15];
    const float* b1     = (const float*)d_in[16];
    const float* W2     = (const float*)d_in[17];
    const float* b2     = (const float*)d_in[18];
    const float* g1     = (const float*)d_in[19];
    const float* be1    = (const float*)d_in[20];
    const float* g2     = (const float*)d_in[21];
    const float* be2    = (const float*)d_in[22];
    const float* g_enc  = (const float*)d_in[23];
    const float* b_enc  = (const float*)d_in[24];
    const float* W_pre  = (const float*)d_in[25];
    const float* b_pre  = (const float*)d_in[26];
    const float* W_fc   = (const float*)d_in[27];
    const float* b_fc   = (const float*)d_in[28];
    float* out = (float*)d_out;

    char* ws = (char*)d_ws;
    float* h    = (float*)(ws);                      // 33.5 MB fp32 residual
    float* tmp  = (float*)(ws + 33554432);           // 33.5 MB fp32
    char*  bigc = ws + 67108864;                     // 134.2 MB multi-use
    float* big  = (float*)bigc;                      // qkv [TOK][1536] fp32 / FFN mid
    // embed-stage overlays inside big:
    float* xln  = (float*)(bigc);                    // 2 MB
    float* acv  = (float*)(bigc + 2097152);          // im2col [TOK][96] fp32, 6.3 MB
    float* pe   = (float*)(bigc + 8388608);          // 4 MB
    float* rsd  = (float*)(bigc + 12582912);         // 33.5 MB
    u32*   wtok = (u32*)(bigc + 46137344);           // W_tok interleaved [512][96]
    u32*   wpair      = (u32*)(ws + 201326592);      // 12.6 MB per-layer weights
    float* Mbuf       = (float*)(ws + 213909504);    // 0.5 MB
    float* vmean      = (float*)(ws + 214433792);
    int*   idx_sample = (int*)(ws + 214450176);
    int*   idx_top    = (int*)(ws + 214843392);
    float* biasqkv    = (float*)(ws + 214849536);
    u64*   cand       = (u64*)(ws + 214855680);      // 98 KB
    float* opart      = (float*)(ws + 214953984);    // 1.57 MB
    float* mspart     = (float*)(ws + 216526848);    // 48 KB

    ln_in_kernel<<<TOK / 256, 256, 0, stream>>>(x, g_in, b_in, xln);
    im2col_kernel<<<TOK, 128, 0, stream>>>(xln, acv);
    wtok_split<<<192, 256, 0, stream>>>(W_tok, wtok);
    pe_kernel<<<4096, 256, 0, stream>>>(pe);
    rsd_kernel<<<TOK, 256, 0, stream>>>(pe, tfeat, W_time, rsd);
    sample_kernel<<<dim3(96, 2), 256, 0, stream>>>(idx_sample);

    // conv-as-GEMM: h = im2col @ W_tok^T + b_time + (pe + time emb)
    gemm_split<false, true><<<dim3(4, 128), 256, 0, stream>>>(
        acv, wtok, b_time, rsd, h, DM, 96, 96);

    const u32* wqkv_p = wpair;                // rows 0..1535 = Wq;Wk;Wv
    const u32* wo_p = wpair + 786432;
    const u32* w1_p = wpair + 1048576;
    const u32* w2_p = wpair + 2097152;

    for (int li = 0; li < 2; li++) {
        split_weights<<<12288, 256, 0, stream>>>(
            Wq + (size_t)li * DM * DM, Wk + (size_t)li * DM * DM,
            Wv + (size_t)li * DM * DM, Wo + (size_t)li * DM * DM,
            W1 + (size_t)li * DFF * DM, W2 + (size_t)li * DM * DFF, wpair);
        concat_bias<<<6, 256, 0, stream>>>(bq + (size_t)li * DM, bk + (size_t)li * DM,
                                           bv + (size_t)li * DM, biasqkv);

        const float* bo_i = bo + (size_t)li * DM;
        const float* b1_i = b1 + (size_t)li * DFF;
        const float* b2_i = b2 + (size_t)li * DM;
        const float* g1_i = g1 + (size_t)li * DM;
        const float* be1_i = be1 + (size_t)li * DM;
        const float* g2_i = g2 + (size_t)li * DM;
        const float* be2_i = be2 + (size_t)li * DM;

        // fused QKV: [TOK][1536] fp32
        gemm_split<false, false><<<dim3(QKVLD / 128, TOK / 128), 256, 0, stream>>>(
            h, wqkv_p, biasqkv, nullptr, big, QKVLD, DM, DM);

        qk_sample_kernel<<<(BATCH * NH * SEQ) / 4, 256, 0, stream>>>(
            big, idx_sample + li * SEQ * NSAMP, Mbuf);
        topk_part<<<dim3(BATCH * NH, 8), 256, 0, stream>>>(Mbuf, cand);
        topk_merge<<<BATCH * NH, 256, 0, stream>>>(cand, idx_top);
        hipMemsetAsync(vmean, 0, BATCH * NH * HD * sizeof(float), stream);
        vmean_kernel<<<dim3(BATCH * NH, 8), 256, 0, stream>>>(big, vmean);
        fillctx_kernel<<<(TOK * DM) / 256, 256, 0, stream>>>(vmean, tmp);
        spattn_flash<<<dim3(BATCH * NH, 4), 256, 0, stream>>>(big, idx_top, opart, mspart);
        spattn_combine<<<BATCH * NH, 256, 0, stream>>>(opart, mspart, idx_top, tmp);

        // Wo with residual into h
        gemm_split<false, true><<<dim3(DM / 128, TOK / 128), 256, 0, stream>>>(
            tmp, wo_p, bo_i, h, h, DM, DM, DM);
        ln_kernel<<<TOK, 256, 0, stream>>>(h, g1_i, be1_i, h);

        // FFN full-width
        gemm_split<true, false><<<dim3(DFF / 128, TOK / 128), 256, 0, stream>>>(
            h, w1_p, b1_i, nullptr, big, DFF, DM, DM);
        gemm_split<false, true><<<dim3(DM / 128, TOK / 128), 256, 0, stream>>>(
            big, w2_p, b2_i, h, tmp, DM, DFF, DFF);
        ln_kernel<<<TOK, 256, 0, stream>>>(tmp, g2_i, be2_i, h);
    }

    ln_kernel<<<TOK, 256, 0, stream>>>(h, g_enc, b_enc, tmp);
    head_kernel<<<BATCH, 256, 0, stream>>>(tmp, W_pre, b_pre, W_fc, b_fc, out);
}

// Round 11
// 1405.723 us; speedup vs baseline: 1.0899x; 1.0506x over previous
//
#include <hip/hip_runtime.h>
#include <math.h>

#define BATCH 8
#define SEQ   2048
#define TOK   (BATCH*SEQ)     // 16384
#define CIN   32
#define DM    512
#define DFF   2048
#define NH    8
#define HD    64
#define NSAMP 24
#define NTOP  24
#define EPS   1e-5f
#define QKVLD 1536

typedef unsigned int u32;
typedef unsigned short u16;
typedef unsigned long long u64;
typedef __attribute__((ext_vector_type(8))) short short8;
typedef __attribute__((ext_vector_type(4))) float floatx4;

__device__ __forceinline__ void async16(const void* g, void* l) {
    __builtin_amdgcn_global_load_lds((const __attribute__((address_space(1))) u32*)g,
                                     (__attribute__((address_space(3))) u32*)l, 16, 0, 0);
}
__device__ __forceinline__ u16 bf16rn(float f) {
    u32 u = __float_as_uint(f);
    return (u16)((u + 0x7fffu + ((u >> 16) & 1u)) >> 16);
}

// ---------------- Threefry-2x32 ----------------
__device__ __forceinline__ void tf_round(unsigned &x0, unsigned &x1, int r) {
    x0 += x1;
    x1 = (x1 << r) | (x1 >> (32 - r));
    x1 ^= x0;
}
__device__ __forceinline__ void threefry(unsigned k0, unsigned k1,
                                         unsigned c0, unsigned c1,
                                         unsigned &o0, unsigned &o1) {
    unsigned ks0 = k0, ks1 = k1, ks2 = k0 ^ k1 ^ 0x1BD11BDAu;
    unsigned x0 = c0 + ks0, x1 = c1 + ks1;
    tf_round(x0,x1,13); tf_round(x0,x1,15); tf_round(x0,x1,26); tf_round(x0,x1,6);
    x0 += ks1; x1 += ks2 + 1u;
    tf_round(x0,x1,17); tf_round(x0,x1,29); tf_round(x0,x1,16); tf_round(x0,x1,24);
    x0 += ks2; x1 += ks0 + 2u;
    tf_round(x0,x1,13); tf_round(x0,x1,15); tf_round(x0,x1,26); tf_round(x0,x1,6);
    x0 += ks0; x1 += ks1 + 3u;
    tf_round(x0,x1,17); tf_round(x0,x1,29); tf_round(x0,x1,16); tf_round(x0,x1,24);
    x0 += ks1; x1 += ks2 + 4u;
    tf_round(x0,x1,13); tf_round(x0,x1,15); tf_round(x0,x1,26); tf_round(x0,x1,6);
    x0 += ks2; x1 += ks0 + 5u;
    o0 = x0; o1 = x1;
}

__global__ void sample_kernel(int* __restrict__ idx_sample) {
    const int HALF = (SEQ * NSAMP) / 2;  // 24576
    int p = blockIdx.x * blockDim.x + threadIdx.x;
    int li = blockIdx.y;
    if (p >= HALF) return;
    unsigned f0, f1;
    threefry(0u, 42u, 0u, (unsigned)li, f0, f1);
    unsigned a0, a1, b0, b1;
    threefry(f0, f1, 0u, 2u, a0, a1);
    threefry(f0, f1, 1u, 3u, b0, b1);
    unsigned o0, o1;
    threefry(a1, b1, (unsigned)p, (unsigned)(p + HALF), o0, o1);
    idx_sample[li * SEQ * NSAMP + p]        = (int)(o0 & (SEQ - 1));
    idx_sample[li * SEQ * NSAMP + p + HALF] = (int)(o1 & (SEQ - 1));
}

// ---------------- input layernorm over C_IN=32 ----------------
__global__ __launch_bounds__(256) void ln_in_kernel(const float* __restrict__ x,
        const float* __restrict__ g, const float* __restrict__ b,
        float* __restrict__ out) {
    int t = blockIdx.x * blockDim.x + threadIdx.x;
    if (t >= TOK) return;
    const float* xr = x + (size_t)t * CIN;
    float vals[CIN];
    float s = 0.f;
#pragma unroll
    for (int c = 0; c < CIN; c++) { vals[c] = xr[c]; s += vals[c]; }
    float m = s * (1.f / CIN);
    float v = 0.f;
#pragma unroll
    for (int c = 0; c < CIN; c++) { float d = vals[c] - m; v += d * d; }
    v *= (1.f / CIN);
    float inv = rsqrtf(v + EPS);
    float* orow = out + (size_t)t * CIN;
#pragma unroll
    for (int c = 0; c < CIN; c++) orow[c] = (vals[c] - m) * inv * g[c] + b[c];
}

// ---------------- im2col (wrap pad), fp32: A[t][j], j=w*32+c ----------------
__global__ __launch_bounds__(128) void im2col_kernel(const float* __restrict__ xln,
        float* __restrict__ a) {
    int t = blockIdx.x;
    int j = threadIdx.x;
    if (j >= 96) return;
    int b = t >> 11, l = t & 2047;
    int w = j >> 5, c = j & 31;
    int lw = (l - 1 + w + SEQ) & 2047;
    a[(size_t)t * 96 + j] = xln[(((size_t)b << 11) | lw) * CIN + c];
}

// ---------------- W_tok transpose + split to interleaved u32: wt[o][j] ----------------
__global__ __launch_bounds__(256) void wtok_split(const float* __restrict__ Wtok,
        u32* __restrict__ wt) {
    int e = blockIdx.x * 256 + threadIdx.x;  // < 49152
    int o = e / 96, j = e % 96;
    float f = Wtok[(size_t)j * DM + o];
    u16 hb = bf16rn(f);
    u16 lb = bf16rn(f - __uint_as_float((u32)hb << 16));
    wt[e] = (u32)hb | ((u32)lb << 16);
}

// ---------------- positional embedding table pe[l][o] ----------------
__global__ __launch_bounds__(256) void pe_kernel(float* __restrict__ pe) {
    int e = blockIdx.x * 256 + threadIdx.x;  // < 1048576
    int l = e >> 9, o = e & 511;
    const float c1 = -0.017988946039016f;  // -ln(10000)/512
    int i2 = o & ~1;
    float div = expf((float)i2 * c1);
    float arg = (float)l * div;
    pe[e] = (o & 1) ? cosf(arg) : sinf(arg);
}

// ---------------- rsd[t][o] = pe[l][o] + tf[t]·Wtime[o] ----------------
__global__ __launch_bounds__(256) void rsd_kernel(const float* __restrict__ pe,
        const float* __restrict__ tfeat, const float* __restrict__ Wtime,
        float* __restrict__ rsd) {
    int t = blockIdx.x, tid = threadIdx.x;
    int l = t & 2047;
    float t0 = tfeat[(size_t)t * 4], t1 = tfeat[(size_t)t * 4 + 1];
    float t2 = tfeat[(size_t)t * 4 + 2], t3 = tfeat[(size_t)t * 4 + 3];
    for (int o = tid; o < DM; o += 256) {
        rsd[(size_t)t * DM + o] = pe[l * DM + o]
            + t0 * Wtime[o * 4] + t1 * Wtime[o * 4 + 1]
            + t2 * Wtime[o * 4 + 2] + t3 * Wtime[o * 4 + 3];
    }
}

// ---------------- weight split: fp32 -> interleaved (bf16_h | bf16_l<<16) ----------------
__global__ __launch_bounds__(256) void split_weights(const float* __restrict__ Wq,
        const float* __restrict__ Wk, const float* __restrict__ Wv,
        const float* __restrict__ Wo, const float* __restrict__ W1,
        const float* __restrict__ W2, u32* __restrict__ out) {
    int i = blockIdx.x * 256 + threadIdx.x;  // < 3145728
    const float* src; int off;
    if (i < 1048576) {
        src = (i < 262144) ? Wq : (i < 524288) ? Wk : (i < 786432) ? Wv : Wo;
        off = i & 262143;
    } else if (i < 2097152) { src = W1; off = i - 1048576; }
    else { src = W2; off = i - 2097152; }
    float f = src[off];
    u16 h = bf16rn(f);
    u16 l = bf16rn(f - __uint_as_float((u32)h << 16));
    out[i] = (u32)h | ((u32)l << 16);
}

__global__ void concat_bias(const float* __restrict__ bq, const float* __restrict__ bk,
                            const float* __restrict__ bv, float* __restrict__ o) {
    int i = blockIdx.x * 256 + threadIdx.x;  // < 1536
    o[i] = (i < 512) ? bq[i] : (i < 1024) ? bk[i - 512] : bv[i - 1024];
}

// ---------------- split-bf16 MFMA GEMM, double-buffered single-barrier K-loop ----------
// C = A[MxK]*W[NxK]^T + bias (+res)(+relu).  A: fp32 split on the fly; Wp: (h|l<<16) u32.
// XCD-aware swizzle: linear%8 = XCD gets a contiguous band of m-tiles (FETCH 288->96MB).
template<bool RELU, bool RES>
__global__ __launch_bounds__(256, 2) void gemm_split(const float* __restrict__ A,
        const u32* __restrict__ Wp, const float* __restrict__ bias,
        const float* __restrict__ Rsd, float* __restrict__ C,
        int ldc, int K, int lda) {
    __shared__ alignas(16) u16 AhS[2][128 * 40];   // padded stride 40
    __shared__ alignas(16) u16 AlS[2][128 * 40];
    __shared__ alignas(16) u32 Wt[2][4 * 128 * 8]; // [kchunk8][row][8 words]
    const int tid = threadIdx.x;
    int linear = blockIdx.y * gridDim.x + blockIdx.x;
    int xcd = linear & 7, sseq = linear >> 3;
    int mper = gridDim.y >> 3;
    int mt = xcd * mper + (sseq % mper);
    int nt = sseq / mper;
    const int m0 = mt * 128, n0 = nt * 128;
    const int lane = tid & 63, wv = tid >> 6;
    const int wm = wv >> 1, wn = wv & 1;
    const int fr = lane & 15, q = lane >> 4;

    floatx4 acc[4][4] = {};

    const int arow = tid >> 1, ahalf = tid & 1;
    const float* abase = A + (size_t)(m0 + arow) * lda + ahalf * 16;
    const u32* wbase = Wp + (size_t)(n0 + (tid >> 1)) * K + (tid & 1) * 4;
    const int wdoff = tid * 16;                 // byte offset in W buf
    const int aoff = arow * 40 + ahalf * 16;

    const int nk = K >> 5;
    float f[16];

    // ---- prologue: stage tile 0 into buf 0, prefetch A tile 1 regs ----
#pragma unroll
    for (int i = 0; i < 4; i++)
        async16(wbase + i * 8, (char*)Wt[0] + wdoff + i * 4096);
    *(float4*)&f[0]  = *(const float4*)(abase);
    *(float4*)&f[4]  = *(const float4*)(abase + 4);
    *(float4*)&f[8]  = *(const float4*)(abase + 8);
    *(float4*)&f[12] = *(const float4*)(abase + 12);
    {
        short8 h0, h1, l0, l1;
#pragma unroll
        for (int j = 0; j < 8; j++) {
            u16 hb = bf16rn(f[j]);
            float r = f[j] - __uint_as_float((u32)hb << 16);
            h0[j] = (short)hb; l0[j] = (short)bf16rn(r);
            u16 hb2 = bf16rn(f[j + 8]);
            float r2 = f[j + 8] - __uint_as_float((u32)hb2 << 16);
            h1[j] = (short)hb2; l1[j] = (short)bf16rn(r2);
        }
        *(short8*)&AhS[0][aoff] = h0;  *(short8*)&AhS[0][aoff + 8] = h1;
        *(short8*)&AlS[0][aoff] = l0;  *(short8*)&AlS[0][aoff + 8] = l1;
    }
    {
        int k1 = (nk > 1) ? 32 : 0;
        const float* ap = abase + k1;
        *(float4*)&f[0]  = *(const float4*)(ap);
        *(float4*)&f[4]  = *(const float4*)(ap + 4);
        *(float4*)&f[8]  = *(const float4*)(ap + 8);
        *(float4*)&f[12] = *(const float4*)(ap + 12);
    }

    for (int k = 0; k < nk; k++) {
        const int b = k & 1;
        __syncthreads();   // buf b staged; drains prev iter's vmem (issued a full MFMA phase ago)
        if (k + 1 < nk) {
            int k0n = (k + 1) << 5;
#pragma unroll
            for (int i = 0; i < 4; i++)
                async16(wbase + k0n + i * 8, (char*)Wt[b ^ 1] + wdoff + i * 4096);
            short8 h0, h1, l0, l1;
#pragma unroll
            for (int j = 0; j < 8; j++) {
                u16 hb = bf16rn(f[j]);
                float r = f[j] - __uint_as_float((u32)hb << 16);
                h0[j] = (short)hb; l0[j] = (short)bf16rn(r);
                u16 hb2 = bf16rn(f[j + 8]);
                float r2 = f[j + 8] - __uint_as_float((u32)hb2 << 16);
                h1[j] = (short)hb2; l1[j] = (short)bf16rn(r2);
            }
            *(short8*)&AhS[b ^ 1][aoff] = h0;  *(short8*)&AhS[b ^ 1][aoff + 8] = h1;
            *(short8*)&AlS[b ^ 1][aoff] = l0;  *(short8*)&AlS[b ^ 1][aoff + 8] = l1;
            int k0nn = (k + 2 < nk) ? ((k + 2) << 5) : 0;
            const float* ap = abase + k0nn;
            *(float4*)&f[0]  = *(const float4*)(ap);
            *(float4*)&f[4]  = *(const float4*)(ap + 4);
            *(float4*)&f[8]  = *(const float4*)(ap + 8);
            *(float4*)&f[12] = *(const float4*)(ap + 12);
        }
        // ---- MFMA on buf b ----
        short8 ah[4], al[4];
#pragma unroll
        for (int mi = 0; mi < 4; mi++) {
            int off = (wm * 64 + mi * 16 + fr) * 40 + q * 8;
            ah[mi] = *(const short8*)&AhS[b][off];
            al[mi] = *(const short8*)&AlS[b][off];
        }
#pragma unroll
        for (int ni = 0; ni < 4; ni++) {
            const u32* cell = &Wt[b][(size_t)(q * 128 + wn * 64 + ni * 16 + fr) * 8];
            union { u32 u[4]; short8 s; } wh, wl;
            u32 w0 = cell[0], w1 = cell[1], w2 = cell[2], w3 = cell[3];
            u32 w4 = cell[4], w5 = cell[5], w6 = cell[6], w7 = cell[7];
            wh.u[0] = (w0 & 0xffffu) | (w1 << 16);
            wh.u[1] = (w2 & 0xffffu) | (w3 << 16);
            wh.u[2] = (w4 & 0xffffu) | (w5 << 16);
            wh.u[3] = (w6 & 0xffffu) | (w7 << 16);
            wl.u[0] = (w0 >> 16) | (w1 & 0xffff0000u);
            wl.u[1] = (w2 >> 16) | (w3 & 0xffff0000u);
            wl.u[2] = (w4 >> 16) | (w5 & 0xffff0000u);
            wl.u[3] = (w6 >> 16) | (w7 & 0xffff0000u);
#pragma unroll
            for (int mi = 0; mi < 4; mi++) {
                acc[mi][ni] = __builtin_amdgcn_mfma_f32_16x16x32_bf16(ah[mi], wh.s, acc[mi][ni], 0, 0, 0);
                acc[mi][ni] = __builtin_amdgcn_mfma_f32_16x16x32_bf16(ah[mi], wl.s, acc[mi][ni], 0, 0, 0);
                acc[mi][ni] = __builtin_amdgcn_mfma_f32_16x16x32_bf16(al[mi], wh.s, acc[mi][ni], 0, 0, 0);
            }
        }
    }
    // --- epilogue ---
#pragma unroll
    for (int ni = 0; ni < 4; ni++) {
        int col = n0 + wn * 64 + ni * 16 + fr;
        float bv = bias[col];
#pragma unroll
        for (int mi = 0; mi < 4; mi++) {
            int row = m0 + wm * 64 + mi * 16 + q * 4;
#pragma unroll
            for (int r = 0; r < 4; r++) {
                size_t idx = (size_t)(row + r) * ldc + col;
                float v = acc[mi][ni][r] + bv;
                if (RES) v += Rsd[idx];
                if (RELU) v = fmaxf(v, 0.f);
                C[idx] = v;
            }
        }
    }
}

// ---------------- M = max(QK_sample) - sum/L : one wave per (b,h,l) ----------------
// All 6 gathers issued before any reduction (overlapped L2 latency).
__global__ __launch_bounds__(256) void qk_sample_kernel(const float* __restrict__ qkv,
        const int* __restrict__ idx_sample, float* __restrict__ Mout) {
    int r = (blockIdx.x * 256 + threadIdx.x) >> 6;
    int lane = threadIdx.x & 63;
    if (r >= BATCH * NH * SEQ) return;
    int b = r / (NH * SEQ);
    int head = (r / SEQ) % NH;
    int l = r % SEQ;
    int sidx = lane >> 4, dc = lane & 15;
    const float* qrow = qkv + ((size_t)(b * SEQ + l)) * QKVLD + head * HD + dc * 4;
    float4 qf = *(const float4*)qrow;
    int myidx = (lane < NSAMP) ? idx_sample[l * NSAMP + lane] : 0;
    const float* kbase = qkv + (size_t)b * SEQ * QKVLD + 512 + head * HD + dc * 4;
    int kidx[6];
#pragma unroll
    for (int p = 0; p < 6; p++) kidx[p] = __shfl(myidx, p * 4 + sidx);
    float4 kf[6];
#pragma unroll
    for (int p = 0; p < 6; p++) kf[p] = *(const float4*)(kbase + (size_t)kidx[p] * QKVLD);
    float mx = -INFINITY, sm = 0.f;
#pragma unroll
    for (int p = 0; p < 6; p++) {
        float part = qf.x * kf[p].x + qf.y * kf[p].y + qf.z * kf[p].z + qf.w * kf[p].w;
        part += __shfl_xor(part, 1);
        part += __shfl_xor(part, 2);
        part += __shfl_xor(part, 4);
        part += __shfl_xor(part, 8);
        mx = fmaxf(mx, part);
        sm += part;
    }
    mx = fmaxf(mx, __shfl_xor(mx, 16));
    mx = fmaxf(mx, __shfl_xor(mx, 32));
    sm += __shfl_xor(sm, 16);
    sm += __shfl_xor(sm, 32);
    if (lane == 0) Mout[r] = mx - sm * (1.f / SEQ);
}

// ---------------- top-24: register keys + wave shuffle reduce ----------------
__device__ __forceinline__ u64 pack_key(float v, int idx) {
    u32 u = __float_as_uint(v);
    u32 m = (u & 0x80000000u) ? ~u : (u | 0x80000000u);
    return ((u64)m << 32) | (u32)(~(u32)idx);
}

__global__ __launch_bounds__(256) void topk_part(const float* __restrict__ Mbuf,
        u64* __restrict__ cand) {
    __shared__ u64 wred[4];
    int bh = blockIdx.x, chunk = blockIdx.y;
    int tid = threadIdx.x, wv = tid >> 6, lane = tid & 63;
    int l = chunk * 256 + tid;
    u64 val = pack_key(Mbuf[(size_t)bh * SEQ + l], l);
    for (int it = 0; it < NTOP; it++) {
        u64 w = val;
#pragma unroll
        for (int off = 32; off > 0; off >>= 1) {
            u64 o = __shfl_xor(w, off);
            if (o > w) w = o;
        }
        if (lane == 0) wred[wv] = w;
        __syncthreads();
        u64 win = wred[0];
        if (wred[1] > win) win = wred[1];
        if (wred[2] > win) win = wred[2];
        if (wred[3] > win) win = wred[3];
        if (val == win) val = 0;
        if (tid == 0) cand[((size_t)bh * 8 + chunk) * NTOP + it] = win;
        __syncthreads();
    }
}

__global__ __launch_bounds__(256) void topk_merge(const u64* __restrict__ cand,
        int* __restrict__ idx_top) {
    __shared__ u64 wred[4];
    int bh = blockIdx.x;
    int tid = threadIdx.x, wv = tid >> 6, lane = tid & 63;
    u64 val = (tid < 8 * NTOP) ? cand[(size_t)bh * 8 * NTOP + tid] : 0;
    for (int it = 0; it < NTOP; it++) {
        u64 w = val;
#pragma unroll
        for (int off = 32; off > 0; off >>= 1) {
            u64 o = __shfl_xor(w, off);
            if (o > w) w = o;
        }
        if (lane == 0) wred[wv] = w;
        __syncthreads();
        u64 win = wred[0];
        if (wred[1] > win) win = wred[1];
        if (wred[2] > win) win = wred[2];
        if (wred[3] > win) win = wred[3];
        if (val == win) val = 0;
        if (tid == 0) idx_top[bh * NTOP + it] = (int)(~(u32)(win & 0xffffffffull) & (SEQ - 1));
        __syncthreads();
    }
}

// ---------------- V mean over keys per (b,h) ----------------
__global__ __launch_bounds__(256) void vmean_kernel(const float* __restrict__ qkv,
        float* __restrict__ vmean) {
    __shared__ float red[256];
    int bh = blockIdx.x, slab = blockIdx.y;
    int b = bh >> 3, head = bh & 7;
    int seg = threadIdx.x >> 6, d = threadIdx.x & 63;
    int base_row = slab * 256 + seg * 64;
    float s = 0.f;
    for (int r = 0; r < 64; r++)
        s += qkv[((size_t)(b * SEQ + base_row + r)) * QKVLD + 1024 + head * HD + d];
    red[threadIdx.x] = s;
    __syncthreads();
    if (threadIdx.x < 128) red[threadIdx.x] += red[threadIdx.x + 128];
    __syncthreads();
    if (threadIdx.x < 64) {
        float t = red[threadIdx.x] + red[threadIdx.x + 64];
        atomicAdd(&vmean[bh * HD + d], t * (1.f / SEQ));
    }
}

// ---------------- fill context with V-mean ----------------
__global__ void fillctx_kernel(const float* __restrict__ vmean, float* __restrict__ out) {
    int e = blockIdx.x * 256 + threadIdx.x;
    int c = e & 511;
    int b = e >> 20;
    out[e] = vmean[(((b << 3) | (c >> 6)) << 6) + (c & 63)];
}

// ---------------- flash-style sparse attention: block = (b*h, key-slab of 512) ----------------
__global__ __launch_bounds__(256) void spattn_flash(const float* __restrict__ qkv,
        const int* __restrict__ idx_top, float* __restrict__ opart,
        float* __restrict__ mspart) {
    __shared__ float KtT[64][65];   // transposed: [dim][key]
    __shared__ float Vt[64][65];    // [key][dim]
    __shared__ float Qs[24][64];
    __shared__ float Ps[24][66];
    int bh = blockIdx.x, slab = blockIdx.y;
    int b = bh >> 3, h = bh & 7;
    int tid = threadIdx.x;
    int wv = tid >> 6, lane = tid & 63;
    for (int i = tid; i < NTOP * 64; i += 256) {
        int u = i >> 6, d = i & 63;
        int qi = idx_top[bh * NTOP + u];
        Qs[u][d] = qkv[((size_t)(b * SEQ + qi)) * QKVLD + h * HD + d];
    }
    float m[6], s[6], o[6], alpha[6];
#pragma unroll
    for (int j = 0; j < 6; j++) { m[j] = -INFINITY; s[j] = 0.f; o[j] = 0.f; }
    int key0 = slab * 512;
    int sr = tid >> 2, sc0 = (tid & 3) * 16;
    for (int t = 0; t < 8; t++) {
        int kbase = key0 + t * 64;
        __syncthreads();
        const float* kr = qkv + ((size_t)(b * SEQ + kbase + sr)) * QKVLD + 512 + h * HD + sc0;
        const float* vr = qkv + ((size_t)(b * SEQ + kbase + sr)) * QKVLD + 1024 + h * HD + sc0;
        float kf[16], vf[16];
        *(float4*)&kf[0]  = *(const float4*)(kr);
        *(float4*)&kf[4]  = *(const float4*)(kr + 4);
        *(float4*)&kf[8]  = *(const float4*)(kr + 8);
        *(float4*)&kf[12] = *(const float4*)(kr + 12);
        *(float4*)&vf[0]  = *(const float4*)(vr);
        *(float4*)&vf[4]  = *(const float4*)(vr + 4);
        *(float4*)&vf[8]  = *(const float4*)(vr + 8);
        *(float4*)&vf[12] = *(const float4*)(vr + 12);
#pragma unroll
        for (int i = 0; i < 16; i++) {
            KtT[sc0 + i][sr] = kf[i];
            Vt[sr][sc0 + i] = vf[i];
        }
        __syncthreads();
        float dot[6] = {};
#pragma unroll
        for (int d = 0; d < 64; d++) {
            float kv = KtT[d][lane];
#pragma unroll
            for (int j = 0; j < 6; j++) dot[j] += Qs[wv * 6 + j][d] * kv;
        }
#pragma unroll
        for (int j = 0; j < 6; j++) {
            float sc = dot[j] * 0.125f;
            float tmax = sc;
            for (int off = 32; off > 0; off >>= 1) tmax = fmaxf(tmax, __shfl_xor(tmax, off));
            float mn = fmaxf(m[j], tmax);
            float p = __expf(sc - mn);
            float psum = p;
            for (int off = 32; off > 0; off >>= 1) psum += __shfl_xor(psum, off);
            alpha[j] = __expf(m[j] - mn);
            s[j] = s[j] * alpha[j] + psum;
            m[j] = mn;
            Ps[wv * 6 + j][lane] = p;
        }
        float pv[6] = {};
#pragma unroll
        for (int key = 0; key < 64; key++) {
            float vvv = Vt[key][lane];
#pragma unroll
            for (int j = 0; j < 6; j++) pv[j] += Ps[wv * 6 + j][key] * vvv;
        }
#pragma unroll
        for (int j = 0; j < 6; j++) o[j] = o[j] * alpha[j] + pv[j];
    }
    float* ob = opart + ((size_t)(bh * 4 + slab)) * NTOP * 64;
#pragma unroll
    for (int j = 0; j < 6; j++) ob[(wv * 6 + j) * 64 + lane] = o[j];
    if (lane == 0) {
        float* ms = mspart + ((size_t)(bh * 4 + slab)) * NTOP * 2;
#pragma unroll
        for (int j = 0; j < 6; j++) {
            ms[(wv * 6 + j) * 2]     = m[j];
            ms[(wv * 6 + j) * 2 + 1] = s[j];
        }
    }
}

// ---------------- merge 4 slab partials, scatter into context ----------------
__global__ __launch_bounds__(256) void spattn_combine(const float* __restrict__ opart,
        const float* __restrict__ mspart, const int* __restrict__ idx_top,
        float* __restrict__ out) {
    __shared__ float wgt[4][NTOP];
    int bh = blockIdx.x;
    int b = bh >> 3, h = bh & 7;
    int tid = threadIdx.x;
    if (tid < NTOP) {
        float mv[4], sv[4];
        float M = -INFINITY;
#pragma unroll
        for (int sl = 0; sl < 4; sl++) {
            mv[sl] = mspart[((size_t)(bh * 4 + sl)) * NTOP * 2 + tid * 2];
            sv[sl] = mspart[((size_t)(bh * 4 + sl)) * NTOP * 2 + tid * 2 + 1];
            M = fmaxf(M, mv[sl]);
        }
        float S = 0.f;
#pragma unroll
        for (int sl = 0; sl < 4; sl++) S += sv[sl] * __expf(mv[sl] - M);
        float invS = 1.f / S;
#pragma unroll
        for (int sl = 0; sl < 4; sl++) wgt[sl][tid] = __expf(mv[sl] - M) * invS;
    }
    __syncthreads();
    for (int i = tid; i < NTOP * 64; i += 256) {
        int u = i >> 6, d = i & 63;
        float val = 0.f;
#pragma unroll
        for (int sl = 0; sl < 4; sl++)
            val += wgt[sl][u] * opart[(((size_t)(bh * 4 + sl)) * NTOP + u) * 64 + d];
        int qi = idx_top[bh * NTOP + u];
        out[((size_t)(b * SEQ + qi)) * DM + h * HD + d] = val;
    }
}

// ---------------- layernorm over DM=512: one wave per row, shuffle-reduce ----------------
__global__ __launch_bounds__(256) void ln_kernel(const float* __restrict__ src,
        const float* __restrict__ g, const float* __restrict__ b,
        float* __restrict__ dst) {
    int wv = threadIdx.x >> 6, lane = threadIdx.x & 63;
    int t = blockIdx.x * 4 + wv;
    const float* xr = src + (size_t)t * DM;
    float4 x0 = *(const float4*)&xr[lane * 4];
    float4 x1 = *(const float4*)&xr[lane * 4 + 256];
    float s  = x0.x + x0.y + x0.z + x0.w + x1.x + x1.y + x1.z + x1.w;
    float s2 = x0.x * x0.x + x0.y * x0.y + x0.z * x0.z + x0.w * x0.w
             + x1.x * x1.x + x1.y * x1.y + x1.z * x1.z + x1.w * x1.w;
#pragma unroll
    for (int off = 32; off > 0; off >>= 1) {
        s  += __shfl_xor(s, off);
        s2 += __shfl_xor(s2, off);
    }
    float m = s * (1.f / DM);
    float var = s2 * (1.f / DM) - m * m;
    float inv = rsqrtf(var + EPS);
    float4 g0 = *(const float4*)&g[lane * 4];
    float4 g1 = *(const float4*)&g[lane * 4 + 256];
    float4 b0 = *(const float4*)&b[lane * 4];
    float4 b1 = *(const float4*)&b[lane * 4 + 256];
    float4 y0, y1;
    y0.x = (x0.x - m) * inv * g0.x + b0.x;  y0.y = (x0.y - m) * inv * g0.y + b0.y;
    y0.z = (x0.z - m) * inv * g0.z + b0.z;  y0.w = (x0.w - m) * inv * g0.w + b0.w;
    y1.x = (x1.x - m) * inv * g1.x + b1.x;  y1.y = (x1.y - m) * inv * g1.y + b1.y;
    y1.z = (x1.z - m) * inv * g1.z + b1.z;  y1.w = (x1.w - m) * inv * g1.w + b1.w;
    float* dr = dst + (size_t)t * DM;
    *(float4*)&dr[lane * 4] = y0;
    *(float4*)&dr[lane * 4 + 256] = y1;
}

// ---------------- prediction head on last token ----------------
__global__ __launch_bounds__(256) void head_kernel(const float* __restrict__ hfin,
        const float* __restrict__ Wpre, const float* __restrict__ bpre,
        const float* __restrict__ Wfc, const float* __restrict__ bfc,
        float* __restrict__ out) {
    __shared__ float last[DM];
    __shared__ float red[256];
    int b = blockIdx.x, tid = threadIdx.x;
    const float* hr = hfin + ((size_t)(b * SEQ + SEQ - 1)) * DM;
    last[tid] = hr[tid];
    last[tid + 256] = hr[tid + 256];
    __syncthreads();
    float acc = bpre[tid];
    for (int c = 0; c < DM; c++) acc += last[c] * Wpre[tid * DM + c];
    acc = fmaxf(acc, 0.f);
    red[tid] = acc * Wfc[tid];
    __syncthreads();
    for (int s = 128; s > 0; s >>= 1) { if (tid < s) red[tid] += red[tid + s]; __syncthreads(); }
    if (tid == 0) out[b] = red[0] + bfc[0];
}

extern "C" void kernel_launch(void* const* d_in, const int* in_sizes, int n_in,
                              void* d_out, int out_size, void* d_ws, size_t ws_size,
                              hipStream_t stream) {
    (void)in_sizes; (void)n_in; (void)out_size; (void)ws_size;
    const float* x      = (const float*)d_in[0];
    const float* tfeat  = (const float*)d_in[1];
    const float* g_in   = (const float*)d_in[2];
    const float* b_in   = (const float*)d_in[3];
    const float* W_tok  = (const float*)d_in[4];
    const float* W_time = (const float*)d_in[5];
    const float* b_time = (const float*)d_in[6];
    const float* Wq     = (const float*)d_in[7];
    const float* bq     = (const float*)d_in[8];
    const float* Wk     = (const float*)d_in[9];
    const float* bk     = (const float*)d_in[10];
    const float* Wv     = (const float*)d_in[11];
    const float* bv     = (const float*)d_in[12];
    const float* Wo     = (const float*)d_in[13];
    const float* bo     = (const float*)d_in[14];
    const float* W1     = (const float*)d_in[15];
    const float* b1     = (const float*)d_in[16];
    const float* W2     = (const float*)d_in[17];
    const float* b2     = (const float*)d_in[18];
    const float* g1     = (const float*)d_in[19];
    const float* be1    = (const float*)d_in[20];
    const float* g2     = (const float*)d_in[21];
    const float* be2    = (const float*)d_in[22];
    const float* g_enc  = (const float*)d_in[23];
    const float* b_enc  = (const float*)d_in[24];
    const float* W_pre  = (const float*)d_in[25];
    const float* b_pre  = (const float*)d_in[26];
    const float* W_fc   = (const float*)d_in[27];
    const float* b_fc   = (const float*)d_in[28];
    float* out = (float*)d_out;

    char* ws = (char*)d_ws;
    float* h    = (float*)(ws);                      // 33.5 MB fp32 residual
    float* tmp  = (float*)(ws + 33554432);           // 33.5 MB fp32
    char*  bigc = ws + 67108864;                     // 134.2 MB multi-use
    float* big  = (float*)bigc;                      // qkv [TOK][1536] fp32 / FFN mid
    // embed-stage overlays inside big:
    float* xln  = (float*)(bigc);                    // 2 MB
    float* acv  = (float*)(bigc + 2097152);          // im2col [TOK][96] fp32, 6.3 MB
    float* pe   = (float*)(bigc + 8388608);          // 4 MB
    float* rsd  = (float*)(bigc + 12582912);         // 33.5 MB
    u32*   wtok = (u32*)(bigc + 46137344);           // W_tok interleaved [512][96]
    u32*   wpair      = (u32*)(ws + 201326592);      // 12.6 MB per-layer weights
    float* Mbuf       = (float*)(ws + 213909504);    // 0.5 MB
    float* vmean      = (float*)(ws + 214433792);
    int*   idx_sample = (int*)(ws + 214450176);
    int*   idx_top    = (int*)(ws + 214843392);
    float* biasqkv    = (float*)(ws + 214849536);
    u64*   cand       = (u64*)(ws + 214855680);      // 98 KB
    float* opart      = (float*)(ws + 214953984);    // 1.57 MB
    float* mspart     = (float*)(ws + 216526848);    // 48 KB

    ln_in_kernel<<<TOK / 256, 256, 0, stream>>>(x, g_in, b_in, xln);
    im2col_kernel<<<TOK, 128, 0, stream>>>(xln, acv);
    wtok_split<<<192, 256, 0, stream>>>(W_tok, wtok);
    pe_kernel<<<4096, 256, 0, stream>>>(pe);
    rsd_kernel<<<TOK, 256, 0, stream>>>(pe, tfeat, W_time, rsd);
    sample_kernel<<<dim3(96, 2), 256, 0, stream>>>(idx_sample);

    // conv-as-GEMM: h = im2col @ W_tok^T + b_time + (pe + time emb)
    gemm_split<false, true><<<dim3(4, 128), 256, 0, stream>>>(
        acv, wtok, b_time, rsd, h, DM, 96, 96);

    const u32* wqkv_p = wpair;                // rows 0..1535 = Wq;Wk;Wv
    const u32* wo_p = wpair + 786432;
    const u32* w1_p = wpair + 1048576;
    const u32* w2_p = wpair + 2097152;

    for (int li = 0; li < 2; li++) {
        split_weights<<<12288, 256, 0, stream>>>(
            Wq + (size_t)li * DM * DM, Wk + (size_t)li * DM * DM,
            Wv + (size_t)li * DM * DM, Wo + (size_t)li * DM * DM,
            W1 + (size_t)li * DFF * DM, W2 + (size_t)li * DM * DFF, wpair);
        concat_bias<<<6, 256, 0, stream>>>(bq + (size_t)li * DM, bk + (size_t)li * DM,
                                           bv + (size_t)li * DM, biasqkv);

        const float* bo_i = bo + (size_t)li * DM;
        const float* b1_i = b1 + (size_t)li * DFF;
        const float* b2_i = b2 + (size_t)li * DM;
        const float* g1_i = g1 + (size_t)li * DM;
        const float* be1_i = be1 + (size_t)li * DM;
        const float* g2_i = g2 + (size_t)li * DM;
        const float* be2_i = be2 + (size_t)li * DM;

        // fused QKV: [TOK][1536] fp32
        gemm_split<false, false><<<dim3(QKVLD / 128, TOK / 128), 256, 0, stream>>>(
            h, wqkv_p, biasqkv, nullptr, big, QKVLD, DM, DM);

        qk_sample_kernel<<<(BATCH * NH * SEQ) / 4, 256, 0, stream>>>(
            big, idx_sample + li * SEQ * NSAMP, Mbuf);
        topk_part<<<dim3(BATCH * NH, 8), 256, 0, stream>>>(Mbuf, cand);
        topk_merge<<<BATCH * NH, 256, 0, stream>>>(cand, idx_top);
        hipMemsetAsync(vmean, 0, BATCH * NH * HD * sizeof(float), stream);
        vmean_kernel<<<dim3(BATCH * NH, 8), 256, 0, stream>>>(big, vmean);
        fillctx_kernel<<<(TOK * DM) / 256, 256, 0, stream>>>(vmean, tmp);
        spattn_flash<<<dim3(BATCH * NH, 4), 256, 0, stream>>>(big, idx_top, opart, mspart);
        spattn_combine<<<BATCH * NH, 256, 0, stream>>>(opart, mspart, idx_top, tmp);

        // Wo with residual into h
        gemm_split<false, true><<<dim3(DM / 128, TOK / 128), 256, 0, stream>>>(
            tmp, wo_p, bo_i, h, h, DM, DM, DM);
        ln_kernel<<<TOK / 4, 256, 0, stream>>>(h, g1_i, be1_i, h);

        // FFN full-width
        gemm_split<true, false><<<dim3(DFF / 128, TOK / 128), 256, 0, stream>>>(
            h, w1_p, b1_i, nullptr, big, DFF, DM, DM);
        gemm_split<false, true><<<dim3(DM / 128, TOK / 128), 256, 0, stream>>>(
            big, w2_p, b2_i, h, tmp, DM, DFF, DFF);
        ln_kernel<<<TOK / 4, 256, 0, stream>>>(tmp, g2_i, be2_i, h);
    }

    ln_kernel<<<TOK / 4, 256, 0, stream>>>(h, g_enc, b_enc, tmp);
    head_kernel<<<BATCH, 256, 0, stream>>>(tmp, W_pre, b_pre, W_fc, b_fc, out);
}

// Round 12
// 1305.884 us; speedup vs baseline: 1.1732x; 1.0765x over previous
//
#include <hip/hip_runtime.h>
#include <math.h>

#define BATCH 8
#define SEQ   2048
#define TOK   (BATCH*SEQ)     // 16384
#define CIN   32
#define DM    512
#define DFF   2048
#define NH    8
#define HD    64
#define NSAMP 24
#define NTOP  24
#define EPS   1e-5f
#define QKVLD 1536

typedef unsigned int u32;
typedef unsigned short u16;
typedef unsigned long long u64;
typedef __attribute__((ext_vector_type(8))) short short8;
typedef __attribute__((ext_vector_type(4))) float floatx4;

__device__ __forceinline__ void async16(const void* g, void* l) {
    __builtin_amdgcn_global_load_lds((const __attribute__((address_space(1))) u32*)g,
                                     (__attribute__((address_space(3))) u32*)l, 16, 0, 0);
}
__device__ __forceinline__ u16 bf16rn(float f) {
    u32 u = __float_as_uint(f);
    return (u16)((u + 0x7fffu + ((u >> 16) & 1u)) >> 16);
}
__device__ __forceinline__ u32 pack_pair(float v) {
    u16 hb = bf16rn(v);
    float r = v - __uint_as_float((u32)hb << 16);
    return (u32)hb | ((u32)bf16rn(r) << 16);
}
__device__ __forceinline__ float unpack_pair(u32 p) {
    return __uint_as_float((p & 0xffffu) << 16) + __uint_as_float(p & 0xffff0000u);
}

// ---------------- Threefry-2x32 ----------------
__device__ __forceinline__ void tf_round(unsigned &x0, unsigned &x1, int r) {
    x0 += x1;
    x1 = (x1 << r) | (x1 >> (32 - r));
    x1 ^= x0;
}
__device__ __forceinline__ void threefry(unsigned k0, unsigned k1,
                                         unsigned c0, unsigned c1,
                                         unsigned &o0, unsigned &o1) {
    unsigned ks0 = k0, ks1 = k1, ks2 = k0 ^ k1 ^ 0x1BD11BDAu;
    unsigned x0 = c0 + ks0, x1 = c1 + ks1;
    tf_round(x0,x1,13); tf_round(x0,x1,15); tf_round(x0,x1,26); tf_round(x0,x1,6);
    x0 += ks1; x1 += ks2 + 1u;
    tf_round(x0,x1,17); tf_round(x0,x1,29); tf_round(x0,x1,16); tf_round(x0,x1,24);
    x0 += ks2; x1 += ks0 + 2u;
    tf_round(x0,x1,13); tf_round(x0,x1,15); tf_round(x0,x1,26); tf_round(x0,x1,6);
    x0 += ks0; x1 += ks1 + 3u;
    tf_round(x0,x1,17); tf_round(x0,x1,29); tf_round(x0,x1,16); tf_round(x0,x1,24);
    x0 += ks1; x1 += ks2 + 4u;
    tf_round(x0,x1,13); tf_round(x0,x1,15); tf_round(x0,x1,26); tf_round(x0,x1,6);
    x0 += ks2; x1 += ks0 + 5u;
    o0 = x0; o1 = x1;
}

__global__ void sample_kernel(int* __restrict__ idx_sample) {
    const int HALF = (SEQ * NSAMP) / 2;  // 24576
    int p = blockIdx.x * blockDim.x + threadIdx.x;
    int li = blockIdx.y;
    if (p >= HALF) return;
    unsigned f0, f1;
    threefry(0u, 42u, 0u, (unsigned)li, f0, f1);
    unsigned a0, a1, b0, b1;
    threefry(f0, f1, 0u, 2u, a0, a1);
    threefry(f0, f1, 1u, 3u, b0, b1);
    unsigned o0, o1;
    threefry(a1, b1, (unsigned)p, (unsigned)(p + HALF), o0, o1);
    idx_sample[li * SEQ * NSAMP + p]        = (int)(o0 & (SEQ - 1));
    idx_sample[li * SEQ * NSAMP + p + HALF] = (int)(o1 & (SEQ - 1));
}

// ---------------- input layernorm over C_IN=32 ----------------
__global__ __launch_bounds__(256) void ln_in_kernel(const float* __restrict__ x,
        const float* __restrict__ g, const float* __restrict__ b,
        float* __restrict__ out) {
    int t = blockIdx.x * blockDim.x + threadIdx.x;
    if (t >= TOK) return;
    const float* xr = x + (size_t)t * CIN;
    float vals[CIN];
    float s = 0.f;
#pragma unroll
    for (int c = 0; c < CIN; c++) { vals[c] = xr[c]; s += vals[c]; }
    float m = s * (1.f / CIN);
    float v = 0.f;
#pragma unroll
    for (int c = 0; c < CIN; c++) { float d = vals[c] - m; v += d * d; }
    v *= (1.f / CIN);
    float inv = rsqrtf(v + EPS);
    float* orow = out + (size_t)t * CIN;
#pragma unroll
    for (int c = 0; c < CIN; c++) orow[c] = (vals[c] - m) * inv * g[c] + b[c];
}

// ---------------- im2col (wrap pad) -> pair u32: A[t][j], j=w*32+c ----------------
__global__ __launch_bounds__(128) void im2col_kernel(const float* __restrict__ xln,
        u32* __restrict__ a) {
    int t = blockIdx.x;
    int j = threadIdx.x;
    if (j >= 96) return;
    int b = t >> 11, l = t & 2047;
    int w = j >> 5, c = j & 31;
    int lw = (l - 1 + w + SEQ) & 2047;
    a[(size_t)t * 96 + j] = pack_pair(xln[(((size_t)b << 11) | lw) * CIN + c]);
}

// ---------------- W_tok transpose + split to interleaved u32: wt[o][j] ----------------
__global__ __launch_bounds__(256) void wtok_split(const float* __restrict__ Wtok,
        u32* __restrict__ wt) {
    int e = blockIdx.x * 256 + threadIdx.x;  // < 49152
    int o = e / 96, j = e % 96;
    wt[e] = pack_pair(Wtok[(size_t)j * DM + o]);
}

// ---------------- positional embedding table pe[l][o] ----------------
__global__ __launch_bounds__(256) void pe_kernel(float* __restrict__ pe) {
    int e = blockIdx.x * 256 + threadIdx.x;  // < 1048576
    int l = e >> 9, o = e & 511;
    const float c1 = -0.017988946039016f;  // -ln(10000)/512
    int i2 = o & ~1;
    float div = expf((float)i2 * c1);
    float arg = (float)l * div;
    pe[e] = (o & 1) ? cosf(arg) : sinf(arg);
}

// ---------------- rsdP[t][o] = pair(pe[l][o] + tf[t]·Wtime[o]) ----------------
__global__ __launch_bounds__(256) void rsd_kernel(const float* __restrict__ pe,
        const float* __restrict__ tfeat, const float* __restrict__ Wtime,
        u32* __restrict__ rsd) {
    int t = blockIdx.x, tid = threadIdx.x;
    int l = t & 2047;
    float t0 = tfeat[(size_t)t * 4], t1 = tfeat[(size_t)t * 4 + 1];
    float t2 = tfeat[(size_t)t * 4 + 2], t3 = tfeat[(size_t)t * 4 + 3];
    for (int o = tid; o < DM; o += 256) {
        float v = pe[l * DM + o]
            + t0 * Wtime[o * 4] + t1 * Wtime[o * 4 + 1]
            + t2 * Wtime[o * 4 + 2] + t3 * Wtime[o * 4 + 3];
        rsd[(size_t)t * DM + o] = pack_pair(v);
    }
}

// ---------------- weight split: fp32 -> interleaved (bf16_h | bf16_l<<16) ----------------
__global__ __launch_bounds__(256) void split_weights(const float* __restrict__ Wq,
        const float* __restrict__ Wk, const float* __restrict__ Wv,
        const float* __restrict__ Wo, const float* __restrict__ W1,
        const float* __restrict__ W2, u32* __restrict__ out) {
    int i = blockIdx.x * 256 + threadIdx.x;  // < 3145728
    const float* src; int off;
    if (i < 1048576) {
        src = (i < 262144) ? Wq : (i < 524288) ? Wk : (i < 786432) ? Wv : Wo;
        off = i & 262143;
    } else if (i < 2097152) { src = W1; off = i - 1048576; }
    else { src = W2; off = i - 2097152; }
    out[i] = pack_pair(src[off]);
}

__global__ void concat_bias(const float* __restrict__ bq, const float* __restrict__ bk,
                            const float* __restrict__ bv, float* __restrict__ o) {
    int i = blockIdx.x * 256 + threadIdx.x;  // < 1536
    o[i] = (i < 512) ? bq[i] : (i < 1024) ? bk[i - 512] : bv[i - 1024];
}

// ---------------- symmetric pair-u32 MFMA GEMM, double-buffered single-barrier ----------
// C = A*W^T + bias (+pair-res)(+relu). A and W both interleaved (h|l<<16) u32, both
// staged via global_load_lds (pure DMA K-loop), unpacked in the MFMA phase.
template<bool RELU, bool RESP, bool OUTP>
__global__ __launch_bounds__(256, 2) void gemm_pp(const u32* __restrict__ Ap,
        const u32* __restrict__ Wp, const float* __restrict__ bias,
        const u32* __restrict__ RsdP, float* __restrict__ Cf, u32* __restrict__ Cp,
        int ldc, int K, int lda) {
    __shared__ alignas(16) u32 At[2][4096];   // [kchunk8][row][8 words]
    __shared__ alignas(16) u32 Wt[2][4096];
    const int tid = threadIdx.x;
    int linear = blockIdx.y * gridDim.x + blockIdx.x;
    int xcd = linear & 7, sseq = linear >> 3;
    int mper = gridDim.y >> 3;
    int mt = xcd * mper + (sseq % mper);
    int nt = sseq / mper;
    const int m0 = mt * 128, n0 = nt * 128;
    const int lane = tid & 63, wv = tid >> 6;
    const int wm = wv >> 1, wn = wv & 1;
    const int fr = lane & 15, q = lane >> 4;

    floatx4 acc[4][4] = {};

    const u32* abase = Ap + (size_t)(m0 + (tid >> 1)) * lda + (tid & 1) * 4;
    const u32* wbase = Wp + (size_t)(n0 + (tid >> 1)) * K + (tid & 1) * 4;
    const int doff = tid * 16;   // byte offset
    const int nk = K >> 5;

    // prologue: stage tile 0 into buf 0
#pragma unroll
    for (int i = 0; i < 4; i++) {
        async16(abase + i * 8, (char*)At[0] + doff + i * 4096);
        async16(wbase + i * 8, (char*)Wt[0] + doff + i * 4096);
    }

    for (int k = 0; k < nk; k++) {
        const int b = k & 1;
        __syncthreads();   // drains DMA issued a full MFMA phase ago
        if (k + 1 < nk) {
            int k0n = (k + 1) << 5;
#pragma unroll
            for (int i = 0; i < 4; i++) {
                async16(abase + k0n + i * 8, (char*)At[b ^ 1] + doff + i * 4096);
                async16(wbase + k0n + i * 8, (char*)Wt[b ^ 1] + doff + i * 4096);
            }
        }
        short8 ah[4], al[4];
#pragma unroll
        for (int mi = 0; mi < 4; mi++) {
            const u32* cell = &At[b][(q * 128 + wm * 64 + mi * 16 + fr) * 8];
            union { u32 u[4]; short8 s; } hh, ll;
            u32 w0 = cell[0], w1 = cell[1], w2 = cell[2], w3 = cell[3];
            u32 w4 = cell[4], w5 = cell[5], w6 = cell[6], w7 = cell[7];
            hh.u[0] = (w0 & 0xffffu) | (w1 << 16);
            hh.u[1] = (w2 & 0xffffu) | (w3 << 16);
            hh.u[2] = (w4 & 0xffffu) | (w5 << 16);
            hh.u[3] = (w6 & 0xffffu) | (w7 << 16);
            ll.u[0] = (w0 >> 16) | (w1 & 0xffff0000u);
            ll.u[1] = (w2 >> 16) | (w3 & 0xffff0000u);
            ll.u[2] = (w4 >> 16) | (w5 & 0xffff0000u);
            ll.u[3] = (w6 >> 16) | (w7 & 0xffff0000u);
            ah[mi] = hh.s; al[mi] = ll.s;
        }
#pragma unroll
        for (int ni = 0; ni < 4; ni++) {
            const u32* cell = &Wt[b][(q * 128 + wn * 64 + ni * 16 + fr) * 8];
            union { u32 u[4]; short8 s; } wh, wl;
            u32 w0 = cell[0], w1 = cell[1], w2 = cell[2], w3 = cell[3];
            u32 w4 = cell[4], w5 = cell[5], w6 = cell[6], w7 = cell[7];
            wh.u[0] = (w0 & 0xffffu) | (w1 << 16);
            wh.u[1] = (w2 & 0xffffu) | (w3 << 16);
            wh.u[2] = (w4 & 0xffffu) | (w5 << 16);
            wh.u[3] = (w6 & 0xffffu) | (w7 << 16);
            wl.u[0] = (w0 >> 16) | (w1 & 0xffff0000u);
            wl.u[1] = (w2 >> 16) | (w3 & 0xffff0000u);
            wl.u[2] = (w4 >> 16) | (w5 & 0xffff0000u);
            wl.u[3] = (w6 >> 16) | (w7 & 0xffff0000u);
#pragma unroll
            for (int mi = 0; mi < 4; mi++) {
                acc[mi][ni] = __builtin_amdgcn_mfma_f32_16x16x32_bf16(ah[mi], wh.s, acc[mi][ni], 0, 0, 0);
                acc[mi][ni] = __builtin_amdgcn_mfma_f32_16x16x32_bf16(ah[mi], wl.s, acc[mi][ni], 0, 0, 0);
                acc[mi][ni] = __builtin_amdgcn_mfma_f32_16x16x32_bf16(al[mi], wh.s, acc[mi][ni], 0, 0, 0);
            }
        }
    }
    // --- epilogue ---
#pragma unroll
    for (int ni = 0; ni < 4; ni++) {
        int col = n0 + wn * 64 + ni * 16 + fr;
        float bv = bias[col];
#pragma unroll
        for (int mi = 0; mi < 4; mi++) {
            int row = m0 + wm * 64 + mi * 16 + q * 4;
#pragma unroll
            for (int r = 0; r < 4; r++) {
                size_t idx = (size_t)(row + r) * ldc + col;
                float v = acc[mi][ni][r] + bv;
                if (RESP) v += unpack_pair(RsdP[idx]);
                if (RELU) v = fmaxf(v, 0.f);
                if (OUTP) Cp[idx] = pack_pair(v);
                else      Cf[idx] = v;
            }
        }
    }
}

// ---------------- M = max(QK_sample) - sum/L : one wave per (b,h,l) ----------------
__global__ __launch_bounds__(256) void qk_sample_kernel(const float* __restrict__ qkv,
        const int* __restrict__ idx_sample, float* __restrict__ Mout) {
    int r = (blockIdx.x * 256 + threadIdx.x) >> 6;
    int lane = threadIdx.x & 63;
    if (r >= BATCH * NH * SEQ) return;
    int b = r / (NH * SEQ);
    int head = (r / SEQ) % NH;
    int l = r % SEQ;
    int sidx = lane >> 4, dc = lane & 15;
    const float* qrow = qkv + ((size_t)(b * SEQ + l)) * QKVLD + head * HD + dc * 4;
    float4 qf = *(const float4*)qrow;
    int myidx = (lane < NSAMP) ? idx_sample[l * NSAMP + lane] : 0;
    const float* kbase = qkv + (size_t)b * SEQ * QKVLD + 512 + head * HD + dc * 4;
    int kidx[6];
#pragma unroll
    for (int p = 0; p < 6; p++) kidx[p] = __shfl(myidx, p * 4 + sidx);
    float4 kf[6];
#pragma unroll
    for (int p = 0; p < 6; p++) kf[p] = *(const float4*)(kbase + (size_t)kidx[p] * QKVLD);
    float mx = -INFINITY, sm = 0.f;
#pragma unroll
    for (int p = 0; p < 6; p++) {
        float part = qf.x * kf[p].x + qf.y * kf[p].y + qf.z * kf[p].z + qf.w * kf[p].w;
        part += __shfl_xor(part, 1);
        part += __shfl_xor(part, 2);
        part += __shfl_xor(part, 4);
        part += __shfl_xor(part, 8);
        mx = fmaxf(mx, part);
        sm += part;
    }
    mx = fmaxf(mx, __shfl_xor(mx, 16));
    mx = fmaxf(mx, __shfl_xor(mx, 32));
    sm += __shfl_xor(sm, 16);
    sm += __shfl_xor(sm, 32);
    if (lane == 0) Mout[r] = mx - sm * (1.f / SEQ);
}

// ---------------- top-24: register keys + wave shuffle reduce ----------------
__device__ __forceinline__ u64 pack_key(float v, int idx) {
    u32 u = __float_as_uint(v);
    u32 m = (u & 0x80000000u) ? ~u : (u | 0x80000000u);
    return ((u64)m << 32) | (u32)(~(u32)idx);
}

__global__ __launch_bounds__(256) void topk_part(const float* __restrict__ Mbuf,
        u64* __restrict__ cand) {
    __shared__ u64 wred[4];
    int bh = blockIdx.x, chunk = blockIdx.y;
    int tid = threadIdx.x, wv = tid >> 6, lane = tid & 63;
    int l = chunk * 256 + tid;
    u64 val = pack_key(Mbuf[(size_t)bh * SEQ + l], l);
    for (int it = 0; it < NTOP; it++) {
        u64 w = val;
#pragma unroll
        for (int off = 32; off > 0; off >>= 1) {
            u64 o = __shfl_xor(w, off);
            if (o > w) w = o;
        }
        if (lane == 0) wred[wv] = w;
        __syncthreads();
        u64 win = wred[0];
        if (wred[1] > win) win = wred[1];
        if (wred[2] > win) win = wred[2];
        if (wred[3] > win) win = wred[3];
        if (val == win) val = 0;
        if (tid == 0) cand[((size_t)bh * 8 + chunk) * NTOP + it] = win;
        __syncthreads();
    }
}

__global__ __launch_bounds__(256) void topk_merge(const u64* __restrict__ cand,
        int* __restrict__ idx_top) {
    __shared__ u64 wred[4];
    int bh = blockIdx.x;
    int tid = threadIdx.x, wv = tid >> 6, lane = tid & 63;
    u64 val = (tid < 8 * NTOP) ? cand[(size_t)bh * 8 * NTOP + tid] : 0;
    for (int it = 0; it < NTOP; it++) {
        u64 w = val;
#pragma unroll
        for (int off = 32; off > 0; off >>= 1) {
            u64 o = __shfl_xor(w, off);
            if (o > w) w = o;
        }
        if (lane == 0) wred[wv] = w;
        __syncthreads();
        u64 win = wred[0];
        if (wred[1] > win) win = wred[1];
        if (wred[2] > win) win = wred[2];
        if (wred[3] > win) win = wred[3];
        if (val == win) val = 0;
        if (tid == 0) idx_top[bh * NTOP + it] = (int)(~(u32)(win & 0xffffffffull) & (SEQ - 1));
        __syncthreads();
    }
}

// ---------------- V mean over keys per (b,h) ----------------
__global__ __launch_bounds__(256) void vmean_kernel(const float* __restrict__ qkv,
        float* __restrict__ vmean) {
    __shared__ float red[256];
    int bh = blockIdx.x, slab = blockIdx.y;
    int b = bh >> 3, head = bh & 7;
    int seg = threadIdx.x >> 6, d = threadIdx.x & 63;
    int base_row = slab * 256 + seg * 64;
    float s = 0.f;
    for (int r = 0; r < 64; r++)
        s += qkv[((size_t)(b * SEQ + base_row + r)) * QKVLD + 1024 + head * HD + d];
    red[threadIdx.x] = s;
    __syncthreads();
    if (threadIdx.x < 128) red[threadIdx.x] += red[threadIdx.x + 128];
    __syncthreads();
    if (threadIdx.x < 64) {
        float t = red[threadIdx.x] + red[threadIdx.x + 64];
        atomicAdd(&vmean[bh * HD + d], t * (1.f / SEQ));
    }
}

// ---------------- fill context (pair u32) with V-mean ----------------
__global__ void fillctx_kernel(const float* __restrict__ vmean, u32* __restrict__ out) {
    int e = blockIdx.x * 256 + threadIdx.x;
    int c = e & 511;
    int b = e >> 20;
    out[e] = pack_pair(vmean[(((b << 3) | (c >> 6)) << 6) + (c & 63)]);
}

// ---------------- flash-style sparse attention: block = (b*h, key-slab of 512) ----------------
__global__ __launch_bounds__(256) void spattn_flash(const float* __restrict__ qkv,
        const int* __restrict__ idx_top, float* __restrict__ opart,
        float* __restrict__ mspart) {
    __shared__ float KtT[64][65];   // transposed: [dim][key]
    __shared__ float Vt[64][65];    // [key][dim]
    __shared__ float Qs[24][64];
    __shared__ float Ps[24][66];
    int bh = blockIdx.x, slab = blockIdx.y;
    int b = bh >> 3, h = bh & 7;
    int tid = threadIdx.x;
    int wv = tid >> 6, lane = tid & 63;
    for (int i = tid; i < NTOP * 64; i += 256) {
        int u = i >> 6, d = i & 63;
        int qi = idx_top[bh * NTOP + u];
        Qs[u][d] = qkv[((size_t)(b * SEQ + qi)) * QKVLD + h * HD + d];
    }
    float m[6], s[6], o[6], alpha[6];
#pragma unroll
    for (int j = 0; j < 6; j++) { m[j] = -INFINITY; s[j] = 0.f; o[j] = 0.f; }
    int key0 = slab * 512;
    int sr = tid >> 2, sc0 = (tid & 3) * 16;
    for (int t = 0; t < 8; t++) {
        int kbase = key0 + t * 64;
        __syncthreads();
        const float* kr = qkv + ((size_t)(b * SEQ + kbase + sr)) * QKVLD + 512 + h * HD + sc0;
        const float* vr = qkv + ((size_t)(b * SEQ + kbase + sr)) * QKVLD + 1024 + h * HD + sc0;
        float kf[16], vf[16];
        *(float4*)&kf[0]  = *(const float4*)(kr);
        *(float4*)&kf[4]  = *(const float4*)(kr + 4);
        *(float4*)&kf[8]  = *(const float4*)(kr + 8);
        *(float4*)&kf[12] = *(const float4*)(kr + 12);
        *(float4*)&vf[0]  = *(const float4*)(vr);
        *(float4*)&vf[4]  = *(const float4*)(vr + 4);
        *(float4*)&vf[8]  = *(const float4*)(vr + 8);
        *(float4*)&vf[12] = *(const float4*)(vr + 12);
#pragma unroll
        for (int i = 0; i < 16; i++) {
            KtT[sc0 + i][sr] = kf[i];
            Vt[sr][sc0 + i] = vf[i];
        }
        __syncthreads();
        float dot[6] = {};
#pragma unroll
        for (int d = 0; d < 64; d++) {
            float kv = KtT[d][lane];
#pragma unroll
            for (int j = 0; j < 6; j++) dot[j] += Qs[wv * 6 + j][d] * kv;
        }
#pragma unroll
        for (int j = 0; j < 6; j++) {
            float sc = dot[j] * 0.125f;
            float tmax = sc;
            for (int off = 32; off > 0; off >>= 1) tmax = fmaxf(tmax, __shfl_xor(tmax, off));
            float mn = fmaxf(m[j], tmax);
            float p = __expf(sc - mn);
            float psum = p;
            for (int off = 32; off > 0; off >>= 1) psum += __shfl_xor(psum, off);
            alpha[j] = __expf(m[j] - mn);
            s[j] = s[j] * alpha[j] + psum;
            m[j] = mn;
            Ps[wv * 6 + j][lane] = p;
        }
        float pv[6] = {};
#pragma unroll
        for (int key = 0; key < 64; key++) {
            float vvv = Vt[key][lane];
#pragma unroll
            for (int j = 0; j < 6; j++) pv[j] += Ps[wv * 6 + j][key] * vvv;
        }
#pragma unroll
        for (int j = 0; j < 6; j++) o[j] = o[j] * alpha[j] + pv[j];
    }
    float* ob = opart + ((size_t)(bh * 4 + slab)) * NTOP * 64;
#pragma unroll
    for (int j = 0; j < 6; j++) ob[(wv * 6 + j) * 64 + lane] = o[j];
    if (lane == 0) {
        float* ms = mspart + ((size_t)(bh * 4 + slab)) * NTOP * 2;
#pragma unroll
        for (int j = 0; j < 6; j++) {
            ms[(wv * 6 + j) * 2]     = m[j];
            ms[(wv * 6 + j) * 2 + 1] = s[j];
        }
    }
}

// ---------------- merge 4 slab partials, scatter (pair u32) into context ----------------
__global__ __launch_bounds__(256) void spattn_combine(const float* __restrict__ opart,
        const float* __restrict__ mspart, const int* __restrict__ idx_top,
        u32* __restrict__ out) {
    __shared__ float wgt[4][NTOP];
    int bh = blockIdx.x;
    int b = bh >> 3, h = bh & 7;
    int tid = threadIdx.x;
    if (tid < NTOP) {
        float mv[4], sv[4];
        float M = -INFINITY;
#pragma unroll
        for (int sl = 0; sl < 4; sl++) {
            mv[sl] = mspart[((size_t)(bh * 4 + sl)) * NTOP * 2 + tid * 2];
            sv[sl] = mspart[((size_t)(bh * 4 + sl)) * NTOP * 2 + tid * 2 + 1];
            M = fmaxf(M, mv[sl]);
        }
        float S = 0.f;
#pragma unroll
        for (int sl = 0; sl < 4; sl++) S += sv[sl] * __expf(mv[sl] - M);
        float invS = 1.f / S;
#pragma unroll
        for (int sl = 0; sl < 4; sl++) wgt[sl][tid] = __expf(mv[sl] - M) * invS;
    }
    __syncthreads();
    for (int i = tid; i < NTOP * 64; i += 256) {
        int u = i >> 6, d = i & 63;
        float val = 0.f;
#pragma unroll
        for (int sl = 0; sl < 4; sl++)
            val += wgt[sl][u] * opart[(((size_t)(bh * 4 + sl)) * NTOP + u) * 64 + d];
        int qi = idx_top[bh * NTOP + u];
        out[((size_t)(b * SEQ + qi)) * DM + h * HD + d] = pack_pair(val);
    }
}

// ---------------- layernorm over DM=512: one wave per row, pair in/out options ---------
template<bool INP, bool OUTPAIR>
__global__ __launch_bounds__(256) void ln_kernel(const float* __restrict__ srcF,
        const u32* __restrict__ srcP, const float* __restrict__ g,
        const float* __restrict__ b, float* __restrict__ dstF, u32* __restrict__ dstP) {
    int wv = threadIdx.x >> 6, lane = threadIdx.x & 63;
    int t = blockIdx.x * 4 + wv;
    float xv[8];
    if (INP) {
        uint4 p0 = *(const uint4*)&srcP[(size_t)t * DM + lane * 4];
        uint4 p1 = *(const uint4*)&srcP[(size_t)t * DM + lane * 4 + 256];
        xv[0] = unpack_pair(p0.x); xv[1] = unpack_pair(p0.y);
        xv[2] = unpack_pair(p0.z); xv[3] = unpack_pair(p0.w);
        xv[4] = unpack_pair(p1.x); xv[5] = unpack_pair(p1.y);
        xv[6] = unpack_pair(p1.z); xv[7] = unpack_pair(p1.w);
    } else {
        float4 x0 = *(const float4*)&srcF[(size_t)t * DM + lane * 4];
        float4 x1 = *(const float4*)&srcF[(size_t)t * DM + lane * 4 + 256];
        xv[0] = x0.x; xv[1] = x0.y; xv[2] = x0.z; xv[3] = x0.w;
        xv[4] = x1.x; xv[5] = x1.y; xv[6] = x1.z; xv[7] = x1.w;
    }
    float s = 0.f, s2 = 0.f;
#pragma unroll
    for (int i = 0; i < 8; i++) { s += xv[i]; s2 += xv[i] * xv[i]; }
#pragma unroll
    for (int off = 32; off > 0; off >>= 1) {
        s  += __shfl_xor(s, off);
        s2 += __shfl_xor(s2, off);
    }
    float m = s * (1.f / DM);
    float var = s2 * (1.f / DM) - m * m;
    float inv = rsqrtf(var + EPS);
    float4 g0 = *(const float4*)&g[lane * 4];
    float4 g1 = *(const float4*)&g[lane * 4 + 256];
    float4 b0 = *(const float4*)&b[lane * 4];
    float4 b1 = *(const float4*)&b[lane * 4 + 256];
    float y[8];
    y[0] = (xv[0] - m) * inv * g0.x + b0.x;  y[1] = (xv[1] - m) * inv * g0.y + b0.y;
    y[2] = (xv[2] - m) * inv * g0.z + b0.z;  y[3] = (xv[3] - m) * inv * g0.w + b0.w;
    y[4] = (xv[4] - m) * inv * g1.x + b1.x;  y[5] = (xv[5] - m) * inv * g1.y + b1.y;
    y[6] = (xv[6] - m) * inv * g1.z + b1.z;  y[7] = (xv[7] - m) * inv * g1.w + b1.w;
    if (OUTPAIR) {
        uint4 o0, o1;
        o0.x = pack_pair(y[0]); o0.y = pack_pair(y[1]);
        o0.z = pack_pair(y[2]); o0.w = pack_pair(y[3]);
        o1.x = pack_pair(y[4]); o1.y = pack_pair(y[5]);
        o1.z = pack_pair(y[6]); o1.w = pack_pair(y[7]);
        *(uint4*)&dstP[(size_t)t * DM + lane * 4] = o0;
        *(uint4*)&dstP[(size_t)t * DM + lane * 4 + 256] = o1;
    } else {
        float4 o0 = { y[0], y[1], y[2], y[3] };
        float4 o1 = { y[4], y[5], y[6], y[7] };
        *(float4*)&dstF[(size_t)t * DM + lane * 4] = o0;
        *(float4*)&dstF[(size_t)t * DM + lane * 4 + 256] = o1;
    }
}

// ---------------- prediction head on last token ----------------
__global__ __launch_bounds__(256) void head_kernel(const float* __restrict__ hfin,
        const float* __restrict__ Wpre, const float* __restrict__ bpre,
        const float* __restrict__ Wfc, const float* __restrict__ bfc,
        float* __restrict__ out) {
    __shared__ float last[DM];
    __shared__ float red[256];
    int b = blockIdx.x, tid = threadIdx.x;
    const float* hr = hfin + ((size_t)(b * SEQ + SEQ - 1)) * DM;
    last[tid] = hr[tid];
    last[tid + 256] = hr[tid + 256];
    __syncthreads();
    float acc = bpre[tid];
    for (int c = 0; c < DM; c++) acc += last[c] * Wpre[tid * DM + c];
    acc = fmaxf(acc, 0.f);
    red[tid] = acc * Wfc[tid];
    __syncthreads();
    for (int s = 128; s > 0; s >>= 1) { if (tid < s) red[tid] += red[tid + s]; __syncthreads(); }
    if (tid == 0) out[b] = red[0] + bfc[0];
}

extern "C" void kernel_launch(void* const* d_in, const int* in_sizes, int n_in,
                              void* d_out, int out_size, void* d_ws, size_t ws_size,
                              hipStream_t stream) {
    (void)in_sizes; (void)n_in; (void)out_size; (void)ws_size;
    const float* x      = (const float*)d_in[0];
    const float* tfeat  = (const float*)d_in[1];
    const float* g_in   = (const float*)d_in[2];
    const float* b_in   = (const float*)d_in[3];
    const float* W_tok  = (const float*)d_in[4];
    const float* W_time = (const float*)d_in[5];
    const float* b_time = (const float*)d_in[6];
    const float* Wq     = (const float*)d_in[7];
    const float* bq     = (const float*)d_in[8];
    const float* Wk     = (const float*)d_in[9];
    const float* bk     = (const float*)d_in[10];
    const float* Wv     = (const float*)d_in[11];
    const float* bv     = (const float*)d_in[12];
    const float* Wo     = (const float*)d_in[13];
    const float* bo     = (const float*)d_in[14];
    const float* W1     = (const float*)d_in[15];
    const float* b1     = (const float*)d_in[16];
    const float* W2     = (const float*)d_in[17];
    const float* b2     = (const float*)d_in[18];
    const float* g1     = (const float*)d_in[19];
    const float* be1    = (const float*)d_in[20];
    const float* g2     = (const float*)d_in[21];
    const float* be2    = (const float*)d_in[22];
    const float* g_enc  = (const float*)d_in[23];
    const float* b_enc  = (const float*)d_in[24];
    const float* W_pre  = (const float*)d_in[25];
    const float* b_pre  = (const float*)d_in[26];
    const float* W_fc   = (const float*)d_in[27];
    const float* b_fc   = (const float*)d_in[28];
    float* out = (float*)d_out;

    char* ws = (char*)d_ws;
    u32*   hp   = (u32*)(ws);                        // 33.5 MB residual stream (pair)
    float* hf   = (float*)(ws + 33554432);           // 33.5 MB fp32 scratch (Wo/W2 out, final)
    char*  bigc = ws + 67108864;                     // 134.2 MB multi-use
    float* qkv  = (float*)bigc;                      // [TOK][1536] fp32 (100.7 MB)
    u32*   ctxP = (u32*)(bigc + 100663296);          // attn ctx pair (33.5 MB)
    u32*   midP = (u32*)bigc;                        // FFN mid pair [TOK][2048] (134.2 MB)
    // embed-stage overlays inside bigc:
    float* xln  = (float*)(bigc);                    // 2 MB
    u32*   acvP = (u32*)(bigc + 2097152);            // im2col pair [TOK][96], 6.3 MB
    float* pe   = (float*)(bigc + 8388608);          // 4 MB
    u32*   rsdP = (u32*)(bigc + 12582912);           // 33.5 MB
    u32*   wtok = (u32*)(bigc + 46137344);           // W_tok pair [512][96]
    u32*   wpair      = (u32*)(ws + 201326592);      // 12.6 MB per-layer weights
    float* Mbuf       = (float*)(ws + 213909504);    // 0.5 MB
    float* vmean      = (float*)(ws + 214433792);
    int*   idx_sample = (int*)(ws + 214450176);
    int*   idx_top    = (int*)(ws + 214843392);
    float* biasqkv    = (float*)(ws + 214849536);
    u64*   cand       = (u64*)(ws + 214855680);      // 98 KB
    float* opart      = (float*)(ws + 214953984);    // 1.57 MB
    float* mspart     = (float*)(ws + 216526848);    // 48 KB

    ln_in_kernel<<<TOK / 256, 256, 0, stream>>>(x, g_in, b_in, xln);
    im2col_kernel<<<TOK, 128, 0, stream>>>(xln, acvP);
    wtok_split<<<192, 256, 0, stream>>>(W_tok, wtok);
    pe_kernel<<<4096, 256, 0, stream>>>(pe);
    rsd_kernel<<<TOK, 256, 0, stream>>>(pe, tfeat, W_time, rsdP);
    sample_kernel<<<dim3(96, 2), 256, 0, stream>>>(idx_sample);

    // conv-as-GEMM: hp = pair(im2col @ W_tok^T + b_time + (pe + time emb))
    gemm_pp<false, true, true><<<dim3(4, 128), 256, 0, stream>>>(
        acvP, wtok, b_time, rsdP, nullptr, hp, DM, 96, 96);

    const u32* wqkv_p = wpair;                // rows 0..1535 = Wq;Wk;Wv
    const u32* wo_p = wpair + 786432;
    const u32* w1_p = wpair + 1048576;
    const u32* w2_p = wpair + 2097152;

    for (int li = 0; li < 2; li++) {
        split_weights<<<12288, 256, 0, stream>>>(
            Wq + (size_t)li * DM * DM, Wk + (size_t)li * DM * DM,
            Wv + (size_t)li * DM * DM, Wo + (size_t)li * DM * DM,
            W1 + (size_t)li * DFF * DM, W2 + (size_t)li * DM * DFF, wpair);
        concat_bias<<<6, 256, 0, stream>>>(bq + (size_t)li * DM, bk + (size_t)li * DM,
                                           bv + (size_t)li * DM, biasqkv);

        const float* bo_i = bo + (size_t)li * DM;
        const float* b1_i = b1 + (size_t)li * DFF;
        const float* b2_i = b2 + (size_t)li * DM;
        const float* g1_i = g1 + (size_t)li * DM;
        const float* be1_i = be1 + (size_t)li * DM;
        const float* g2_i = g2 + (size_t)li * DM;
        const float* be2_i = be2 + (size_t)li * DM;

        // fused QKV: [TOK][1536] fp32
        gemm_pp<false, false, false><<<dim3(QKVLD / 128, TOK / 128), 256, 0, stream>>>(
            hp, wqkv_p, biasqkv, nullptr, qkv, nullptr, QKVLD, DM, DM);

        qk_sample_kernel<<<(BATCH * NH * SEQ) / 4, 256, 0, stream>>>(
            qkv, idx_sample + li * SEQ * NSAMP, Mbuf);
        topk_part<<<dim3(BATCH * NH, 8), 256, 0, stream>>>(Mbuf, cand);
        topk_merge<<<BATCH * NH, 256, 0, stream>>>(cand, idx_top);
        hipMemsetAsync(vmean, 0, BATCH * NH * HD * sizeof(float), stream);
        vmean_kernel<<<dim3(BATCH * NH, 8), 256, 0, stream>>>(qkv, vmean);
        fillctx_kernel<<<(TOK * DM) / 256, 256, 0, stream>>>(vmean, ctxP);
        spattn_flash<<<dim3(BATCH * NH, 4), 256, 0, stream>>>(qkv, idx_top, opart, mspart);
        spattn_combine<<<BATCH * NH, 256, 0, stream>>>(opart, mspart, idx_top, ctxP);

        // Wo with pair-residual hp -> fp32 hf
        gemm_pp<false, true, false><<<dim3(DM / 128, TOK / 128), 256, 0, stream>>>(
            ctxP, wo_p, bo_i, hp, hf, nullptr, DM, DM, DM);
        ln_kernel<false, true><<<TOK / 4, 256, 0, stream>>>(hf, nullptr, g1_i, be1_i, nullptr, hp);

        // FFN: W1 -> mid pair; W2 + pair-residual hp -> fp32 hf
        gemm_pp<true, false, true><<<dim3(DFF / 128, TOK / 128), 256, 0, stream>>>(
            hp, w1_p, b1_i, nullptr, nullptr, midP, DFF, DM, DM);
        gemm_pp<false, true, false><<<dim3(DM / 128, TOK / 128), 256, 0, stream>>>(
            midP, w2_p, b2_i, hp, hf, nullptr, DM, DFF, DFF);
        ln_kernel<false, true><<<TOK / 4, 256, 0, stream>>>(hf, nullptr, g2_i, be2_i, nullptr, hp);
    }

    ln_kernel<true, false><<<TOK / 4, 256, 0, stream>>>(nullptr, hp, g_enc, b_enc, hf, nullptr);
    head_kernel<<<BATCH, 256, 0, stream>>>(hf, W_pre, b_pre, W_fc, b_fc, out);
}

// Round 13
// 1190.092 us; speedup vs baseline: 1.2874x; 1.0973x over previous
//
#include <hip/hip_runtime.h>
#include <math.h>

#define BATCH 8
#define SEQ   2048
#define TOK   (BATCH*SEQ)     // 16384
#define CIN   32
#define DM    512
#define DFF   2048
#define NH    8
#define HD    64
#define NSAMP 24
#define NTOP  24
#define EPS   1e-5f
#define QKVLD 1536

typedef unsigned int u32;
typedef unsigned short u16;
typedef unsigned long long u64;
typedef __attribute__((ext_vector_type(8))) short short8;
typedef __attribute__((ext_vector_type(4))) short short4v;
typedef __attribute__((ext_vector_type(4))) float floatx4;

__device__ __forceinline__ void async16(const void* g, void* l) {
    __builtin_amdgcn_global_load_lds((const __attribute__((address_space(1))) u32*)g,
                                     (__attribute__((address_space(3))) u32*)l, 16, 0, 0);
}
__device__ __forceinline__ u16 bf16rn(float f) {
    u32 u = __float_as_uint(f);
    return (u16)((u + 0x7fffu + ((u >> 16) & 1u)) >> 16);
}
// separated-group format: per row of K elems, group g=j>>3 at u16 offset g*16: [h0..h7][l0..l7]
__device__ __forceinline__ void sep_store(u16* base, size_t row, int ld2, int j, float v) {
    u16 hb = bf16rn(v);
    float r = v - __uint_as_float((u32)hb << 16);
    size_t o = row * (size_t)ld2 + (size_t)((j >> 3) << 4) + (j & 7);
    base[o] = hb;
    base[o + 8] = bf16rn(r);
}
__device__ __forceinline__ float sep_load(const u16* base, size_t row, int ld2, int j) {
    size_t o = row * (size_t)ld2 + (size_t)((j >> 3) << 4) + (j & 7);
    return __uint_as_float((u32)base[o] << 16) + __uint_as_float((u32)base[o + 8] << 16);
}
__device__ __forceinline__ float hl2f(u16 h, u16 l) {
    return __uint_as_float((u32)h << 16) + __uint_as_float((u32)l << 16);
}

// ---------------- Threefry-2x32 ----------------
__device__ __forceinline__ void tf_round(unsigned &x0, unsigned &x1, int r) {
    x0 += x1;
    x1 = (x1 << r) | (x1 >> (32 - r));
    x1 ^= x0;
}
__device__ __forceinline__ void threefry(unsigned k0, unsigned k1,
                                         unsigned c0, unsigned c1,
                                         unsigned &o0, unsigned &o1) {
    unsigned ks0 = k0, ks1 = k1, ks2 = k0 ^ k1 ^ 0x1BD11BDAu;
    unsigned x0 = c0 + ks0, x1 = c1 + ks1;
    tf_round(x0,x1,13); tf_round(x0,x1,15); tf_round(x0,x1,26); tf_round(x0,x1,6);
    x0 += ks1; x1 += ks2 + 1u;
    tf_round(x0,x1,17); tf_round(x0,x1,29); tf_round(x0,x1,16); tf_round(x0,x1,24);
    x0 += ks2; x1 += ks0 + 2u;
    tf_round(x0,x1,13); tf_round(x0,x1,15); tf_round(x0,x1,26); tf_round(x0,x1,6);
    x0 += ks0; x1 += ks1 + 3u;
    tf_round(x0,x1,17); tf_round(x0,x1,29); tf_round(x0,x1,16); tf_round(x0,x1,24);
    x0 += ks1; x1 += ks2 + 4u;
    tf_round(x0,x1,13); tf_round(x0,x1,15); tf_round(x0,x1,26); tf_round(x0,x1,6);
    x0 += ks2; x1 += ks0 + 5u;
    o0 = x0; o1 = x1;
}

__global__ void sample_kernel(int* __restrict__ idx_sample) {
    const int HALF = (SEQ * NSAMP) / 2;  // 24576
    int p = blockIdx.x * blockDim.x + threadIdx.x;
    int li = blockIdx.y;
    if (p >= HALF) return;
    unsigned f0, f1;
    threefry(0u, 42u, 0u, (unsigned)li, f0, f1);
    unsigned a0, a1, b0, b1;
    threefry(f0, f1, 0u, 2u, a0, a1);
    threefry(f0, f1, 1u, 3u, b0, b1);
    unsigned o0, o1;
    threefry(a1, b1, (unsigned)p, (unsigned)(p + HALF), o0, o1);
    idx_sample[li * SEQ * NSAMP + p]        = (int)(o0 & (SEQ - 1));
    idx_sample[li * SEQ * NSAMP + p + HALF] = (int)(o1 & (SEQ - 1));
}

// ---------------- input layernorm over C_IN=32 ----------------
__global__ __launch_bounds__(256) void ln_in_kernel(const float* __restrict__ x,
        const float* __restrict__ g, const float* __restrict__ b,
        float* __restrict__ out) {
    int t = blockIdx.x * blockDim.x + threadIdx.x;
    if (t >= TOK) return;
    const float* xr = x + (size_t)t * CIN;
    float vals[CIN];
    float s = 0.f;
#pragma unroll
    for (int c = 0; c < CIN; c++) { vals[c] = xr[c]; s += vals[c]; }
    float m = s * (1.f / CIN);
    float v = 0.f;
#pragma unroll
    for (int c = 0; c < CIN; c++) { float d = vals[c] - m; v += d * d; }
    v *= (1.f / CIN);
    float inv = rsqrtf(v + EPS);
    float* orow = out + (size_t)t * CIN;
#pragma unroll
    for (int c = 0; c < CIN; c++) orow[c] = (vals[c] - m) * inv * g[c] + b[c];
}

// ---------------- im2col (wrap pad) -> separated u16: A[t][j], j=w*32+c ----------------
__global__ __launch_bounds__(128) void im2col_kernel(const float* __restrict__ xln,
        u16* __restrict__ a) {
    int t = blockIdx.x;
    int j = threadIdx.x;
    if (j >= 96) return;
    int b = t >> 11, l = t & 2047;
    int w = j >> 5, c = j & 31;
    int lw = (l - 1 + w + SEQ) & 2047;
    sep_store(a, (size_t)t, 192, j, xln[(((size_t)b << 11) | lw) * CIN + c]);
}

// ---------------- W_tok transpose + split: wt[o][j] separated ----------------
__global__ __launch_bounds__(256) void wtok_split(const float* __restrict__ Wtok,
        u16* __restrict__ wt) {
    int e = blockIdx.x * 256 + threadIdx.x;  // < 49152
    int o = e / 96, j = e % 96;
    sep_store(wt, (size_t)o, 192, j, Wtok[(size_t)j * DM + o]);
}

// ---------------- positional embedding table pe[l][o] ----------------
__global__ __launch_bounds__(256) void pe_kernel(float* __restrict__ pe) {
    int e = blockIdx.x * 256 + threadIdx.x;  // < 1048576
    int l = e >> 9, o = e & 511;
    const float c1 = -0.017988946039016f;  // -ln(10000)/512
    int i2 = o & ~1;
    float div = expf((float)i2 * c1);
    float arg = (float)l * div;
    pe[e] = (o & 1) ? cosf(arg) : sinf(arg);
}

// ---------------- rsd[t][o] = sep(pe[l][o] + tf[t]·Wtime[o]) ----------------
__global__ __launch_bounds__(256) void rsd_kernel(const float* __restrict__ pe,
        const float* __restrict__ tfeat, const float* __restrict__ Wtime,
        u16* __restrict__ rsd) {
    int t = blockIdx.x, tid = threadIdx.x;
    int l = t & 2047;
    float t0 = tfeat[(size_t)t * 4], t1 = tfeat[(size_t)t * 4 + 1];
    float t2 = tfeat[(size_t)t * 4 + 2], t3 = tfeat[(size_t)t * 4 + 3];
    for (int o = tid; o < DM; o += 256) {
        float v = pe[l * DM + o]
            + t0 * Wtime[o * 4] + t1 * Wtime[o * 4 + 1]
            + t2 * Wtime[o * 4 + 2] + t3 * Wtime[o * 4 + 3];
        sep_store(rsd, (size_t)t, 1024, o, v);
    }
}

// ---------------- weight split -> separated u16 buffers ----------------
__global__ __launch_bounds__(256) void split_weights(const float* __restrict__ Wq,
        const float* __restrict__ Wk, const float* __restrict__ Wv,
        const float* __restrict__ Wo, const float* __restrict__ W1,
        const float* __restrict__ W2, u16* __restrict__ out) {
    int i = blockIdx.x * 256 + threadIdx.x;  // < 3145728
    if (i < 1048576) {
        const float* src = (i < 262144) ? Wq : (i < 524288) ? Wk : (i < 786432) ? Wv : Wo;
        int off = i & 262143;
        size_t base = (size_t)(i >> 18) * 524288;  // u16
        sep_store(out + base, (size_t)(off >> 9), 1024, off & 511, src[off]);
    } else if (i < 2097152) {
        int off = i - 1048576;
        sep_store(out + 2097152, (size_t)(off >> 9), 1024, off & 511, W1[off]);
    } else {
        int off = i - 2097152;
        sep_store(out + 4194304, (size_t)(off >> 11), 4096, off & 2047, W2[off]);
    }
}

__global__ void concat_bias(const float* __restrict__ bq, const float* __restrict__ bk,
                            const float* __restrict__ bv, float* __restrict__ o) {
    int i = blockIdx.x * 256 + threadIdx.x;  // < 1536
    o[i] = (i < 512) ? bq[i] : (i < 1024) ? bk[i - 512] : bv[i - 1024];
}

// ---------------- separated-u16 MFMA GEMM, double-buffered single-barrier ------------
// A,W in separated-group format; LDS row-major [row][chunk c'] with c' = c ^ (row&7)
// XOR swizzle (conflict <=2-way); fragments are direct ds_read_b128, zero unpack VALU.
template<bool RELU, bool RESP, bool OUTP>
__global__ __launch_bounds__(256, 2) void gemm_pp(const u16* __restrict__ Ap,
        const u16* __restrict__ Wp, const float* __restrict__ bias,
        const u16* __restrict__ RsdS, float* __restrict__ Cf, u16* __restrict__ Cp,
        int ldc, int K, int lda) {
    __shared__ alignas(16) u16 At[2][8192];   // [row 0..127][chunk 0..7][8 u16]
    __shared__ alignas(16) u16 Wt[2][8192];
    const int tid = threadIdx.x;
    int linear = blockIdx.y * gridDim.x + blockIdx.x;
    int xcd = linear & 7, sseq = linear >> 3;
    int mper = gridDim.y >> 3;
    int mt = xcd * mper + (sseq % mper);
    int nt = sseq / mper;
    const int m0 = mt * 128, n0 = nt * 128;
    const int lane = tid & 63, wv = tid >> 6;
    const int wm = wv >> 1, wn = wv & 1;
    const int fr = lane & 15, q = lane >> 4;

    floatx4 acc[4][4] = {};

    // staging: LDS 16B-slot p = tid + i*256 -> row = p>>3, c' = tid&7; global c = c'^(row&7)
    const int r0 = tid >> 3;
    const int gc = (tid & 7) ^ (r0 & 7);        // fixed across i (i*32 = 0 mod 8)
    const u16* abase = Ap + (size_t)(m0 + r0) * (2 * lda) + gc * 8;
    const u16* wbase = Wp + (size_t)(n0 + r0) * (2 * K) + gc * 8;
    const size_t astep = (size_t)32 * 2 * lda;  // +32 rows per i
    const size_t wstep = (size_t)32 * 2 * K;
    const int doff = tid * 16;                  // byte offset; +i*4096
    const int nk = K >> 5;

    // fragment offsets (u16 idx): row*64 + c'*8, c'_h = (2q)^(fr&7), c'_l = c'_h^1
    const int cph = ((q << 1) ^ (fr & 7)) << 3;
    const int cpl = ((q << 1) ^ (fr & 7) ^ 1) << 3;

    // prologue: stage tile 0 into buf 0
#pragma unroll
    for (int i = 0; i < 4; i++) {
        async16(abase + i * astep, (char*)At[0] + doff + i * 4096);
        async16(wbase + i * wstep, (char*)Wt[0] + doff + i * 4096);
    }

    for (int k = 0; k < nk; k++) {
        const int b = k & 1;
        __syncthreads();   // drains DMA issued a full MFMA phase ago
        if (k + 1 < nk) {
            int k2 = (k + 1) << 6;  // k0*2 in u16
#pragma unroll
            for (int i = 0; i < 4; i++) {
                async16(abase + k2 + i * astep, (char*)At[b ^ 1] + doff + i * 4096);
                async16(wbase + k2 + i * wstep, (char*)Wt[b ^ 1] + doff + i * 4096);
            }
        }
        short8 ah[4], al[4];
#pragma unroll
        for (int mi = 0; mi < 4; mi++) {
            int r = wm * 64 + mi * 16 + fr;
            ah[mi] = *(const short8*)&At[b][r * 64 + cph];
            al[mi] = *(const short8*)&At[b][r * 64 + cpl];
        }
#pragma unroll
        for (int ni = 0; ni < 4; ni++) {
            int r = wn * 64 + ni * 16 + fr;
            short8 wh8 = *(const short8*)&Wt[b][r * 64 + cph];
            short8 wl8 = *(const short8*)&Wt[b][r * 64 + cpl];
#pragma unroll
            for (int mi = 0; mi < 4; mi++) {
                acc[mi][ni] = __builtin_amdgcn_mfma_f32_16x16x32_bf16(ah[mi], wh8, acc[mi][ni], 0, 0, 0);
                acc[mi][ni] = __builtin_amdgcn_mfma_f32_16x16x32_bf16(ah[mi], wl8, acc[mi][ni], 0, 0, 0);
                acc[mi][ni] = __builtin_amdgcn_mfma_f32_16x16x32_bf16(al[mi], wh8, acc[mi][ni], 0, 0, 0);
            }
        }
    }
    // --- epilogue ---
#pragma unroll
    for (int ni = 0; ni < 4; ni++) {
        int col = n0 + wn * 64 + ni * 16 + fr;
        float bv = bias[col];
#pragma unroll
        for (int mi = 0; mi < 4; mi++) {
            int row = m0 + wm * 64 + mi * 16 + q * 4;
#pragma unroll
            for (int r = 0; r < 4; r++) {
                float v = acc[mi][ni][r] + bv;
                if (RESP) v += sep_load(RsdS, (size_t)(row + r), 2 * ldc, col);
                if (RELU) v = fmaxf(v, 0.f);
                if (OUTP) sep_store(Cp, (size_t)(row + r), 2 * ldc, col, v);
                else      Cf[(size_t)(row + r) * ldc + col] = v;
            }
        }
    }
}

// ---------------- M = max(QK_sample) - sum/L : one wave per (b,h,l) ----------------
__global__ __launch_bounds__(256) void qk_sample_kernel(const float* __restrict__ qkv,
        const int* __restrict__ idx_sample, float* __restrict__ Mout) {
    int r = (blockIdx.x * 256 + threadIdx.x) >> 6;
    int lane = threadIdx.x & 63;
    if (r >= BATCH * NH * SEQ) return;
    int b = r / (NH * SEQ);
    int head = (r / SEQ) % NH;
    int l = r % SEQ;
    int sidx = lane >> 4, dc = lane & 15;
    const float* qrow = qkv + ((size_t)(b * SEQ + l)) * QKVLD + head * HD + dc * 4;
    float4 qf = *(const float4*)qrow;
    int myidx = (lane < NSAMP) ? idx_sample[l * NSAMP + lane] : 0;
    const float* kbase = qkv + (size_t)b * SEQ * QKVLD + 512 + head * HD + dc * 4;
    int kidx[6];
#pragma unroll
    for (int p = 0; p < 6; p++) kidx[p] = __shfl(myidx, p * 4 + sidx);
    float4 kf[6];
#pragma unroll
    for (int p = 0; p < 6; p++) kf[p] = *(const float4*)(kbase + (size_t)kidx[p] * QKVLD);
    float mx = -INFINITY, sm = 0.f;
#pragma unroll
    for (int p = 0; p < 6; p++) {
        float part = qf.x * kf[p].x + qf.y * kf[p].y + qf.z * kf[p].z + qf.w * kf[p].w;
        part += __shfl_xor(part, 1);
        part += __shfl_xor(part, 2);
        part += __shfl_xor(part, 4);
        part += __shfl_xor(part, 8);
        mx = fmaxf(mx, part);
        sm += part;
    }
    mx = fmaxf(mx, __shfl_xor(mx, 16));
    mx = fmaxf(mx, __shfl_xor(mx, 32));
    sm += __shfl_xor(sm, 16);
    sm += __shfl_xor(sm, 32);
    if (lane == 0) Mout[r] = mx - sm * (1.f / SEQ);
}

// ---------------- top-24: register keys + wave shuffle reduce ----------------
__device__ __forceinline__ u64 pack_key(float v, int idx) {
    u32 u = __float_as_uint(v);
    u32 m = (u & 0x80000000u) ? ~u : (u | 0x80000000u);
    return ((u64)m << 32) | (u32)(~(u32)idx);
}

__global__ __launch_bounds__(256) void topk_part(const float* __restrict__ Mbuf,
        u64* __restrict__ cand) {
    __shared__ u64 wred[4];
    int bh = blockIdx.x, chunk = blockIdx.y;
    int tid = threadIdx.x, wv = tid >> 6, lane = tid & 63;
    int l = chunk * 256 + tid;
    u64 val = pack_key(Mbuf[(size_t)bh * SEQ + l], l);
    for (int it = 0; it < NTOP; it++) {
        u64 w = val;
#pragma unroll
        for (int off = 32; off > 0; off >>= 1) {
            u64 o = __shfl_xor(w, off);
            if (o > w) w = o;
        }
        if (lane == 0) wred[wv] = w;
        __syncthreads();
        u64 win = wred[0];
        if (wred[1] > win) win = wred[1];
        if (wred[2] > win) win = wred[2];
        if (wred[3] > win) win = wred[3];
        if (val == win) val = 0;
        if (tid == 0) cand[((size_t)bh * 8 + chunk) * NTOP + it] = win;
        __syncthreads();
    }
}

__global__ __launch_bounds__(256) void topk_merge(const u64* __restrict__ cand,
        int* __restrict__ idx_top) {
    __shared__ u64 wred[4];
    int bh = blockIdx.x;
    int tid = threadIdx.x, wv = tid >> 6, lane = tid & 63;
    u64 val = (tid < 8 * NTOP) ? cand[(size_t)bh * 8 * NTOP + tid] : 0;
    for (int it = 0; it < NTOP; it++) {
        u64 w = val;
#pragma unroll
        for (int off = 32; off > 0; off >>= 1) {
            u64 o = __shfl_xor(w, off);
            if (o > w) w = o;
        }
        if (lane == 0) wred[wv] = w;
        __syncthreads();
        u64 win = wred[0];
        if (wred[1] > win) win = wred[1];
        if (wred[2] > win) win = wred[2];
        if (wred[3] > win) win = wred[3];
        if (val == win) val = 0;
        if (tid == 0) idx_top[bh * NTOP + it] = (int)(~(u32)(win & 0xffffffffull) & (SEQ - 1));
        __syncthreads();
    }
}

// ---------------- V mean over keys per (b,h) ----------------
__global__ __launch_bounds__(256) void vmean_kernel(const float* __restrict__ qkv,
        float* __restrict__ vmean) {
    __shared__ float red[256];
    int bh = blockIdx.x, slab = blockIdx.y;
    int b = bh >> 3, head = bh & 7;
    int seg = threadIdx.x >> 6, d = threadIdx.x & 63;
    int base_row = slab * 256 + seg * 64;
    float s = 0.f;
    for (int r = 0; r < 64; r++)
        s += qkv[((size_t)(b * SEQ + base_row + r)) * QKVLD + 1024 + head * HD + d];
    red[threadIdx.x] = s;
    __syncthreads();
    if (threadIdx.x < 128) red[threadIdx.x] += red[threadIdx.x + 128];
    __syncthreads();
    if (threadIdx.x < 64) {
        float t = red[threadIdx.x] + red[threadIdx.x + 64];
        atomicAdd(&vmean[bh * HD + d], t * (1.f / SEQ));
    }
}

// ---------------- fill context (separated u16) with V-mean: thread = one group ---------
__global__ void fillctx_kernel(const float* __restrict__ vmean, u16* __restrict__ out) {
    int e = blockIdx.x * 256 + threadIdx.x;   // < TOK*64
    int t = e >> 6, g = e & 63;
    const float* vm = vmean + ((((t >> 11) << 3) | (g >> 3)) << 6) + (g & 7) * 8;
    short8 hh, ll;
#pragma unroll
    for (int s = 0; s < 8; s++) {
        float v = vm[s];
        u16 hb = bf16rn(v);
        hh[s] = (short)hb;
        ll[s] = (short)bf16rn(v - __uint_as_float((u32)hb << 16));
    }
    u16* dp = out + (size_t)t * 1024 + g * 16;
    *(short8*)dp = hh;
    *(short8*)(dp + 8) = ll;
}

// ---------------- flash-style sparse attention: block = (b*h, key-slab of 512) ----------------
__global__ __launch_bounds__(256) void spattn_flash(const float* __restrict__ qkv,
        const int* __restrict__ idx_top, float* __restrict__ opart,
        float* __restrict__ mspart) {
    __shared__ float KtT[64][65];   // transposed: [dim][key]
    __shared__ float Vt[64][65];    // [key][dim]
    __shared__ float Qs[24][64];
    __shared__ float Ps[24][66];
    int bh = blockIdx.x, slab = blockIdx.y;
    int b = bh >> 3, h = bh & 7;
    int tid = threadIdx.x;
    int wv = tid >> 6, lane = tid & 63;
    for (int i = tid; i < NTOP * 64; i += 256) {
        int u = i >> 6, d = i & 63;
        int qi = idx_top[bh * NTOP + u];
        Qs[u][d] = qkv[((size_t)(b * SEQ + qi)) * QKVLD + h * HD + d];
    }
    float m[6], s[6], o[6], alpha[6];
#pragma unroll
    for (int j = 0; j < 6; j++) { m[j] = -INFINITY; s[j] = 0.f; o[j] = 0.f; }
    int key0 = slab * 512;
    int sr = tid >> 2, sc0 = (tid & 3) * 16;
    for (int t = 0; t < 8; t++) {
        int kbase = key0 + t * 64;
        __syncthreads();
        const float* kr = qkv + ((size_t)(b * SEQ + kbase + sr)) * QKVLD + 512 + h * HD + sc0;
        const float* vr = qkv + ((size_t)(b * SEQ + kbase + sr)) * QKVLD + 1024 + h * HD + sc0;
        float kf[16], vf[16];
        *(float4*)&kf[0]  = *(const float4*)(kr);
        *(float4*)&kf[4]  = *(const float4*)(kr + 4);
        *(float4*)&kf[8]  = *(const float4*)(kr + 8);
        *(float4*)&kf[12] = *(const float4*)(kr + 12);
        *(float4*)&vf[0]  = *(const float4*)(vr);
        *(float4*)&vf[4]  = *(const float4*)(vr + 4);
        *(float4*)&vf[8]  = *(const float4*)(vr + 8);
        *(float4*)&vf[12] = *(const float4*)(vr + 12);
#pragma unroll
        for (int i = 0; i < 16; i++) {
            KtT[sc0 + i][sr] = kf[i];
            Vt[sr][sc0 + i] = vf[i];
        }
        __syncthreads();
        float dot[6] = {};
#pragma unroll
        for (int d = 0; d < 64; d++) {
            float kv = KtT[d][lane];
#pragma unroll
            for (int j = 0; j < 6; j++) dot[j] += Qs[wv * 6 + j][d] * kv;
        }
#pragma unroll
        for (int j = 0; j < 6; j++) {
            float sc = dot[j] * 0.125f;
            float tmax = sc;
            for (int off = 32; off > 0; off >>= 1) tmax = fmaxf(tmax, __shfl_xor(tmax, off));
            float mn = fmaxf(m[j], tmax);
            float p = __expf(sc - mn);
            float psum = p;
            for (int off = 32; off > 0; off >>= 1) psum += __shfl_xor(psum, off);
            alpha[j] = __expf(m[j] - mn);
            s[j] = s[j] * alpha[j] + psum;
            m[j] = mn;
            Ps[wv * 6 + j][lane] = p;
        }
        float pv[6] = {};
#pragma unroll
        for (int key = 0; key < 64; key++) {
            float vvv = Vt[key][lane];
#pragma unroll
            for (int j = 0; j < 6; j++) pv[j] += Ps[wv * 6 + j][key] * vvv;
        }
#pragma unroll
        for (int j = 0; j < 6; j++) o[j] = o[j] * alpha[j] + pv[j];
    }
    float* ob = opart + ((size_t)(bh * 4 + slab)) * NTOP * 64;
#pragma unroll
    for (int j = 0; j < 6; j++) ob[(wv * 6 + j) * 64 + lane] = o[j];
    if (lane == 0) {
        float* ms = mspart + ((size_t)(bh * 4 + slab)) * NTOP * 2;
#pragma unroll
        for (int j = 0; j < 6; j++) {
            ms[(wv * 6 + j) * 2]     = m[j];
            ms[(wv * 6 + j) * 2 + 1] = s[j];
        }
    }
}

// ---------------- merge 4 slab partials, scatter (separated u16) into context ----------
__global__ __launch_bounds__(256) void spattn_combine(const float* __restrict__ opart,
        const float* __restrict__ mspart, const int* __restrict__ idx_top,
        u16* __restrict__ out) {
    __shared__ float wgt[4][NTOP];
    int bh = blockIdx.x;
    int b = bh >> 3, h = bh & 7;
    int tid = threadIdx.x;
    if (tid < NTOP) {
        float mv[4], sv[4];
        float M = -INFINITY;
#pragma unroll
        for (int sl = 0; sl < 4; sl++) {
            mv[sl] = mspart[((size_t)(bh * 4 + sl)) * NTOP * 2 + tid * 2];
            sv[sl] = mspart[((size_t)(bh * 4 + sl)) * NTOP * 2 + tid * 2 + 1];
            M = fmaxf(M, mv[sl]);
        }
        float S = 0.f;
#pragma unroll
        for (int sl = 0; sl < 4; sl++) S += sv[sl] * __expf(mv[sl] - M);
        float invS = 1.f / S;
#pragma unroll
        for (int sl = 0; sl < 4; sl++) wgt[sl][tid] = __expf(mv[sl] - M) * invS;
    }
    __syncthreads();
    for (int i = tid; i < NTOP * 64; i += 256) {
        int u = i >> 6, d = i & 63;
        float val = 0.f;
#pragma unroll
        for (int sl = 0; sl < 4; sl++)
            val += wgt[sl][u] * opart[(((size_t)(bh * 4 + sl)) * NTOP + u) * 64 + d];
        int qi = idx_top[bh * NTOP + u];
        sep_store(out, (size_t)(b * SEQ + qi), 1024, h * HD + d, val);
    }
}

// ---------------- layernorm over DM=512: one wave per row; sep in/out options ----------
template<bool INP, bool OUTSEP>
__global__ __launch_bounds__(256) void ln_kernel(const float* __restrict__ srcF,
        const u16* __restrict__ srcS, const float* __restrict__ g,
        const float* __restrict__ b, float* __restrict__ dstF, u16* __restrict__ dstS) {
    int wv = threadIdx.x >> 6, lane = threadIdx.x & 63;
    int t = blockIdx.x * 4 + wv;
    float xv[8];
    if (INP) {
        const u16* sp = srcS + (size_t)t * 1024 + (lane >> 1) * 16 + (lane & 1) * 4;
        short4v h0 = *(const short4v*)sp;
        short4v l0 = *(const short4v*)(sp + 8);
        short4v h1 = *(const short4v*)(sp + 512);
        short4v l1 = *(const short4v*)(sp + 520);
#pragma unroll
        for (int i = 0; i < 4; i++) {
            xv[i]     = hl2f((u16)h0[i], (u16)l0[i]);
            xv[i + 4] = hl2f((u16)h1[i], (u16)l1[i]);
        }
    } else {
        float4 x0 = *(const float4*)&srcF[(size_t)t * DM + lane * 4];
        float4 x1 = *(const float4*)&srcF[(size_t)t * DM + lane * 4 + 256];
        xv[0] = x0.x; xv[1] = x0.y; xv[2] = x0.z; xv[3] = x0.w;
        xv[4] = x1.x; xv[5] = x1.y; xv[6] = x1.z; xv[7] = x1.w;
    }
    float s = 0.f, s2 = 0.f;
#pragma unroll
    for (int i = 0; i < 8; i++) { s += xv[i]; s2 += xv[i] * xv[i]; }
#pragma unroll
    for (int off = 32; off > 0; off >>= 1) {
        s  += __shfl_xor(s, off);
        s2 += __shfl_xor(s2, off);
    }
    float m = s * (1.f / DM);
    float var = s2 * (1.f / DM) - m * m;
    float inv = rsqrtf(var + EPS);
    float4 g0 = *(const float4*)&g[lane * 4];
    float4 g1 = *(const float4*)&g[lane * 4 + 256];
    float4 b0 = *(const float4*)&b[lane * 4];
    float4 b1 = *(const float4*)&b[lane * 4 + 256];
    float y[8];
    y[0] = (xv[0] - m) * inv * g0.x + b0.x;  y[1] = (xv[1] - m) * inv * g0.y + b0.y;
    y[2] = (xv[2] - m) * inv * g0.z + b0.z;  y[3] = (xv[3] - m) * inv * g0.w + b0.w;
    y[4] = (xv[4] - m) * inv * g1.x + b1.x;  y[5] = (xv[5] - m) * inv * g1.y + b1.y;
    y[6] = (xv[6] - m) * inv * g1.z + b1.z;  y[7] = (xv[7] - m) * inv * g1.w + b1.w;
    if (OUTSEP) {
        u16* dp = dstS + (size_t)t * 1024 + (lane >> 1) * 16 + (lane & 1) * 4;
        short4v hh0, ll0, hh1, ll1;
#pragma unroll
        for (int i = 0; i < 4; i++) {
            u16 hb = bf16rn(y[i]);
            hh0[i] = (short)hb;
            ll0[i] = (short)bf16rn(y[i] - __uint_as_float((u32)hb << 16));
            u16 hb2 = bf16rn(y[i + 4]);
            hh1[i] = (short)hb2;
            ll1[i] = (short)bf16rn(y[i + 4] - __uint_as_float((u32)hb2 << 16));
        }
        *(short4v*)dp = hh0;
        *(short4v*)(dp + 8) = ll0;
        *(short4v*)(dp + 512) = hh1;
        *(short4v*)(dp + 520) = ll1;
    } else {
        float4 o0 = { y[0], y[1], y[2], y[3] };
        float4 o1 = { y[4], y[5], y[6], y[7] };
        *(float4*)&dstF[(size_t)t * DM + lane * 4] = o0;
        *(float4*)&dstF[(size_t)t * DM + lane * 4 + 256] = o1;
    }
}

// ---------------- prediction head on last token ----------------
__global__ __launch_bounds__(256) void head_kernel(const float* __restrict__ hfin,
        const float* __restrict__ Wpre, const float* __restrict__ bpre,
        const float* __restrict__ Wfc, const float* __restrict__ bfc,
        float* __restrict__ out) {
    __shared__ float last[DM];
    __shared__ float red[256];
    int b = blockIdx.x, tid = threadIdx.x;
    const float* hr = hfin + ((size_t)(b * SEQ + SEQ - 1)) * DM;
    last[tid] = hr[tid];
    last[tid + 256] = hr[tid + 256];
    __syncthreads();
    float acc = bpre[tid];
    for (int c = 0; c < DM; c++) acc += last[c] * Wpre[tid * DM + c];
    acc = fmaxf(acc, 0.f);
    red[tid] = acc * Wfc[tid];
    __syncthreads();
    for (int s = 128; s > 0; s >>= 1) { if (tid < s) red[tid] += red[tid + s]; __syncthreads(); }
    if (tid == 0) out[b] = red[0] + bfc[0];
}

extern "C" void kernel_launch(void* const* d_in, const int* in_sizes, int n_in,
                              void* d_out, int out_size, void* d_ws, size_t ws_size,
                              hipStream_t stream) {
    (void)in_sizes; (void)n_in; (void)out_size; (void)ws_size;
    const float* x      = (const float*)d_in[0];
    const float* tfeat  = (const float*)d_in[1];
    const float* g_in   = (const float*)d_in[2];
    const float* b_in   = (const float*)d_in[3];
    const float* W_tok  = (const float*)d_in[4];
    const float* W_time = (const float*)d_in[5];
    const float* b_time = (const float*)d_in[6];
    const float* Wq     = (const float*)d_in[7];
    const float* bq     = (const float*)d_in[8];
    const float* Wk     = (const float*)d_in[9];
    const float* bk     = (const float*)d_in[10];
    const float* Wv     = (const float*)d_in[11];
    const float* bv     = (const float*)d_in[12];
    const float* Wo     = (const float*)d_in[13];
    const float* bo     = (const float*)d_in[14];
    const float* W1     = (const float*)d_in[15];
    const float* b1     = (const float*)d_in[16];
    const float* W2     = (const float*)d_in[17];
    const float* b2     = (const float*)d_in[18];
    const float* g1     = (const float*)d_in[19];
    const float* be1    = (const float*)d_in[20];
    const float* g2     = (const float*)d_in[21];
    const float* be2    = (const float*)d_in[22];
    const float* g_enc  = (const float*)d_in[23];
    const float* b_enc  = (const float*)d_in[24];
    const float* W_pre  = (const float*)d_in[25];
    const float* b_pre  = (const float*)d_in[26];
    const float* W_fc   = (const float*)d_in[27];
    const float* b_fc   = (const float*)d_in[28];
    float* out = (float*)d_out;

    char* ws = (char*)d_ws;
    u16*   hp   = (u16*)(ws);                        // 33.5 MB residual stream (separated)
    float* hf   = (float*)(ws + 33554432);           // 33.5 MB fp32 scratch
    char*  bigc = ws + 67108864;                     // 134.2 MB multi-use
    float* qkv  = (float*)bigc;                      // [TOK][1536] fp32 (100.7 MB)
    u16*   ctxP = (u16*)(bigc + 100663296);          // attn ctx separated (33.5 MB)
    u16*   midP = (u16*)bigc;                        // FFN mid separated [TOK][2*2048] u16
    // embed-stage overlays inside bigc:
    float* xln  = (float*)(bigc);                    // 2 MB
    u16*   acvP = (u16*)(bigc + 2097152);            // im2col separated [TOK][192] u16
    float* pe   = (float*)(bigc + 8388608);          // 4 MB
    u16*   rsdS = (u16*)(bigc + 12582912);           // 33.5 MB
    u16*   wtok = (u16*)(bigc + 46137344);           // W_tok separated [512][192] u16
    u16*   wsep       = (u16*)(ws + 201326592);      // 12.6 MB per-layer weights
    float* Mbuf       = (float*)(ws + 213909504);    // 0.5 MB
    float* vmean      = (float*)(ws + 214433792);
    int*   idx_sample = (int*)(ws + 214450176);
    int*   idx_top    = (int*)(ws + 214843392);
    float* biasqkv    = (float*)(ws + 214849536);
    u64*   cand       = (u64*)(ws + 214855680);      // 98 KB
    float* opart      = (float*)(ws + 214953984);    // 1.57 MB
    float* mspart     = (float*)(ws + 216526848);    // 48 KB

    ln_in_kernel<<<TOK / 256, 256, 0, stream>>>(x, g_in, b_in, xln);
    im2col_kernel<<<TOK, 128, 0, stream>>>(xln, acvP);
    wtok_split<<<192, 256, 0, stream>>>(W_tok, wtok);
    pe_kernel<<<4096, 256, 0, stream>>>(pe);
    rsd_kernel<<<TOK, 256, 0, stream>>>(pe, tfeat, W_time, rsdS);
    sample_kernel<<<dim3(96, 2), 256, 0, stream>>>(idx_sample);

    // conv-as-GEMM: hp = sep(im2col @ W_tok^T + b_time + (pe + time emb))
    gemm_pp<false, true, true><<<dim3(4, 128), 256, 0, stream>>>(
        acvP, wtok, b_time, rsdS, nullptr, hp, DM, 96, 96);

    const u16* wqkv_p = wsep;                 // rows 0..1535 = Wq;Wk;Wv (K=512)
    const u16* wo_p = wsep + 1572864;
    const u16* w1_p = wsep + 2097152;
    const u16* w2_p = wsep + 4194304;

    for (int li = 0; li < 2; li++) {
        split_weights<<<12288, 256, 0, stream>>>(
            Wq + (size_t)li * DM * DM, Wk + (size_t)li * DM * DM,
            Wv + (size_t)li * DM * DM, Wo + (size_t)li * DM * DM,
            W1 + (size_t)li * DFF * DM, W2 + (size_t)li * DM * DFF, wsep);
        concat_bias<<<6, 256, 0, stream>>>(bq + (size_t)li * DM, bk + (size_t)li * DM,
                                           bv + (size_t)li * DM, biasqkv);

        const float* bo_i = bo + (size_t)li * DM;
        const float* b1_i = b1 + (size_t)li * DFF;
        const float* b2_i = b2 + (size_t)li * DM;
        const float* g1_i = g1 + (size_t)li * DM;
        const float* be1_i = be1 + (size_t)li * DM;
        const float* g2_i = g2 + (size_t)li * DM;
        const float* be2_i = be2 + (size_t)li * DM;

        // fused QKV: [TOK][1536] fp32
        gemm_pp<false, false, false><<<dim3(QKVLD / 128, TOK / 128), 256, 0, stream>>>(
            hp, wqkv_p, biasqkv, nullptr, qkv, nullptr, QKVLD, DM, DM);

        qk_sample_kernel<<<(BATCH * NH * SEQ) / 4, 256, 0, stream>>>(
            qkv, idx_sample + li * SEQ * NSAMP, Mbuf);
        topk_part<<<dim3(BATCH * NH, 8), 256, 0, stream>>>(Mbuf, cand);
        topk_merge<<<BATCH * NH, 256, 0, stream>>>(cand, idx_top);
        hipMemsetAsync(vmean, 0, BATCH * NH * HD * sizeof(float), stream);
        vmean_kernel<<<dim3(BATCH * NH, 8), 256, 0, stream>>>(qkv, vmean);
        fillctx_kernel<<<(TOK * 64) / 256, 256, 0, stream>>>(vmean, ctxP);
        spattn_flash<<<dim3(BATCH * NH, 4), 256, 0, stream>>>(qkv, idx_top, opart, mspart);
        spattn_combine<<<BATCH * NH, 256, 0, stream>>>(opart, mspart, idx_top, ctxP);

        // Wo with sep-residual hp -> fp32 hf
        gemm_pp<false, true, false><<<dim3(DM / 128, TOK / 128), 256, 0, stream>>>(
            ctxP, wo_p, bo_i, hp, hf, nullptr, DM, DM, DM);
        ln_kernel<false, true><<<TOK / 4, 256, 0, stream>>>(hf, nullptr, g1_i, be1_i, nullptr, hp);

        // FFN: W1 -> mid sep; W2 + sep-residual hp -> fp32 hf
        gemm_pp<true, false, true><<<dim3(DFF / 128, TOK / 128), 256, 0, stream>>>(
            hp, w1_p, b1_i, nullptr, nullptr, midP, DFF, DM, DM);
        gemm_pp<false, true, false><<<dim3(DM / 128, TOK / 128), 256, 0, stream>>>(
            midP, w2_p, b2_i, hp, hf, nullptr, DM, DFF, DFF);
        ln_kernel<false, true><<<TOK / 4, 256, 0, stream>>>(hf, nullptr, g2_i, be2_i, nullptr, hp);
    }

    ln_kernel<true, false><<<TOK / 4, 256, 0, stream>>>(nullptr, hp, g_enc, b_enc, hf, nullptr);
    head_kernel<<<BATCH, 256, 0, stream>>>(hf, W_pre, b_pre, W_fc, b_fc, out);
}

// Round 14
// 1154.727 us; speedup vs baseline: 1.3268x; 1.0306x over previous
//
#include <hip/hip_runtime.h>
#include <math.h>

#define BATCH 8
#define SEQ   2048
#define TOK   (BATCH*SEQ)     // 16384
#define CIN   32
#define DM    512
#define DFF   2048
#define NH    8
#define HD    64
#define NSAMP 24
#define NTOP  24
#define EPS   1e-5f
#define QKVLD 1536

typedef unsigned int u32;
typedef unsigned short u16;
typedef unsigned long long u64;
typedef __attribute__((ext_vector_type(8))) short short8;
typedef __attribute__((ext_vector_type(4))) short short4v;
typedef __attribute__((ext_vector_type(4))) float floatx4;

__device__ __forceinline__ void async16(const void* g, void* l) {
    __builtin_amdgcn_global_load_lds((const __attribute__((address_space(1))) u32*)g,
                                     (__attribute__((address_space(3))) u32*)l, 16, 0, 0);
}
__device__ __forceinline__ u16 bf16rn(float f) {
    u32 u = __float_as_uint(f);
    return (u16)((u + 0x7fffu + ((u >> 16) & 1u)) >> 16);
}
// separated-group format: per row of K elems, group g=j>>3 at u16 offset g*16: [h0..h7][l0..l7]
__device__ __forceinline__ void sep_store(u16* base, size_t row, int ld2, int j, float v) {
    u16 hb = bf16rn(v);
    float r = v - __uint_as_float((u32)hb << 16);
    size_t o = row * (size_t)ld2 + (size_t)((j >> 3) << 4) + (j & 7);
    base[o] = hb;
    base[o + 8] = bf16rn(r);
}
__device__ __forceinline__ float sep_load(const u16* base, size_t row, int ld2, int j) {
    size_t o = row * (size_t)ld2 + (size_t)((j >> 3) << 4) + (j & 7);
    return __uint_as_float((u32)base[o] << 16) + __uint_as_float((u32)base[o + 8] << 16);
}
__device__ __forceinline__ float hl2f(u16 h, u16 l) {
    return __uint_as_float((u32)h << 16) + __uint_as_float((u32)l << 16);
}

// ---------------- Threefry-2x32 ----------------
__device__ __forceinline__ void tf_round(unsigned &x0, unsigned &x1, int r) {
    x0 += x1;
    x1 = (x1 << r) | (x1 >> (32 - r));
    x1 ^= x0;
}
__device__ __forceinline__ void threefry(unsigned k0, unsigned k1,
                                         unsigned c0, unsigned c1,
                                         unsigned &o0, unsigned &o1) {
    unsigned ks0 = k0, ks1 = k1, ks2 = k0 ^ k1 ^ 0x1BD11BDAu;
    unsigned x0 = c0 + ks0, x1 = c1 + ks1;
    tf_round(x0,x1,13); tf_round(x0,x1,15); tf_round(x0,x1,26); tf_round(x0,x1,6);
    x0 += ks1; x1 += ks2 + 1u;
    tf_round(x0,x1,17); tf_round(x0,x1,29); tf_round(x0,x1,16); tf_round(x0,x1,24);
    x0 += ks2; x1 += ks0 + 2u;
    tf_round(x0,x1,13); tf_round(x0,x1,15); tf_round(x0,x1,26); tf_round(x0,x1,6);
    x0 += ks0; x1 += ks1 + 3u;
    tf_round(x0,x1,17); tf_round(x0,x1,29); tf_round(x0,x1,16); tf_round(x0,x1,24);
    x0 += ks1; x1 += ks2 + 4u;
    tf_round(x0,x1,13); tf_round(x0,x1,15); tf_round(x0,x1,26); tf_round(x0,x1,6);
    x0 += ks2; x1 += ks0 + 5u;
    o0 = x0; o1 = x1;
}

__global__ void sample_kernel(int* __restrict__ idx_sample) {
    const int HALF = (SEQ * NSAMP) / 2;  // 24576
    int p = blockIdx.x * blockDim.x + threadIdx.x;
    int li = blockIdx.y;
    if (p >= HALF) return;
    unsigned f0, f1;
    threefry(0u, 42u, 0u, (unsigned)li, f0, f1);
    unsigned a0, a1, b0, b1;
    threefry(f0, f1, 0u, 2u, a0, a1);
    threefry(f0, f1, 1u, 3u, b0, b1);
    unsigned o0, o1;
    threefry(a1, b1, (unsigned)p, (unsigned)(p + HALF), o0, o1);
    idx_sample[li * SEQ * NSAMP + p]        = (int)(o0 & (SEQ - 1));
    idx_sample[li * SEQ * NSAMP + p + HALF] = (int)(o1 & (SEQ - 1));
}

// ---------------- input layernorm over C_IN=32 ----------------
__global__ __launch_bounds__(256) void ln_in_kernel(const float* __restrict__ x,
        const float* __restrict__ g, const float* __restrict__ b,
        float* __restrict__ out) {
    int t = blockIdx.x * blockDim.x + threadIdx.x;
    if (t >= TOK) return;
    const float* xr = x + (size_t)t * CIN;
    float vals[CIN];
    float s = 0.f;
#pragma unroll
    for (int c = 0; c < CIN; c++) { vals[c] = xr[c]; s += vals[c]; }
    float m = s * (1.f / CIN);
    float v = 0.f;
#pragma unroll
    for (int c = 0; c < CIN; c++) { float d = vals[c] - m; v += d * d; }
    v *= (1.f / CIN);
    float inv = rsqrtf(v + EPS);
    float* orow = out + (size_t)t * CIN;
#pragma unroll
    for (int c = 0; c < CIN; c++) orow[c] = (vals[c] - m) * inv * g[c] + b[c];
}

// ---------------- im2col (wrap pad) -> separated u16: A[t][j], j=w*32+c ----------------
__global__ __launch_bounds__(128) void im2col_kernel(const float* __restrict__ xln,
        u16* __restrict__ a) {
    int t = blockIdx.x;
    int j = threadIdx.x;
    if (j >= 96) return;
    int b = t >> 11, l = t & 2047;
    int w = j >> 5, c = j & 31;
    int lw = (l - 1 + w + SEQ) & 2047;
    sep_store(a, (size_t)t, 192, j, xln[(((size_t)b << 11) | lw) * CIN + c]);
}

// ---------------- W_tok transpose + split: wt[o][j] separated ----------------
__global__ __launch_bounds__(256) void wtok_split(const float* __restrict__ Wtok,
        u16* __restrict__ wt) {
    int e = blockIdx.x * 256 + threadIdx.x;  // < 49152
    int o = e / 96, j = e % 96;
    sep_store(wt, (size_t)o, 192, j, Wtok[(size_t)j * DM + o]);
}

// ---------------- positional embedding table pe[l][o] ----------------
__global__ __launch_bounds__(256) void pe_kernel(float* __restrict__ pe) {
    int e = blockIdx.x * 256 + threadIdx.x;  // < 1048576
    int l = e >> 9, o = e & 511;
    const float c1 = -0.017988946039016f;  // -ln(10000)/512
    int i2 = o & ~1;
    float div = expf((float)i2 * c1);
    float arg = (float)l * div;
    pe[e] = (o & 1) ? cosf(arg) : sinf(arg);
}

// ---------------- rsd[t][o] = sep(pe[l][o] + tf[t]·Wtime[o]) ----------------
__global__ __launch_bounds__(256) void rsd_kernel(const float* __restrict__ pe,
        const float* __restrict__ tfeat, const float* __restrict__ Wtime,
        u16* __restrict__ rsd) {
    int t = blockIdx.x, tid = threadIdx.x;
    int l = t & 2047;
    float t0 = tfeat[(size_t)t * 4], t1 = tfeat[(size_t)t * 4 + 1];
    float t2 = tfeat[(size_t)t * 4 + 2], t3 = tfeat[(size_t)t * 4 + 3];
    for (int o = tid; o < DM; o += 256) {
        float v = pe[l * DM + o]
            + t0 * Wtime[o * 4] + t1 * Wtime[o * 4 + 1]
            + t2 * Wtime[o * 4 + 2] + t3 * Wtime[o * 4 + 3];
        sep_store(rsd, (size_t)t, 1024, o, v);
    }
}

// ---------------- weight split -> separated u16 buffers (+ fused bias concat) ----------
__global__ __launch_bounds__(256) void split_weights(const float* __restrict__ Wq,
        const float* __restrict__ Wk, const float* __restrict__ Wv,
        const float* __restrict__ Wo, const float* __restrict__ W1,
        const float* __restrict__ W2, u16* __restrict__ out,
        const float* __restrict__ bq, const float* __restrict__ bk,
        const float* __restrict__ bv, float* __restrict__ bqkv) {
    int i = blockIdx.x * 256 + threadIdx.x;  // < 3145728
    if (i < 1536)
        bqkv[i] = (i < 512) ? bq[i] : (i < 1024) ? bk[i - 512] : bv[i - 1024];
    if (i < 1048576) {
        const float* src = (i < 262144) ? Wq : (i < 524288) ? Wk : (i < 786432) ? Wv : Wo;
        int off = i & 262143;
        size_t base = (size_t)(i >> 18) * 524288;  // u16
        sep_store(out + base, (size_t)(off >> 9), 1024, off & 511, src[off]);
    } else if (i < 2097152) {
        int off = i - 1048576;
        sep_store(out + 2097152, (size_t)(off >> 9), 1024, off & 511, W1[off]);
    } else {
        int off = i - 2097152;
        sep_store(out + 4194304, (size_t)(off >> 11), 4096, off & 2047, W2[off]);
    }
}

// ---------------- separated-u16 MFMA GEMM, double-buffered single-barrier ------------
// A,W separated-group; LDS XOR chunk swizzle; direct ds_read_b128 fragments.
// Output: fp32 (OUTP=0,OUTB=0), separated pair (OUTP=1), or plain bf16 (OUTB=1).
template<bool RELU, bool RESP, bool OUTP, bool OUTB>
__global__ __launch_bounds__(256, 2) void gemm_pp(const u16* __restrict__ Ap,
        const u16* __restrict__ Wp, const float* __restrict__ bias,
        const u16* __restrict__ RsdS, float* __restrict__ Cf, u16* __restrict__ Cp,
        int ldc, int K, int lda) {
    __shared__ alignas(16) u16 At[2][8192];   // [row 0..127][chunk 0..7][8 u16]
    __shared__ alignas(16) u16 Wt[2][8192];
    const int tid = threadIdx.x;
    int linear = blockIdx.y * gridDim.x + blockIdx.x;
    int xcd = linear & 7, sseq = linear >> 3;
    int mper = gridDim.y >> 3;
    int mt = xcd * mper + (sseq % mper);
    int nt = sseq / mper;
    const int m0 = mt * 128, n0 = nt * 128;
    const int lane = tid & 63, wv = tid >> 6;
    const int wm = wv >> 1, wn = wv & 1;
    const int fr = lane & 15, q = lane >> 4;

    floatx4 acc[4][4] = {};

    const int r0 = tid >> 3;
    const int gc = (tid & 7) ^ (r0 & 7);
    const u16* abase = Ap + (size_t)(m0 + r0) * (2 * lda) + gc * 8;
    const u16* wbase = Wp + (size_t)(n0 + r0) * (2 * K) + gc * 8;
    const size_t astep = (size_t)32 * 2 * lda;
    const size_t wstep = (size_t)32 * 2 * K;
    const int doff = tid * 16;
    const int nk = K >> 5;

    const int cph = ((q << 1) ^ (fr & 7)) << 3;
    const int cpl = ((q << 1) ^ (fr & 7) ^ 1) << 3;

#pragma unroll
    for (int i = 0; i < 4; i++) {
        async16(abase + i * astep, (char*)At[0] + doff + i * 4096);
        async16(wbase + i * wstep, (char*)Wt[0] + doff + i * 4096);
    }

    for (int k = 0; k < nk; k++) {
        const int b = k & 1;
        __syncthreads();
        if (k + 1 < nk) {
            int k2 = (k + 1) << 6;
#pragma unroll
            for (int i = 0; i < 4; i++) {
                async16(abase + k2 + i * astep, (char*)At[b ^ 1] + doff + i * 4096);
                async16(wbase + k2 + i * wstep, (char*)Wt[b ^ 1] + doff + i * 4096);
            }
        }
        short8 ah[4], al[4];
#pragma unroll
        for (int mi = 0; mi < 4; mi++) {
            int r = wm * 64 + mi * 16 + fr;
            ah[mi] = *(const short8*)&At[b][r * 64 + cph];
            al[mi] = *(const short8*)&At[b][r * 64 + cpl];
        }
#pragma unroll
        for (int ni = 0; ni < 4; ni++) {
            int r = wn * 64 + ni * 16 + fr;
            short8 wh8 = *(const short8*)&Wt[b][r * 64 + cph];
            short8 wl8 = *(const short8*)&Wt[b][r * 64 + cpl];
#pragma unroll
            for (int mi = 0; mi < 4; mi++) {
                acc[mi][ni] = __builtin_amdgcn_mfma_f32_16x16x32_bf16(ah[mi], wh8, acc[mi][ni], 0, 0, 0);
                acc[mi][ni] = __builtin_amdgcn_mfma_f32_16x16x32_bf16(ah[mi], wl8, acc[mi][ni], 0, 0, 0);
                acc[mi][ni] = __builtin_amdgcn_mfma_f32_16x16x32_bf16(al[mi], wh8, acc[mi][ni], 0, 0, 0);
            }
        }
    }
#pragma unroll
    for (int ni = 0; ni < 4; ni++) {
        int col = n0 + wn * 64 + ni * 16 + fr;
        float bv = bias[col];
#pragma unroll
        for (int mi = 0; mi < 4; mi++) {
            int row = m0 + wm * 64 + mi * 16 + q * 4;
#pragma unroll
            for (int r = 0; r < 4; r++) {
                float v = acc[mi][ni][r] + bv;
                if (RESP) v += sep_load(RsdS, (size_t)(row + r), 2 * ldc, col);
                if (RELU) v = fmaxf(v, 0.f);
                if (OUTP)      sep_store(Cp, (size_t)(row + r), 2 * ldc, col, v);
                else if (OUTB) Cp[(size_t)(row + r) * ldc + col] = bf16rn(v);
                else           Cf[(size_t)(row + r) * ldc + col] = v;
            }
        }
    }
}

// ---------------- single-bf16-A GEMM (2 MFMA/step): C = A*W^T + bias + sep-res --------
// A: plain bf16 [row][K]. LDS A: slot p -> row=p&127, kc=p>>7 (col-major; 2-way free).
template<bool RELU, bool RESP>
__global__ __launch_bounds__(256, 2) void gemm_sb(const u16* __restrict__ Ab,
        const u16* __restrict__ Wp, const float* __restrict__ bias,
        const u16* __restrict__ RsdS, float* __restrict__ Cf,
        int ldc, int K, int lda) {
    __shared__ alignas(16) u16 At[2][4096];   // [kc 0..3][row 0..127][8 u16]
    __shared__ alignas(16) u16 Wt[2][8192];
    const int tid = threadIdx.x;
    int linear = blockIdx.y * gridDim.x + blockIdx.x;
    int xcd = linear & 7, sseq = linear >> 3;
    int mper = gridDim.y >> 3;
    int mt = xcd * mper + (sseq % mper);
    int nt = sseq / mper;
    const int m0 = mt * 128, n0 = nt * 128;
    const int lane = tid & 63, wv = tid >> 6;
    const int wm = wv >> 1, wn = wv & 1;
    const int fr = lane & 15, q = lane >> 4;

    floatx4 acc[4][4] = {};

    // A staging: slot p = tid + i*256; row = tid&127, kc = (tid>>7) + 2i
    const int ar = tid & 127;
    const u16* abase = Ab + (size_t)(m0 + ar) * lda + (tid >> 7) * 8;
    const int adoff = tid * 16;   // byte, +i*4096
    // W staging (separated pair, same as gemm_pp)
    const int r0 = tid >> 3;
    const int gc = (tid & 7) ^ (r0 & 7);
    const u16* wbase = Wp + (size_t)(n0 + r0) * (2 * K) + gc * 8;
    const size_t wstep = (size_t)32 * 2 * K;
    const int wdoff = tid * 16;
    const int nk = K >> 5;

    const int cph = ((q << 1) ^ (fr & 7)) << 3;
    const int cpl = ((q << 1) ^ (fr & 7) ^ 1) << 3;

#pragma unroll
    for (int i = 0; i < 2; i++)
        async16(abase + i * 16, (char*)At[0] + adoff + i * 4096);
#pragma unroll
    for (int i = 0; i < 4; i++)
        async16(wbase + i * wstep, (char*)Wt[0] + wdoff + i * 4096);

    for (int k = 0; k < nk; k++) {
        const int b = k & 1;
        __syncthreads();
        if (k + 1 < nk) {
            int ka = (k + 1) << 5;   // u16 elems
            int kw = (k + 1) << 6;
#pragma unroll
            for (int i = 0; i < 2; i++)
                async16(abase + ka + i * 16, (char*)At[b ^ 1] + adoff + i * 4096);
#pragma unroll
            for (int i = 0; i < 4; i++)
                async16(wbase + kw + i * wstep, (char*)Wt[b ^ 1] + wdoff + i * 4096);
        }
        short8 af[4];
#pragma unroll
        for (int mi = 0; mi < 4; mi++) {
            int r = wm * 64 + mi * 16 + fr;
            af[mi] = *(const short8*)&At[b][q * 1024 + r * 8];
        }
#pragma unroll
        for (int ni = 0; ni < 4; ni++) {
            int r = wn * 64 + ni * 16 + fr;
            short8 wh8 = *(const short8*)&Wt[b][r * 64 + cph];
            short8 wl8 = *(const short8*)&Wt[b][r * 64 + cpl];
#pragma unroll
            for (int mi = 0; mi < 4; mi++) {
                acc[mi][ni] = __builtin_amdgcn_mfma_f32_16x16x32_bf16(af[mi], wh8, acc[mi][ni], 0, 0, 0);
                acc[mi][ni] = __builtin_amdgcn_mfma_f32_16x16x32_bf16(af[mi], wl8, acc[mi][ni], 0, 0, 0);
            }
        }
    }
#pragma unroll
    for (int ni = 0; ni < 4; ni++) {
        int col = n0 + wn * 64 + ni * 16 + fr;
        float bv = bias[col];
#pragma unroll
        for (int mi = 0; mi < 4; mi++) {
            int row = m0 + wm * 64 + mi * 16 + q * 4;
#pragma unroll
            for (int r = 0; r < 4; r++) {
                float v = acc[mi][ni][r] + bv;
                if (RESP) v += sep_load(RsdS, (size_t)(row + r), 2 * ldc, col);
                if (RELU) v = fmaxf(v, 0.f);
                Cf[(size_t)(row + r) * ldc + col] = v;
            }
        }
    }
}

// ---------------- M = max(QK_sample) - sum/L : one wave per (b,h,l) ----------------
__global__ __launch_bounds__(256) void qk_sample_kernel(const float* __restrict__ qkv,
        const int* __restrict__ idx_sample, float* __restrict__ Mout) {
    int r = (blockIdx.x * 256 + threadIdx.x) >> 6;
    int lane = threadIdx.x & 63;
    if (r >= BATCH * NH * SEQ) return;
    int b = r / (NH * SEQ);
    int head = (r / SEQ) % NH;
    int l = r % SEQ;
    int sidx = lane >> 4, dc = lane & 15;
    const float* qrow = qkv + ((size_t)(b * SEQ + l)) * QKVLD + head * HD + dc * 4;
    float4 qf = *(const float4*)qrow;
    int myidx = (lane < NSAMP) ? idx_sample[l * NSAMP + lane] : 0;
    const float* kbase = qkv + (size_t)b * SEQ * QKVLD + 512 + head * HD + dc * 4;
    int kidx[6];
#pragma unroll
    for (int p = 0; p < 6; p++) kidx[p] = __shfl(myidx, p * 4 + sidx);
    float4 kf[6];
#pragma unroll
    for (int p = 0; p < 6; p++) kf[p] = *(const float4*)(kbase + (size_t)kidx[p] * QKVLD);
    float mx = -INFINITY, sm = 0.f;
#pragma unroll
    for (int p = 0; p < 6; p++) {
        float part = qf.x * kf[p].x + qf.y * kf[p].y + qf.z * kf[p].z + qf.w * kf[p].w;
        part += __shfl_xor(part, 1);
        part += __shfl_xor(part, 2);
        part += __shfl_xor(part, 4);
        part += __shfl_xor(part, 8);
        mx = fmaxf(mx, part);
        sm += part;
    }
    mx = fmaxf(mx, __shfl_xor(mx, 16));
    mx = fmaxf(mx, __shfl_xor(mx, 32));
    sm += __shfl_xor(sm, 16);
    sm += __shfl_xor(sm, 32);
    if (lane == 0) Mout[r] = mx - sm * (1.f / SEQ);
}

// ---------------- top-24: register keys + wave shuffle reduce ----------------
__device__ __forceinline__ u64 pack_key(float v, int idx) {
    u32 u = __float_as_uint(v);
    u32 m = (u & 0x80000000u) ? ~u : (u | 0x80000000u);
    return ((u64)m << 32) | (u32)(~(u32)idx);
}

__global__ __launch_bounds__(256) void topk_part(const float* __restrict__ Mbuf,
        u64* __restrict__ cand) {
    __shared__ u64 wred[4];
    int bh = blockIdx.x, chunk = blockIdx.y;
    int tid = threadIdx.x, wv = tid >> 6, lane = tid & 63;
    int l = chunk * 256 + tid;
    u64 val = pack_key(Mbuf[(size_t)bh * SEQ + l], l);
    for (int it = 0; it < NTOP; it++) {
        u64 w = val;
#pragma unroll
        for (int off = 32; off > 0; off >>= 1) {
            u64 o = __shfl_xor(w, off);
            if (o > w) w = o;
        }
        if (lane == 0) wred[wv] = w;
        __syncthreads();
        u64 win = wred[0];
        if (wred[1] > win) win = wred[1];
        if (wred[2] > win) win = wred[2];
        if (wred[3] > win) win = wred[3];
        if (val == win) val = 0;
        if (tid == 0) cand[((size_t)bh * 8 + chunk) * NTOP + it] = win;
        __syncthreads();
    }
}

__global__ __launch_bounds__(256) void topk_merge(const u64* __restrict__ cand,
        int* __restrict__ idx_top) {
    __shared__ u64 wred[4];
    int bh = blockIdx.x;
    int tid = threadIdx.x, wv = tid >> 6, lane = tid & 63;
    u64 val = (tid < 8 * NTOP) ? cand[(size_t)bh * 8 * NTOP + tid] : 0;
    for (int it = 0; it < NTOP; it++) {
        u64 w = val;
#pragma unroll
        for (int off = 32; off > 0; off >>= 1) {
            u64 o = __shfl_xor(w, off);
            if (o > w) w = o;
        }
        if (lane == 0) wred[wv] = w;
        __syncthreads();
        u64 win = wred[0];
        if (wred[1] > win) win = wred[1];
        if (wred[2] > win) win = wred[2];
        if (wred[3] > win) win = wred[3];
        if (val == win) val = 0;
        if (tid == 0) idx_top[bh * NTOP + it] = (int)(~(u32)(win & 0xffffffffull) & (SEQ - 1));
        __syncthreads();
    }
}

// ---------------- V mean over keys per (b,h) ----------------
__global__ __launch_bounds__(256) void vmean_kernel(const float* __restrict__ qkv,
        float* __restrict__ vmean) {
    __shared__ float red[256];
    int bh = blockIdx.x, slab = blockIdx.y;
    int b = bh >> 3, head = bh & 7;
    int seg = threadIdx.x >> 6, d = threadIdx.x & 63;
    int base_row = slab * 256 + seg * 64;
    float s = 0.f;
    for (int r = 0; r < 64; r++)
        s += qkv[((size_t)(b * SEQ + base_row + r)) * QKVLD + 1024 + head * HD + d];
    red[threadIdx.x] = s;
    __syncthreads();
    if (threadIdx.x < 128) red[threadIdx.x] += red[threadIdx.x + 128];
    __syncthreads();
    if (threadIdx.x < 64) {
        float t = red[threadIdx.x] + red[threadIdx.x + 64];
        atomicAdd(&vmean[bh * HD + d], t * (1.f / SEQ));
    }
}

// ---------------- fill context (separated u16) with V-mean: thread = one group ---------
__global__ void fillctx_kernel(const float* __restrict__ vmean, u16* __restrict__ out) {
    int e = blockIdx.x * 256 + threadIdx.x;   // < TOK*64
    int t = e >> 6, g = e & 63;
    const float* vm = vmean + ((((t >> 11) << 3) | (g >> 3)) << 6) + (g & 7) * 8;
    short8 hh, ll;
#pragma unroll
    for (int s = 0; s < 8; s++) {
        float v = vm[s];
        u16 hb = bf16rn(v);
        hh[s] = (short)hb;
        ll[s] = (short)bf16rn(v - __uint_as_float((u32)hb << 16));
    }
    u16* dp = out + (size_t)t * 1024 + g * 16;
    *(short8*)dp = hh;
    *(short8*)(dp + 8) = ll;
}

// ---------------- flash-style sparse attention: block = (b*h, key-slab of 512) ----------------
__global__ __launch_bounds__(256) void spattn_flash(const float* __restrict__ qkv,
        const int* __restrict__ idx_top, float* __restrict__ opart,
        float* __restrict__ mspart) {
    __shared__ float KtT[64][65];   // transposed: [dim][key]
    __shared__ float Vt[64][65];    // [key][dim]
    __shared__ float Qs[24][64];
    __shared__ float Ps[24][66];
    int bh = blockIdx.x, slab = blockIdx.y;
    int b = bh >> 3, h = bh & 7;
    int tid = threadIdx.x;
    int wv = tid >> 6, lane = tid & 63;
    for (int i = tid; i < NTOP * 64; i += 256) {
        int u = i >> 6, d = i & 63;
        int qi = idx_top[bh * NTOP + u];
        Qs[u][d] = qkv[((size_t)(b * SEQ + qi)) * QKVLD + h * HD + d];
    }
    float m[6], s[6], o[6], alpha[6];
#pragma unroll
    for (int j = 0; j < 6; j++) { m[j] = -INFINITY; s[j] = 0.f; o[j] = 0.f; }
    int key0 = slab * 512;
    int sr = tid >> 2, sc0 = (tid & 3) * 16;
    for (int t = 0; t < 8; t++) {
        int kbase = key0 + t * 64;
        __syncthreads();
        const float* kr = qkv + ((size_t)(b * SEQ + kbase + sr)) * QKVLD + 512 + h * HD + sc0;
        const float* vr = qkv + ((size_t)(b * SEQ + kbase + sr)) * QKVLD + 1024 + h * HD + sc0;
        float kf[16], vf[16];
        *(float4*)&kf[0]  = *(const float4*)(kr);
        *(float4*)&kf[4]  = *(const float4*)(kr + 4);
        *(float4*)&kf[8]  = *(const float4*)(kr + 8);
        *(float4*)&kf[12] = *(const float4*)(kr + 12);
        *(float4*)&vf[0]  = *(const float4*)(vr);
        *(float4*)&vf[4]  = *(const float4*)(vr + 4);
        *(float4*)&vf[8]  = *(const float4*)(vr + 8);
        *(float4*)&vf[12] = *(const float4*)(vr + 12);
#pragma unroll
        for (int i = 0; i < 16; i++) {
            KtT[sc0 + i][sr] = kf[i];
            Vt[sr][sc0 + i] = vf[i];
        }
        __syncthreads();
        float dot[6] = {};
#pragma unroll
        for (int d = 0; d < 64; d++) {
            float kv = KtT[d][lane];
#pragma unroll
            for (int j = 0; j < 6; j++) dot[j] += Qs[wv * 6 + j][d] * kv;
        }
#pragma unroll
        for (int j = 0; j < 6; j++) {
            float sc = dot[j] * 0.125f;
            float tmax = sc;
            for (int off = 32; off > 0; off >>= 1) tmax = fmaxf(tmax, __shfl_xor(tmax, off));
            float mn = fmaxf(m[j], tmax);
            float p = __expf(sc - mn);
            float psum = p;
            for (int off = 32; off > 0; off >>= 1) psum += __shfl_xor(psum, off);
            alpha[j] = __expf(m[j] - mn);
            s[j] = s[j] * alpha[j] + psum;
            m[j] = mn;
            Ps[wv * 6 + j][lane] = p;
        }
        float pv[6] = {};
#pragma unroll
        for (int key = 0; key < 64; key++) {
            float vvv = Vt[key][lane];
#pragma unroll
            for (int j = 0; j < 6; j++) pv[j] += Ps[wv * 6 + j][key] * vvv;
        }
#pragma unroll
        for (int j = 0; j < 6; j++) o[j] = o[j] * alpha[j] + pv[j];
    }
    float* ob = opart + ((size_t)(bh * 4 + slab)) * NTOP * 64;
#pragma unroll
    for (int j = 0; j < 6; j++) ob[(wv * 6 + j) * 64 + lane] = o[j];
    if (lane == 0) {
        float* ms = mspart + ((size_t)(bh * 4 + slab)) * NTOP * 2;
#pragma unroll
        for (int j = 0; j < 6; j++) {
            ms[(wv * 6 + j) * 2]     = m[j];
            ms[(wv * 6 + j) * 2 + 1] = s[j];
        }
    }
}

// ---------------- merge 4 slab partials, scatter (separated u16) into context ----------
__global__ __launch_bounds__(256) void spattn_combine(const float* __restrict__ opart,
        const float* __restrict__ mspart, const int* __restrict__ idx_top,
        u16* __restrict__ out) {
    __shared__ float wgt[4][NTOP];
    int bh = blockIdx.x;
    int b = bh >> 3, h = bh & 7;
    int tid = threadIdx.x;
    if (tid < NTOP) {
        float mv[4], sv[4];
        float M = -INFINITY;
#pragma unroll
        for (int sl = 0; sl < 4; sl++) {
            mv[sl] = mspart[((size_t)(bh * 4 + sl)) * NTOP * 2 + tid * 2];
            sv[sl] = mspart[((size_t)(bh * 4 + sl)) * NTOP * 2 + tid * 2 + 1];
            M = fmaxf(M, mv[sl]);
        }
        float S = 0.f;
#pragma unroll
        for (int sl = 0; sl < 4; sl++) S += sv[sl] * __expf(mv[sl] - M);
        float invS = 1.f / S;
#pragma unroll
        for (int sl = 0; sl < 4; sl++) wgt[sl][tid] = __expf(mv[sl] - M) * invS;
    }
    __syncthreads();
    for (int i = tid; i < NTOP * 64; i += 256) {
        int u = i >> 6, d = i & 63;
        float val = 0.f;
#pragma unroll
        for (int sl = 0; sl < 4; sl++)
            val += wgt[sl][u] * opart[(((size_t)(bh * 4 + sl)) * NTOP + u) * 64 + d];
        int qi = idx_top[bh * NTOP + u];
        sep_store(out, (size_t)(b * SEQ + qi), 1024, h * HD + d, val);
    }
}

// ---------------- layernorm over DM=512: one wave per row; sep in/out options ----------
template<bool INP, bool OUTSEP>
__global__ __launch_bounds__(256) void ln_kernel(const float* __restrict__ srcF,
        const u16* __restrict__ srcS, const float* __restrict__ g,
        const float* __restrict__ b, float* __restrict__ dstF, u16* __restrict__ dstS) {
    int wv = threadIdx.x >> 6, lane = threadIdx.x & 63;
    int t = blockIdx.x * 4 + wv;
    float xv[8];
    if (INP) {
        const u16* sp = srcS + (size_t)t * 1024 + (lane >> 1) * 16 + (lane & 1) * 4;
        short4v h0 = *(const short4v*)sp;
        short4v l0 = *(const short4v*)(sp + 8);
        short4v h1 = *(const short4v*)(sp + 512);
        short4v l1 = *(const short4v*)(sp + 520);
#pragma unroll
        for (int i = 0; i < 4; i++) {
            xv[i]     = hl2f((u16)h0[i], (u16)l0[i]);
            xv[i + 4] = hl2f((u16)h1[i], (u16)l1[i]);
        }
    } else {
        float4 x0 = *(const float4*)&srcF[(size_t)t * DM + lane * 4];
        float4 x1 = *(const float4*)&srcF[(size_t)t * DM + lane * 4 + 256];
        xv[0] = x0.x; xv[1] = x0.y; xv[2] = x0.z; xv[3] = x0.w;
        xv[4] = x1.x; xv[5] = x1.y; xv[6] = x1.z; xv[7] = x1.w;
    }
    float s = 0.f, s2 = 0.f;
#pragma unroll
    for (int i = 0; i < 8; i++) { s += xv[i]; s2 += xv[i] * xv[i]; }
#pragma unroll
    for (int off = 32; off > 0; off >>= 1) {
        s  += __shfl_xor(s, off);
        s2 += __shfl_xor(s2, off);
    }
    float m = s * (1.f / DM);
    float var = s2 * (1.f / DM) - m * m;
    float inv = rsqrtf(var + EPS);
    float4 g0 = *(const float4*)&g[lane * 4];
    float4 g1 = *(const float4*)&g[lane * 4 + 256];
    float4 b0 = *(const float4*)&b[lane * 4];
    float4 b1 = *(const float4*)&b[lane * 4 + 256];
    float y[8];
    y[0] = (xv[0] - m) * inv * g0.x + b0.x;  y[1] = (xv[1] - m) * inv * g0.y + b0.y;
    y[2] = (xv[2] - m) * inv * g0.z + b0.z;  y[3] = (xv[3] - m) * inv * g0.w + b0.w;
    y[4] = (xv[4] - m) * inv * g1.x + b1.x;  y[5] = (xv[5] - m) * inv * g1.y + b1.y;
    y[6] = (xv[6] - m) * inv * g1.z + b1.z;  y[7] = (xv[7] - m) * inv * g1.w + b1.w;
    if (OUTSEP) {
        u16* dp = dstS + (size_t)t * 1024 + (lane >> 1) * 16 + (lane & 1) * 4;
        short4v hh0, ll0, hh1, ll1;
#pragma unroll
        for (int i = 0; i < 4; i++) {
            u16 hb = bf16rn(y[i]);
            hh0[i] = (short)hb;
            ll0[i] = (short)bf16rn(y[i] - __uint_as_float((u32)hb << 16));
            u16 hb2 = bf16rn(y[i + 4]);
            hh1[i] = (short)hb2;
            ll1[i] = (short)bf16rn(y[i + 4] - __uint_as_float((u32)hb2 << 16));
        }
        *(short4v*)dp = hh0;
        *(short4v*)(dp + 8) = ll0;
        *(short4v*)(dp + 512) = hh1;
        *(short4v*)(dp + 520) = ll1;
    } else {
        float4 o0 = { y[0], y[1], y[2], y[3] };
        float4 o1 = { y[4], y[5], y[6], y[7] };
        *(float4*)&dstF[(size_t)t * DM + lane * 4] = o0;
        *(float4*)&dstF[(size_t)t * DM + lane * 4 + 256] = o1;
    }
}

// ---------------- prediction head on last token ----------------
__global__ __launch_bounds__(256) void head_kernel(const float* __restrict__ hfin,
        const float* __restrict__ Wpre, const float* __restrict__ bpre,
        const float* __restrict__ Wfc, const float* __restrict__ bfc,
        float* __restrict__ out) {
    __shared__ float last[DM];
    __shared__ float red[256];
    int b = blockIdx.x, tid = threadIdx.x;
    const float* hr = hfin + ((size_t)(b * SEQ + SEQ - 1)) * DM;
    last[tid] = hr[tid];
    last[tid + 256] = hr[tid + 256];
    __syncthreads();
    float acc = bpre[tid];
    for (int c = 0; c < DM; c++) acc += last[c] * Wpre[tid * DM + c];
    acc = fmaxf(acc, 0.f);
    red[tid] = acc * Wfc[tid];
    __syncthreads();
    for (int s = 128; s > 0; s >>= 1) { if (tid < s) red[tid] += red[tid + s]; __syncthreads(); }
    if (tid == 0) out[b] = red[0] + bfc[0];
}

extern "C" void kernel_launch(void* const* d_in, const int* in_sizes, int n_in,
                              void* d_out, int out_size, void* d_ws, size_t ws_size,
                              hipStream_t stream) {
    (void)in_sizes; (void)n_in; (void)out_size; (void)ws_size;
    const float* x      = (const float*)d_in[0];
    const float* tfeat  = (const float*)d_in[1];
    const float* g_in   = (const float*)d_in[2];
    const float* b_in   = (const float*)d_in[3];
    const float* W_tok  = (const float*)d_in[4];
    const float* W_time = (const float*)d_in[5];
    const float* b_time = (const float*)d_in[6];
    const float* Wq     = (const float*)d_in[7];
    const float* bq     = (const float*)d_in[8];
    const float* Wk     = (const float*)d_in[9];
    const float* bk     = (const float*)d_in[10];
    const float* Wv     = (const float*)d_in[11];
    const float* bv     = (const float*)d_in[12];
    const float* Wo     = (const float*)d_in[13];
    const float* bo     = (const float*)d_in[14];
    const float* W1     = (const float*)d_in[15];
    const float* b1     = (const float*)d_in[16];
    const float* W2     = (const float*)d_in[17];
    const float* b2     = (const float*)d_in[18];
    const float* g1     = (const float*)d_in[19];
    const float* be1    = (const float*)d_in[20];
    const float* g2     = (const float*)d_in[21];
    const float* be2    = (const float*)d_in[22];
    const float* g_enc  = (const float*)d_in[23];
    const float* b_enc  = (const float*)d_in[24];
    const float* W_pre  = (const float*)d_in[25];
    const float* b_pre  = (const float*)d_in[26];
    const float* W_fc   = (const float*)d_in[27];
    const float* b_fc   = (const float*)d_in[28];
    float* out = (float*)d_out;

    char* ws = (char*)d_ws;
    u16*   hp   = (u16*)(ws);                        // 33.5 MB residual stream (separated)
    float* hf   = (float*)(ws + 33554432);           // 33.5 MB fp32 scratch
    char*  bigc = ws + 67108864;                     // 134.2 MB multi-use
    float* qkv  = (float*)bigc;                      // [TOK][1536] fp32 (100.7 MB)
    u16*   ctxP = (u16*)(bigc + 100663296);          // attn ctx separated (33.5 MB)
    u16*   midP = (u16*)bigc;                        // FFN mid separated (layer 1)
    u16*   midB = (u16*)bigc;                        // FFN mid plain bf16 (layer 2, 67 MB)
    // embed-stage overlays inside bigc:
    float* xln  = (float*)(bigc);                    // 2 MB
    u16*   acvP = (u16*)(bigc + 2097152);            // im2col separated [TOK][192] u16
    float* pe   = (float*)(bigc + 8388608);          // 4 MB
    u16*   rsdS = (u16*)(bigc + 12582912);           // 33.5 MB
    u16*   wtok = (u16*)(bigc + 46137344);           // W_tok separated [512][192] u16
    u16*   wsep       = (u16*)(ws + 201326592);      // 12.6 MB per-layer weights
    float* Mbuf       = (float*)(ws + 213909504);    // 0.5 MB
    float* vmean      = (float*)(ws + 214433792);
    int*   idx_sample = (int*)(ws + 214450176);
    int*   idx_top    = (int*)(ws + 214843392);
    float* biasqkv    = (float*)(ws + 214849536);
    u64*   cand       = (u64*)(ws + 214855680);      // 98 KB
    float* opart      = (float*)(ws + 214953984);    // 1.57 MB
    float* mspart     = (float*)(ws + 216526848);    // 48 KB

    ln_in_kernel<<<TOK / 256, 256, 0, stream>>>(x, g_in, b_in, xln);
    im2col_kernel<<<TOK, 128, 0, stream>>>(xln, acvP);
    wtok_split<<<192, 256, 0, stream>>>(W_tok, wtok);
    pe_kernel<<<4096, 256, 0, stream>>>(pe);
    rsd_kernel<<<TOK, 256, 0, stream>>>(pe, tfeat, W_time, rsdS);
    sample_kernel<<<dim3(96, 2), 256, 0, stream>>>(idx_sample);

    // conv-as-GEMM: hp = sep(im2col @ W_tok^T + b_time + (pe + time emb))
    gemm_pp<false, true, true, false><<<dim3(4, 128), 256, 0, stream>>>(
        acvP, wtok, b_time, rsdS, nullptr, hp, DM, 96, 96);

    const u16* wqkv_p = wsep;                 // rows 0..1535 = Wq;Wk;Wv (K=512)
    const u16* wo_p = wsep + 1572864;
    const u16* w1_p = wsep + 2097152;
    const u16* w2_p = wsep + 4194304;

    for (int li = 0; li < 2; li++) {
        split_weights<<<12288, 256, 0, stream>>>(
            Wq + (size_t)li * DM * DM, Wk + (size_t)li * DM * DM,
            Wv + (size_t)li * DM * DM, Wo + (size_t)li * DM * DM,
            W1 + (size_t)li * DFF * DM, W2 + (size_t)li * DM * DFF, wsep,
            bq + (size_t)li * DM, bk + (size_t)li * DM, bv + (size_t)li * DM, biasqkv);

        const float* bo_i = bo + (size_t)li * DM;
        const float* b1_i = b1 + (size_t)li * DFF;
        const float* b2_i = b2 + (size_t)li * DM;
        const float* g1_i = g1 + (size_t)li * DM;
        const float* be1_i = be1 + (size_t)li * DM;
        const float* g2_i = g2 + (size_t)li * DM;
        const float* be2_i = be2 + (size_t)li * DM;

        // fused QKV: [TOK][1536] fp32
        gemm_pp<false, false, false, false><<<dim3(QKVLD / 128, TOK / 128), 256, 0, stream>>>(
            hp, wqkv_p, biasqkv, nullptr, qkv, nullptr, QKVLD, DM, DM);

        qk_sample_kernel<<<(BATCH * NH * SEQ) / 4, 256, 0, stream>>>(
            qkv, idx_sample + li * SEQ * NSAMP, Mbuf);
        topk_part<<<dim3(BATCH * NH, 8), 256, 0, stream>>>(Mbuf, cand);
        topk_merge<<<BATCH * NH, 256, 0, stream>>>(cand, idx_top);
        hipMemsetAsync(vmean, 0, BATCH * NH * HD * sizeof(float), stream);
        vmean_kernel<<<dim3(BATCH * NH, 8), 256, 0, stream>>>(qkv, vmean);
        fillctx_kernel<<<(TOK * 64) / 256, 256, 0, stream>>>(vmean, ctxP);
        spattn_flash<<<dim3(BATCH * NH, 4), 256, 0, stream>>>(qkv, idx_top, opart, mspart);
        spattn_combine<<<BATCH * NH, 256, 0, stream>>>(opart, mspart, idx_top, ctxP);

        // Wo with sep-residual hp -> fp32 hf
        gemm_pp<false, true, false, false><<<dim3(DM / 128, TOK / 128), 256, 0, stream>>>(
            ctxP, wo_p, bo_i, hp, hf, nullptr, DM, DM, DM);
        ln_kernel<false, true><<<TOK / 4, 256, 0, stream>>>(hf, nullptr, g1_i, be1_i, nullptr, hp);

        if (li == 0) {
            // layer-1 FFN: full-precision mid (protects layer-2 ProbSparse selection)
            gemm_pp<true, false, true, false><<<dim3(DFF / 128, TOK / 128), 256, 0, stream>>>(
                hp, w1_p, b1_i, nullptr, nullptr, midP, DFF, DM, DM);
            gemm_pp<false, true, false, false><<<dim3(DM / 128, TOK / 128), 256, 0, stream>>>(
                midP, w2_p, b2_i, hp, hf, nullptr, DM, DFF, DFF);
        } else {
            // layer-2 FFN: plain-bf16 mid (output path only; 2-MFMA W2)
            gemm_pp<true, false, false, true><<<dim3(DFF / 128, TOK / 128), 256, 0, stream>>>(
                hp, w1_p, b1_i, nullptr, nullptr, midB, DFF, DM, DM);
            gemm_sb<false, true><<<dim3(DM / 128, TOK / 128), 256, 0, stream>>>(
                midB, w2_p, b2_i, hp, hf, DM, DFF, DFF);
        }
        ln_kernel<false, true><<<TOK / 4, 256, 0, stream>>>(hf, nullptr, g2_i, be2_i, nullptr, hp);
    }

    ln_kernel<true, false><<<TOK / 4, 256, 0, stream>>>(nullptr, hp, g_enc, b_enc, hf, nullptr);
    head_kernel<<<BATCH, 256, 0, stream>>>(hf, W_pre, b_pre, W_fc, b_fc, out);
}